// Round 8
// baseline (708.887 us; speedup 1.0000x reference)
//
#include <hip/hip_runtime.h>
#include <cstddef>
#include <cstdint>

#define B_ 8
#define T_ 120
#define NB_ 40
#define VD_ 2053
#define E_ 256
#define H_ 512
#define M_ 38400   // B*T*NB
#define R_ 960     // B*T

// ---------------- workspace layout (float offsets) ----------------
static constexpr size_t OFF_VE    = 0;                        // 38400*256 (fallback path only)
static constexpr size_t OFF_SSUB  = OFF_VE + (size_t)M_ * E_; // 38400
static constexpr size_t OFF_SOBJ  = OFF_SSUB + M_;
static constexpr size_t OFF_WBS   = OFF_SOBJ + M_;            // 8*256
static constexpr size_t OFF_WBO   = OFF_WBS + B_ * E_;
static constexpr size_t OFF_TBIAS = OFF_WBO + B_ * E_;        // 8*512
static constexpr size_t OFF_ORIX  = OFF_TBIAS + B_ * H_;      // 960*512 each below
static constexpr size_t OFF_X     = OFF_ORIX + (size_t)R_ * H_;
static constexpr size_t OFF_Q     = OFF_X    + (size_t)R_ * H_;
static constexpr size_t OFF_K     = OFF_Q    + (size_t)R_ * H_;
static constexpr size_t OFF_V     = OFF_K    + (size_t)R_ * H_;
static constexpr size_t OFF_AO    = OFF_V    + (size_t)R_ * H_;
static constexpr size_t OFF_ATTN  = OFF_AO   + (size_t)R_ * H_;
static constexpr size_t OFF_X1    = OFF_ATTN + (size_t)R_ * H_;
static constexpr size_t OFF_F1    = OFF_X1   + (size_t)R_ * H_;
static constexpr size_t OFF_F2    = OFF_F1   + (size_t)R_ * H_;
static constexpr size_t OFF_WIN   = OFF_F2   + (size_t)R_ * H_;
static constexpr size_t OFF_WT    = OFF_WIN  + (size_t)R_ * H_; // 2M floats (bf16 weights)
static constexpr size_t OFF_Z2    = OFF_WT + (size_t)1024 * 2048; // 80
static constexpr size_t OFF_H0    = OFF_Z2 + 128;               // h0,h1,c : 3*4096
static constexpr size_t OFF_HB    = OFF_H0 + 3 * 4096;          // 8*512
static constexpr size_t OFF_L1    = OFF_HB + B_ * H_;           // 960
static constexpr size_t OFF_BAR   = OFF_L1 + 960;               // 1 uint (grid barrier)
static constexpr size_t OFF_END0  = OFF_BAR + 4;
// big-ws region (dedicated, non-aliased)
static constexpr size_t OFF_WIH   = (OFF_END0 + 3) & ~(size_t)3;     // 2048*512 ushort
static constexpr size_t OFF_WHH   = OFF_WIH + 524288;
static constexpr size_t OFF_WL1B  = OFF_WHH + 524288;                // 512*512 ushort
static constexpr size_t OFF_WINBF = OFF_WL1B + 131072;               // 960*512 ushort
static constexpr size_t OFF_VEBF  = OFF_WINBF + 245760;              // M*E ushort
static constexpr size_t OFF_END   = OFF_VEBF + (size_t)M_ * E_ / 2;  // ~23.8M floats

// ---------------- d_out layout (float offsets) ----------------
static constexpr size_t O_OUT  = 0;      // 8*512
static constexpr size_t O_HT   = 4096;   // 8*512
static constexpr size_t O_CT   = 8192;   // 8*512
static constexpr size_t O_SATT = 12288;  // 8*120*40
static constexpr size_t O_OATT = 50688;  // 8*120*40
static constexpr size_t O_B1   = 89088;  // 8*120
static constexpr size_t O_B2   = 90048;  // 8*10

#define DEVFN __device__ __forceinline__

typedef __attribute__((ext_vector_type(8))) short short8;
typedef __attribute__((ext_vector_type(4))) float f32x4;

DEVFN float sigf(float x) { return 1.0f / (1.0f + __expf(-x)); }

// inline tanh: no OCML call (round-1 lesson: tanhf caused VGPR spill disaster)
DEVFN float fast_tanh(float x) {
  float e = __expf(2.f * x);
  return 1.f - 2.f / (e + 1.f);
}

// fp32 -> bf16 RNE (validated r3)
DEVFN unsigned short f2bf(float x) {
  unsigned int u = __float_as_uint(x);
  u += 0x7FFFu + ((u >> 16) & 1u);
  return (unsigned short)(u >> 16);
}
DEVFN float bf2f(unsigned short u) { return __uint_as_float((unsigned int)u << 16); }

DEVFN short8 mk8(const float* f) {
  short8 r;
#pragma unroll
  for (int j = 0; j < 8; ++j) r[j] = (short)f2bf(f[j]);
  return r;
}

DEVFN float wredsum(float v) {
#pragma unroll
  for (int m = 32; m; m >>= 1) v += __shfl_xor(v, m);
  return v;
}
DEVFN float wredmax(float v) {
#pragma unroll
  for (int m = 32; m; m >>= 1) v = fmaxf(v, __shfl_xor(v, m));
  return v;
}

// ---------------------------------------------------------------
__global__ __launch_bounds__(256) void k_zero(float* p, int n) {
  int i = blockIdx.x * 256 + threadIdx.x;
  if (i < n) p[i] = 0.f;
}

// Per-batch small precompute (unchanged)
__global__ __launch_bounds__(256) void k_small0(
    const float* __restrict__ sub_g, const float* __restrict__ obj_g,
    const float* __restrict__ W_ew, const float* __restrict__ b_ew,
    const float* __restrict__ W_sp1, const float* __restrict__ b_sp1,
    const float* __restrict__ W_tr, const float* __restrict__ b_tr,
    const float* __restrict__ W_tb1, const float* __restrict__ b_tb1,
    float* __restrict__ wbs, float* __restrict__ wbo, float* __restrict__ tbias) {
  int b = blockIdx.x, tid = threadIdx.x;
  __shared__ float sg[300], og[300], se[256], oe[256], trl[512];
  for (int i = tid; i < 300; i += 256) { sg[i] = sub_g[b * 300 + i]; og[i] = obj_g[b * 300 + i]; }
  __syncthreads();
  {
    float a1 = b_ew[tid], a2 = a1;
    for (int w = 0; w < 300; ++w) {
      float we = W_ew[w * 256 + tid];
      a1 += sg[w] * we; a2 += og[w] * we;
    }
    se[tid] = fmaxf(a1, 0.f); oe[tid] = fmaxf(a2, 0.f);
  }
  __syncthreads();
  {
    float a1 = b_sp1[tid], a2 = a1;
    for (int e = 0; e < 256; ++e) {
      float ww = W_sp1[(256 + e) * 256 + tid];
      a1 += se[e] * ww; a2 += oe[e] * ww;
    }
    wbs[b * 256 + tid] = a1; wbo[b * 256 + tid] = a2;
  }
  for (int jj = 0; jj < 2; ++jj) {
    int j = tid + jj * 256;
    float a = b_tr[j];
    for (int i = 0; i < 256; ++i) a += se[i] * W_tr[i * 512 + j];
    for (int i = 0; i < 256; ++i) a += oe[i] * W_tr[(256 + i) * 512 + j];
    trl[j] = fmaxf(a, 0.f);
  }
  __syncthreads();
  for (int jj = 0; jj < 2; ++jj) {
    int j = tid + jj * 256;
    float a = b_tb1[j];
    for (int i = 0; i < 512; ++i) a += trl[i] * W_tb1[(size_t)(512 + i) * 512 + j];
    tbias[b * 512 + j] = a;
  }
}

// Unified prep kernel (big path): all weight converts + h/c/bar zero, ONE launch.
__global__ __launch_bounds__(256) void k_wprep(
    const float* __restrict__ W_ev, const float* __restrict__ W_tv,
    const float* __restrict__ Wq, const float* __restrict__ Wk,
    const float* __restrict__ Wv, const float* __restrict__ Wo,
    const float* __restrict__ Wf1, const float* __restrict__ Wf2,
    const float* __restrict__ W_sp1, const float* __restrict__ W_l1,
    const float* __restrict__ W_ih, const float* __restrict__ W_hh,
    unsigned short* __restrict__ wevbf, unsigned short* __restrict__ w7bf,
    unsigned short* __restrict__ wsp1bf, unsigned short* __restrict__ wl1bf,
    unsigned short* __restrict__ wihbf, unsigned short* __restrict__ whhbf,
    float* __restrict__ hz, unsigned int* __restrict__ bar) {
  int bid = blockIdx.x, tid = threadIdx.x;
  __shared__ float t[64][65];
  if (bid < 128) {
    int kb = bid >> 2, nb = bid & 3;
#pragma unroll
    for (int i = 0; i < 16; ++i) {
      int idx = tid + 256 * i; int r = idx >> 6, c = idx & 63;
      t[r][c] = W_ev[(size_t)(kb * 64 + r) * 256 + nb * 64 + c];
    }
    __syncthreads();
#pragma unroll
    for (int i = 0; i < 16; ++i) {
      int idx = tid + 256 * i; int n = idx >> 6, kk = idx & 63;
      wevbf[(size_t)(nb * 64 + n) * 2048 + kb * 64 + kk] = f2bf(t[kk][n]);
    }
  } else if (bid < 576) {
    int b2 = bid - 128;
    int wsel = b2 >> 6, sub = b2 & 63;
    int kb = sub >> 3, nb = sub & 7;
    const float* src = wsel == 0 ? W_tv : wsel == 1 ? Wq : wsel == 2 ? Wk
                     : wsel == 3 ? Wv : wsel == 4 ? Wo : wsel == 5 ? Wf1 : Wf2;
    unsigned short* dst = w7bf + (size_t)wsel * 262144;
#pragma unroll
    for (int i = 0; i < 16; ++i) {
      int idx = tid + 256 * i; int r = idx >> 6, c = idx & 63;
      t[r][c] = src[(size_t)(kb * 64 + r) * 512 + nb * 64 + c];
    }
    __syncthreads();
#pragma unroll
    for (int i = 0; i < 16; ++i) {
      int idx = tid + 256 * i; int n = idx >> 6, kk = idx & 63;
      dst[(size_t)(nb * 64 + n) * 512 + kb * 64 + kk] = f2bf(t[kk][n]);
    }
  } else if (bid < 592) {
    int b2 = bid - 576;
    int kb = b2 >> 2, nb = b2 & 3;
#pragma unroll
    for (int i = 0; i < 16; ++i) {
      int idx = tid + 256 * i; int r = idx >> 6, c = idx & 63;
      t[r][c] = W_sp1[(size_t)(kb * 64 + r) * 256 + nb * 64 + c];
    }
    __syncthreads();
#pragma unroll
    for (int i = 0; i < 16; ++i) {
      int idx = tid + 256 * i; int n = idx >> 6, kk = idx & 63;
      wsp1bf[(size_t)(nb * 64 + n) * 256 + kb * 64 + kk] = f2bf(t[kk][n]);
    }
  } else if (bid < 656) {
    int b2 = bid - 592;
    int kb = b2 >> 3, nb = b2 & 7;
#pragma unroll
    for (int i = 0; i < 16; ++i) {
      int idx = tid + 256 * i; int r = idx >> 6, c = idx & 63;
      t[r][c] = W_l1[(size_t)(kb * 64 + r) * 512 + nb * 64 + c];  // rows 0..511
    }
    __syncthreads();
#pragma unroll
    for (int i = 0; i < 16; ++i) {
      int idx = tid + 256 * i; int n = idx >> 6, kk = idx & 63;
      wl1bf[(size_t)(nb * 64 + n) * 512 + kb * 64 + kk] = f2bf(t[kk][n]);
    }
  } else if (bid < 1680) {
    int i = (bid - 656) * 256 + tid;
    const float* s; unsigned short* d; int off;
    if (i < 131072) { s = W_ih; d = wihbf; off = i * 8; }
    else            { s = W_hh; d = whhbf; off = (i - 131072) * 8; }
    float f[8];
#pragma unroll
    for (int j = 0; j < 8; ++j) f[j] = s[off + j];
    *(short8*)(d + off) = mk8(f);
  } else {
    for (int i = tid; i < 12288; i += 256) hz[i] = 0.f;
    if (tid == 0) *bar = 0u;
  }
}

// Fallback converters (small-ws path)
__global__ __launch_bounds__(256) void k_wconvT(const float* __restrict__ src,
                                                unsigned short* __restrict__ dst,
                                                int K, int N) {
  __shared__ float t[64][65];
  int nblk = N >> 6;
  int kb = blockIdx.x / nblk, nb = blockIdx.x - kb * nblk;
  int tid = threadIdx.x;
#pragma unroll
  for (int i = 0; i < 16; ++i) {
    int idx = tid + 256 * i;
    int r = idx >> 6, c = idx & 63;
    t[r][c] = src[(size_t)(kb * 64 + r) * N + nb * 64 + c];
  }
  __syncthreads();
#pragma unroll
  for (int i = 0; i < 16; ++i) {
    int idx = tid + 256 * i;
    int n = idx >> 6, kk = idx & 63;
    dst[(size_t)(nb * 64 + n) * K + kb * 64 + kk] = f2bf(t[kk][n]);
  }
}

__global__ __launch_bounds__(256) void k_wconv7(
    const float* __restrict__ w0, const float* __restrict__ w1,
    const float* __restrict__ w2, const float* __restrict__ w3,
    const float* __restrict__ w4, const float* __restrict__ w5,
    const float* __restrict__ w6, unsigned short* __restrict__ dstb) {
  __shared__ float t[64][65];
  int wsel = blockIdx.x >> 6, sub = blockIdx.x & 63;
  int kb = sub >> 3, nb = sub & 7;
  const float* src = wsel == 0 ? w0 : wsel == 1 ? w1 : wsel == 2 ? w2
                   : wsel == 3 ? w3 : wsel == 4 ? w4 : wsel == 5 ? w5 : w6;
  unsigned short* dst = dstb + (size_t)wsel * 262144;
  int tid = threadIdx.x;
#pragma unroll
  for (int i = 0; i < 16; ++i) {
    int idx = tid + 256 * i;
    int r = idx >> 6, c = idx & 63;
    t[r][c] = src[(size_t)(kb * 64 + r) * 512 + nb * 64 + c];
  }
  __syncthreads();
#pragma unroll
  for (int i = 0; i < 16; ++i) {
    int idx = tid + 256 * i;
    int n = idx >> 6, kk = idx & 63;
    dst[(size_t)(nb * 64 + n) * 512 + kb * 64 + kk] = f2bf(t[kk][n]);
  }
}

__global__ __launch_bounds__(256) void k_cvt2(const float* __restrict__ a,
                                              const float* __restrict__ b,
                                              unsigned short* __restrict__ da,
                                              unsigned short* __restrict__ db) {
  int i = blockIdx.x * 256 + threadIdx.x;
  const float* s; unsigned short* d; int off;
  if (i < 131072) { s = a; d = da; off = i * 8; }
  else            { s = b; d = db; off = (i - 131072) * 8; }
  float f[8];
#pragma unroll
  for (int j = 0; j < 8; ++j) f[j] = s[off + j];
  *(short8*)(d + off) = mk8(f);
}

// ve GEMM, m97 structure, BN-SPLIT: BM=64, BN=128, BK=64, 256 thr / 4 waves,
// wave tile 64x32 (acc 4x2, indexing identical to r6/r7-validated). Grid 1200
// (600 rowblocks x 2 colblocks) -> ~4.7 blocks/CU: more independent barrier
// domains hide the per-step vmcnt drain. XCD-pairing swizzle puts a rowblock's
// two colblocks 8 apart in blockIdx (same XCD under round-robin) so the shared
// A-tile is an L2 hit. Fused fp32->bf16 A staging (scalar loads, r7-validated).
__global__ __launch_bounds__(256) void k_gemm_ve_m97(
    const float* __restrict__ videos, const unsigned short* __restrict__ wtbf,
    const float* __restrict__ bev, const float* __restrict__ Wel,
    const float* __restrict__ bel, unsigned short* __restrict__ vebf) {
  __shared__ __align__(16) unsigned short lds[12288];  // A: [0,4096) B: [4096,12288)
  int tid = threadIdx.x;
  int bid = blockIdx.x;                 // 1200
  int chunk = bid >> 4, within = bid & 15;
  int cb = within >> 3, r8 = within & 7;
  int rowbase = (chunk * 8 + r8) * 64;  // 0..599 rowblocks
  int colbase = cb * 128;
  int lane = tid & 63, wid = tid >> 6;  // 4 waves, wave strip of 32 cols
  int l16 = lane & 15, lk = lane >> 4;

  // A staging: 2 chunks/thread (rows 0..63, 8 fp32 scalar each)
  const float* spA[2];
  int dstA[2];
#pragma unroll
  for (int i = 0; i < 2; ++i) {
    int g = tid + 256 * i;
    int row = g >> 3, kc = g & 7;
    spA[i] = videos + (size_t)(rowbase + row) * VD_ + kc * 8;
    dstA[i] = row * 64 + ((kc ^ (row & 7)) * 8);
  }
  // B staging: 4 chunks/thread (n 0..127, 16B bf16 each)
  const unsigned short* spB[4];
  int dstB[4];
#pragma unroll
  for (int i = 0; i < 4; ++i) {
    int g = tid + 256 * i;
    int n = g >> 3, kc = g & 7;
    spB[i] = wtbf + (size_t)(colbase + n) * 2048 + kc * 8;
    dstB[i] = 4096 + n * 64 + ((kc ^ (n & 7)) * 8);
  }
  float fa[2][8];
  short8 stB[4];
#pragma unroll
  for (int i = 0; i < 2; ++i)
#pragma unroll
    for (int j = 0; j < 8; ++j) fa[i][j] = spA[i][j];
#pragma unroll
  for (int i = 0; i < 4; ++i) stB[i] = *(const short8*)(spB[i]);

  f32x4 acc[4][2] = {};
  for (int k0 = 0; k0 < 2048; k0 += 64) {
    short8 ha0 = mk8(fa[0]), ha1 = mk8(fa[1]);
    __syncthreads();  // prev readers done; prefetch loads drained
    *(short8*)(lds + dstA[0]) = ha0;
    *(short8*)(lds + dstA[1]) = ha1;
#pragma unroll
    for (int i = 0; i < 4; ++i) *(short8*)(lds + dstB[i]) = stB[i];
    __syncthreads();  // tile visible
    int kn = (k0 + 64 < 2048) ? k0 + 64 : 0;
#pragma unroll
    for (int i = 0; i < 2; ++i)
#pragma unroll
      for (int j = 0; j < 8; ++j) fa[i][j] = spA[i][kn + j];
#pragma unroll
    for (int i = 0; i < 4; ++i) stB[i] = *(const short8*)(spB[i] + kn);
#pragma unroll
    for (int kk = 0; kk < 2; ++kk) {
      short8 a8[4], b8[2];
#pragma unroll
      for (int fm = 0; fm < 4; ++fm) {
        int row = fm * 16 + l16;
        a8[fm] = *(const short8*)(lds + row * 64 + (((kk * 4 + lk) ^ (row & 7)) * 8));
      }
#pragma unroll
      for (int fn = 0; fn < 2; ++fn) {
        int n = wid * 32 + fn * 16 + l16;
        b8[fn] = *(const short8*)(lds + 4096 + n * 64 + (((kk * 4 + lk) ^ (n & 7)) * 8));
      }
#pragma unroll
      for (int fm = 0; fm < 4; ++fm)
#pragma unroll
        for (int fn = 0; fn < 2; ++fn)
          acc[fm][fn] = __builtin_amdgcn_mfma_f32_16x16x32_bf16(
              a8[fm], b8[fn], acc[fm][fn], 0, 0, 0);
    }
  }
  // epilogue: C/D map col=lane&15, row=(lane>>4)*4+reg (validated r3-r7)
  float bevv[2], belv[2], w5[5][2];
#pragma unroll
  for (int fn = 0; fn < 2; ++fn) {
    int col = colbase + wid * 32 + fn * 16 + l16;
    bevv[fn] = bev[col]; belv[fn] = bel[col];
#pragma unroll
    for (int kk = 0; kk < 5; ++kk) w5[kk][fn] = Wel[kk * 256 + col];
  }
#pragma unroll
  for (int fm = 0; fm < 4; ++fm) {
#pragma unroll
    for (int r = 0; r < 4; ++r) {
      int grow = rowbase + fm * 16 + lk * 4 + r;
      const float* vt = videos + (size_t)grow * VD_ + 2048;
      float t0 = vt[0], t1 = vt[1], t2 = vt[2], t3 = vt[3], t4 = vt[4];
      unsigned short* vob = vebf + (size_t)grow * 256;
#pragma unroll
      for (int fn = 0; fn < 2; ++fn) {
        int col = colbase + wid * 32 + fn * 16 + l16;
        float s2 = belv[fn] + t0 * w5[0][fn] + t1 * w5[1][fn] + t2 * w5[2][fn] +
                   t3 * w5[3][fn] + t4 * w5[4][fn];
        float vvv = fmaxf(acc[fm][fn][r] + bevv[fn], 0.f) + fmaxf(s2, 0.f);
        vob[col] = f2bf(vvv);
      }
    }
  }
}

// MFMA score kernel (unchanged, validated r5-r7)
__global__ __launch_bounds__(256) void k_score_bf(
    const unsigned short* __restrict__ vebf, const unsigned short* __restrict__ wsp1,
    const float* __restrict__ w_sp2, const float* __restrict__ wbs,
    const float* __restrict__ wbo, float* __restrict__ s_sub,
    float* __restrict__ s_obj) {
  __shared__ float reds[4][64], redo_[4][64];
  int tid = threadIdx.x;
  int rowbase = blockIdx.x * 64;
  int lane = tid & 63, wid = tid >> 6;
  int l16 = lane & 15, lk = lane >> 4;
  const unsigned short* ap[4];
  const unsigned short* bp[4];
#pragma unroll
  for (int fm = 0; fm < 4; ++fm)
    ap[fm] = vebf + (size_t)(rowbase + fm * 16 + l16) * 256 + lk * 8;
#pragma unroll
  for (int fn = 0; fn < 4; ++fn)
    bp[fn] = wsp1 + (size_t)(wid * 64 + fn * 16 + l16) * 256 + lk * 8;
  f32x4 acc[4][4] = {};
#pragma unroll 2
  for (int k0 = 0; k0 < 256; k0 += 32) {
    short8 a8[4], b8[4];
#pragma unroll
    for (int fm = 0; fm < 4; ++fm) a8[fm] = *(const short8*)(ap[fm] + k0);
#pragma unroll
    for (int fn = 0; fn < 4; ++fn) b8[fn] = *(const short8*)(bp[fn] + k0);
#pragma unroll
    for (int fm = 0; fm < 4; ++fm)
#pragma unroll
      for (int fn = 0; fn < 4; ++fn)
        acc[fm][fn] = __builtin_amdgcn_mfma_f32_16x16x32_bf16(
            a8[fm], b8[fn], acc[fm][fn], 0, 0, 0);
  }
  int b = rowbase / 4800;
  float w2[4], bs[4], bo[4];
#pragma unroll
  for (int fn = 0; fn < 4; ++fn) {
    int col = wid * 64 + fn * 16 + l16;
    w2[fn] = w_sp2[col];
    bs[fn] = wbs[b * 256 + col];
    bo[fn] = wbo[b * 256 + col];
  }
  float ps[4][4], po[4][4];
#pragma unroll
  for (int fm = 0; fm < 4; ++fm)
#pragma unroll
    for (int r = 0; r < 4; ++r) {
      float aps = 0, apo = 0;
#pragma unroll
      for (int fn = 0; fn < 4; ++fn) {
        float t = acc[fm][fn][r];
        aps += fast_tanh(t + bs[fn]) * w2[fn];
        apo += fast_tanh(t + bo[fn]) * w2[fn];
      }
      ps[fm][r] = aps;
      po[fm][r] = apo;
    }
#pragma unroll
  for (int m = 1; m < 16; m <<= 1) {
#pragma unroll
    for (int fm = 0; fm < 4; ++fm)
#pragma unroll
      for (int r = 0; r < 4; ++r) {
        ps[fm][r] += __shfl_xor(ps[fm][r], m);
        po[fm][r] += __shfl_xor(po[fm][r], m);
      }
  }
  if (l16 == 0) {
#pragma unroll
    for (int fm = 0; fm < 4; ++fm)
#pragma unroll
      for (int r = 0; r < 4; ++r) {
        int row = fm * 16 + lk * 4 + r;
        reds[wid][row] = ps[fm][r];
        redo_[wid][row] = po[fm][r];
      }
  }
  __syncthreads();
  if (tid < 64) {
    float s1 = reds[0][tid] + reds[1][tid] + reds[2][tid] + reds[3][tid];
    float s2 = redo_[0][tid] + redo_[1][tid] + redo_[2][tid] + redo_[3][tid];
    s_sub[rowbase + tid] = s1;
    s_obj[rowbase + tid] = s2;
  }
}

// attend from bf16 ve (unchanged, validated r6/r7)
__global__ __launch_bounds__(256) void k_attend_bf(
    const float* __restrict__ s_sub, const float* __restrict__ s_obj,
    const unsigned short* __restrict__ vebf, const float* __restrict__ W_s2o,
    const float* __restrict__ b_s2o, const float* __restrict__ W_o2s,
    const float* __restrict__ b_o2s, float* __restrict__ out_satt,
    float* __restrict__ out_oatt, float* __restrict__ orix) {
  int row = blockIdx.x;
  int tid = threadIdx.x;
  __shared__ float alds[2][40];
  int wv = tid >> 6, lane = tid & 63;
  if (wv < 2) {
    const float* sarr = (wv ? s_obj : s_sub) + row * 40;
    float v = (lane < 40) ? sarr[lane] : -1e30f;
    float mx = wredmax(v);
    float e = (lane < 40) ? __expf(v - mx) : 0.f;
    float sm = wredsum(e);
    float p = e / sm;
    if (lane < 40) {
      alds[wv][lane] = p;
      (wv ? out_oatt : out_satt)[row * 40 + lane] = p;
    }
  }
  __syncthreads();
  int e = tid;
  const unsigned short* vrow = vebf + (size_t)row * 40 * 256;
  float sf = 0, of = 0, s2o = b_s2o[e], o2s = b_o2s[e];
  for (int n = 0; n < 40; ++n) {
    float as = alds[0][n], aob = alds[1][n];
    float vv = bf2f(vrow[n * 256 + e]);
    sf += as * vv;
    of += aob * vv;
    s2o += as * W_s2o[n * 256 + e];
    o2s += aob * W_o2s[n * 256 + e];
  }
  s2o = fmaxf(s2o, 0.f);
  o2s = fmaxf(o2s, 0.f);
  orix[(size_t)row * 512 + e] = sf + o2s;
  orix[(size_t)row * 512 + 256 + e] = of + s2o;
}

// --------- fallback kernels (small-ws path, r6/r7-validated) -------
__global__ __launch_bounds__(256) void k_gemm_ve_mfma(
    const float* __restrict__ videos, const unsigned short* __restrict__ wtbf,
    const float* __restrict__ bev, const float* __restrict__ Wel,
    const float* __restrict__ bel, float* __restrict__ ve) {
  int tid = threadIdx.x;
  int rowbase = blockIdx.x * 64;
  int lane = tid & 63, wid = tid >> 6;
  int l16 = lane & 15, lk = lane >> 4;
  const float* ap[4];
  const unsigned short* bp[4];
#pragma unroll
  for (int fm = 0; fm < 4; ++fm)
    ap[fm] = videos + (size_t)(rowbase + fm * 16 + l16) * VD_ + lk * 8;
#pragma unroll
  for (int fn = 0; fn < 4; ++fn)
    bp[fn] = wtbf + (size_t)(wid * 64 + fn * 16 + l16) * 2048 + lk * 8;
  f32x4 acc[4][4] = {};
  for (int k0 = 0; k0 < 2048; k0 += 64) {
#pragma unroll
    for (int kk = 0; kk < 2; ++kk) {
      int ko = k0 + kk * 32;
      short8 a8[4], b8[4];
#pragma unroll
      for (int fm = 0; fm < 4; ++fm) {
        const float* a = ap[fm] + ko;
        float f[8];
#pragma unroll
        for (int j = 0; j < 8; ++j) f[j] = a[j];
        a8[fm] = mk8(f);
      }
#pragma unroll
      for (int fn = 0; fn < 4; ++fn) b8[fn] = *(const short8*)(bp[fn] + ko);
#pragma unroll
      for (int fm = 0; fm < 4; ++fm)
#pragma unroll
        for (int fn = 0; fn < 4; ++fn)
          acc[fm][fn] = __builtin_amdgcn_mfma_f32_16x16x32_bf16(
              a8[fm], b8[fn], acc[fm][fn], 0, 0, 0);
    }
    if ((k0 & 255) == 192) __builtin_amdgcn_s_barrier();
  }
  float bevv[4], belv[4], w5[5][4];
#pragma unroll
  for (int fn = 0; fn < 4; ++fn) {
    int col = wid * 64 + fn * 16 + l16;
    bevv[fn] = bev[col]; belv[fn] = bel[col];
#pragma unroll
    for (int kk = 0; kk < 5; ++kk) w5[kk][fn] = Wel[kk * 256 + col];
  }
#pragma unroll
  for (int fm = 0; fm < 4; ++fm) {
#pragma unroll
    for (int r = 0; r < 4; ++r) {
      int grow = rowbase + fm * 16 + lk * 4 + r;
      const float* vt = videos + (size_t)grow * VD_ + 2048;
      float t0 = vt[0], t1 = vt[1], t2 = vt[2], t3 = vt[3], t4 = vt[4];
      float* vo = ve + (size_t)grow * 256;
#pragma unroll
      for (int fn = 0; fn < 4; ++fn) {
        int col = wid * 64 + fn * 16 + l16;
        float s2 = belv[fn] + t0 * w5[0][fn] + t1 * w5[1][fn] + t2 * w5[2][fn] +
                   t3 * w5[3][fn] + t4 * w5[4][fn];
        vo[col] = fmaxf(acc[fm][fn][r] + bevv[fn], 0.f) + fmaxf(s2, 0.f);
      }
    }
  }
}

__global__ __launch_bounds__(256) void k_score(
    const float* __restrict__ ve, const float* __restrict__ W_sp1,
    const float* __restrict__ w_sp2, const float* __restrict__ wbs,
    const float* __restrict__ wbo, float* __restrict__ s_sub,
    float* __restrict__ s_obj) {
  __shared__ float vel[32][264];
  int tid = threadIdx.x;
  int rowbase = blockIdx.x * 32;
  for (int i = tid; i < 2048; i += 256) {
    int r = i >> 6, c = (i & 63) << 2;
    *(float4*)&vel[r][c] = *(const float4*)&ve[(size_t)(rowbase + r) * 256 + c];
  }
  __syncthreads();
  int wv = tid >> 6, lane = tid & 63;
  int r0 = wv * 8;
  float acc[8][4] = {};
  for (int k = 0; k < 256; ++k) {
    float w4[4];
#pragma unroll
    for (int c = 0; c < 4; ++c) w4[c] = W_sp1[(size_t)k * 256 + c * 64 + lane];
#pragma unroll
    for (int m = 0; m < 8; ++m) {
      float a = vel[r0 + m][k];
#pragma unroll
      for (int c = 0; c < 4; ++c) acc[m][c] += a * w4[c];
    }
  }
  int b = rowbase / 4800;
  float w2[4], bs[4], bo[4];
#pragma unroll
  for (int c = 0; c < 4; ++c) {
    int col = c * 64 + lane;
    w2[c] = w_sp2[col];
    bs[c] = wbs[b * 256 + col];
    bo[c] = wbo[b * 256 + col];
  }
#pragma unroll
  for (int m = 0; m < 8; ++m) {
    float ps = 0, po = 0;
#pragma unroll
    for (int c = 0; c < 4; ++c) {
      float t = acc[m][c];
      ps += fast_tanh(t + bs[c]) * w2[c];
      po += fast_tanh(t + bo[c]) * w2[c];
    }
    ps = wredsum(ps);
    po = wredsum(po);
    if (lane == 0) {
      s_sub[rowbase + r0 + m] = ps;
      s_obj[rowbase + r0 + m] = po;
    }
  }
}

__global__ __launch_bounds__(256) void k_attend(
    const float* __restrict__ s_sub, const float* __restrict__ s_obj,
    const float* __restrict__ ve, const float* __restrict__ W_s2o,
    const float* __restrict__ b_s2o, const float* __restrict__ W_o2s,
    const float* __restrict__ b_o2s, float* __restrict__ out_satt,
    float* __restrict__ out_oatt, float* __restrict__ orix) {
  int row = blockIdx.x;
  int tid = threadIdx.x;
  __shared__ float alds[2][40];
  int wv = tid >> 6, lane = tid & 63;
  if (wv < 2) {
    const float* sarr = (wv ? s_obj : s_sub) + row * 40;
    float v = (lane < 40) ? sarr[lane] : -1e30f;
    float mx = wredmax(v);
    float e = (lane < 40) ? __expf(v - mx) : 0.f;
    float sm = wredsum(e);
    float p = e / sm;
    if (lane < 40) {
      alds[wv][lane] = p;
      (wv ? out_oatt : out_satt)[row * 40 + lane] = p;
    }
  }
  __syncthreads();
  int e = tid;
  const float* vrow = ve + (size_t)row * 40 * 256;
  float sf = 0, of = 0, s2o = b_s2o[e], o2s = b_o2s[e];
  for (int n = 0; n < 40; ++n) {
    float as = alds[0][n], aob = alds[1][n];
    float vv = vrow[n * 256 + e];
    sf += as * vv;
    of += aob * vv;
    s2o += as * W_s2o[n * 256 + e];
    o2s += aob * W_o2s[n * 256 + e];
  }
  s2o = fmaxf(s2o, 0.f);
  o2s = fmaxf(o2s, 0.f);
  orix[(size_t)row * 512 + e] = sf + o2s;
  orix[(size_t)row * 512 + 256 + e] = of + s2o;
}

// Generic H-GEMM, LDS-free MFMA (unchanged)
__global__ __launch_bounds__(256) void k_gemm_h(
    const float* __restrict__ A, const unsigned short* __restrict__ WT,
    const float* __restrict__ b0, const float* __restrict__ b1,
    const float* __restrict__ b2, float* __restrict__ Cbase, int ntiles,
    int relu) {
  int tid = threadIdx.x;
  int bid = blockIdx.x;
  int mt = bid / ntiles, nt = bid - mt * ntiles;
  int rowbase = mt * 64;
  int lane = tid & 63, wid = tid >> 6;
  int wrow = wid >> 1, wcol = wid & 1;
  int l16 = lane & 15, lk = lane >> 4;
  const float* ap[2];
  const unsigned short* bp[2];
#pragma unroll
  for (int fm = 0; fm < 2; ++fm)
    ap[fm] = A + (size_t)(rowbase + wrow * 32 + fm * 16 + l16) * 512 + lk * 8;
#pragma unroll
  for (int fn = 0; fn < 2; ++fn)
    bp[fn] = WT + (size_t)(nt * 64 + wcol * 32 + fn * 16 + l16) * 512 + lk * 8;
  f32x4 acc[2][2] = {};
  for (int k0 = 0; k0 < 512; k0 += 64) {
#pragma unroll
    for (int kk = 0; kk < 2; ++kk) {
      int ko = k0 + kk * 32;
      short8 a8[2], b8[2];
#pragma unroll
      for (int fm = 0; fm < 2; ++fm) {
        float4 x = *(const float4*)(ap[fm] + ko);
        float4 y = *(const float4*)(ap[fm] + ko + 4);
        float f[8] = {x.x, x.y, x.z, x.w, y.x, y.y, y.z, y.w};
        a8[fm] = mk8(f);
      }
#pragma unroll
      for (int fn = 0; fn < 2; ++fn) b8[fn] = *(const short8*)(bp[fn] + ko);
#pragma unroll
      for (int fm = 0; fm < 2; ++fm)
#pragma unroll
        for (int fn = 0; fn < 2; ++fn)
          acc[fm][fn] = __builtin_amdgcn_mfma_f32_16x16x32_bf16(
              a8[fm], b8[fn], acc[fm][fn], 0, 0, 0);
    }
  }
#pragma unroll
  for (int fn = 0; fn < 2; ++fn) {
    int cg = nt * 64 + wcol * 32 + fn * 16 + l16;
    int third = cg >> 9, c = cg & 511;
    const float* bb = third == 0 ? b0 : (third == 1 ? b1 : b2);
    float bv = bb[c];
    float* outp = Cbase + (size_t)third * ((size_t)R_ * H_);
#pragma unroll
    for (int fm = 0; fm < 2; ++fm) {
#pragma unroll
      for (int r = 0; r < 4; ++r) {
        int grow = rowbase + wrow * 32 + fm * 16 + lk * 4 + r;
        float v = acc[fm][fn][r] + bv;
        if (relu) v = fmaxf(v, 0.f);
        outp[(size_t)grow * 512 + c] = v;
      }
    }
  }
}

// LSTM x-projection (unchanged)
__global__ __launch_bounds__(256) void k_xproj(
    const float* __restrict__ win, const unsigned short* __restrict__ wih,
    const float* __restrict__ b_ih, const float* __restrict__ b_hh,
    float* __restrict__ gx) {
  int bid = blockIdx.x;
  int mt = bid >> 5, nt = bid & 31;
  int tid = threadIdx.x;
  int lane = tid & 63, wid = tid >> 6;
  int wrow = wid >> 1, wcol = wid & 1;
  int l16 = lane & 15, lk = lane >> 4;
  const float* ap[2];
  bool av[2];
#pragma unroll
  for (int fm = 0; fm < 2; ++fm) {
    int base = mt * 64 + wrow * 32 + fm * 16;
    av[fm] = base < 80;
    int grow = base + l16;
    int s = grow >> 3, b = grow & 7;
    ap[fm] = av[fm] ? (win + (size_t)(b * 120 + 11 + 12 * s) * 512 + lk * 8)
                    : win;
  }
  const unsigned short* bp[2];
#pragma unroll
  for (int fn = 0; fn < 2; ++fn)
    bp[fn] = wih + (size_t)(nt * 64 + wcol * 32 + fn * 16 + l16) * 512 + lk * 8;
  f32x4 acc[2][2] = {};
  for (int k0 = 0; k0 < 512; k0 += 64) {
#pragma unroll
    for (int kk = 0; kk < 2; ++kk) {
      int ko = k0 + kk * 32;
      short8 a8[2], b8[2];
#pragma unroll
      for (int fm = 0; fm < 2; ++fm) {
        if (av[fm]) {
          float4 x = *(const float4*)(ap[fm] + ko);
          float4 y = *(const float4*)(ap[fm] + ko + 4);
          float f[8] = {x.x, x.y, x.z, x.w, y.x, y.y, y.z, y.w};
          a8[fm] = mk8(f);
        } else {
          a8[fm] = short8{0, 0, 0, 0, 0, 0, 0, 0};
        }
      }
#pragma unroll
      for (int fn = 0; fn < 2; ++fn) b8[fn] = *(const short8*)(bp[fn] + ko);
#pragma unroll
      for (int fm = 0; fm < 2; ++fm)
#pragma unroll
        for (int fn = 0; fn < 2; ++fn)
          acc[fm][fn] = __builtin_amdgcn_mfma_f32_16x16x32_bf16(
              a8[fm], b8[fn], acc[fm][fn], 0, 0, 0);
    }
  }
#pragma unroll
  for (int fn = 0; fn < 2; ++fn) {
    int cg = nt * 64 + wcol * 32 + fn * 16 + l16;
    float bv = b_ih[cg] + b_hh[cg];
#pragma unroll
    for (int fm = 0; fm < 2; ++fm) {
      if (!av[fm]) continue;
#pragma unroll
      for (int r = 0; r < 4; ++r) {
        int grow = mt * 64 + wrow * 32 + fm * 16 + lk * 4 + r;
        if (grow < 80) gx[(size_t)grow * 2048 + cg] = acc[fm][fn][r] + bv;
      }
    }
  }
}

// Persistent LSTM: all 10 steps in ONE launch. 32 blocks x 128 thr (all
// trivially co-resident on 256 CUs). Grid sync = device-scope release/acquire
// barrier on a counter zeroed each call by k_wprep (deterministic for graph
// replay). Per-step body identical to r6/r7-validated k_lstm_step. Epilogue
// folds k_hbias (final h is in h0 after step 9).
__global__ __launch_bounds__(128) void k_lstm_all(
    const unsigned short* __restrict__ whh, const float* __restrict__ gx,
    float* __restrict__ h0, float* __restrict__ h1, float* __restrict__ c_st,
    const float* __restrict__ W_l1, const float* __restrict__ b_l1,
    float* __restrict__ hb, unsigned int* __restrict__ bar) {
  int jb = blockIdx.x;
  int tid = threadIdx.x;
  int lane = tid & 63, kw = tid >> 6;
  int l16 = lane & 15, lk = lane >> 4;
  const unsigned short* bp[4];
#pragma unroll
  for (int fn = 0; fn < 4; ++fn)
    bp[fn] = whh + (size_t)(fn * 512 + jb * 16 + l16) * 512 + kw * 256 + lk * 8;
  __shared__ float part[4][64][4];
  for (int s = 0; s < 10; ++s) {
    const float* hin = (s & 1) ? h1 : h0;
    float* hout = (s & 1) ? h0 : h1;
    const float* ap = hin + (size_t)l16 * 512 + kw * 256 + lk * 8;
    f32x4 acc[4] = {};
    for (int k0 = 0; k0 < 256; k0 += 64) {
#pragma unroll
      for (int kk = 0; kk < 2; ++kk) {
        int ko = k0 + kk * 32;
        float4 x = *(const float4*)(ap + ko);
        float4 y = *(const float4*)(ap + ko + 4);
        float f[8] = {x.x, x.y, x.z, x.w, y.x, y.y, y.z, y.w};
        short8 a8 = mk8(f);
#pragma unroll
        for (int fn = 0; fn < 4; ++fn) {
          short8 b8 = *(const short8*)(bp[fn] + ko);
          acc[fn] = __builtin_amdgcn_mfma_f32_16x16x32_bf16(a8, b8, acc[fn], 0, 0, 0);
        }
      }
    }
    if (kw == 1) {
#pragma unroll
      for (int fn = 0; fn < 4; ++fn)
#pragma unroll
        for (int r = 0; r < 4; ++r) part[fn][lane][r] = acc[fn][r];
    }
    __syncthreads();
    if (kw == 0 && lk < 2) {
      int j = jb * 16 + l16;
#pragma unroll
      for (int r = 0; r < 4; ++r) {
        int b = lk * 4 + r;
        const float* g = gx + (size_t)(s * 8 + b) * 2048;
        float gi = acc[0][r] + part[0][lane][r] + g[j];
        float gf = acc[1][r] + part[1][lane][r] + g[512 + j];
        float gg = acc[2][r] + part[2][lane][r] + g[1024 + j];
        float go = acc[3][r] + part[3][lane][r] + g[1536 + j];
        float c = sigf(gf) * c_st[b * 512 + j] + sigf(gi) * fast_tanh(gg);
        c_st[b * 512 + j] = c;
        hout[b * 512 + j] = sigf(go) * fast_tanh(c);
      }
    }
    // ---- grid barrier (release/acquire, device scope) ----
    __syncthreads();      // writers' stores issued before any thread fences
    __threadfence();      // writers (among all threads) flush to device scope
    __syncthreads();
    if (tid == 0) {
      atomicAdd(bar, 1u);
      while (atomicAdd(bar, 0u) < 32u * (unsigned)(s + 1)) {}
    }
    __syncthreads();
    __threadfence();      // acquire: subsequent reads see other blocks' writes
  }
  // hbias epilogue: hb[b][j] = b_l1[j] + sum_i hT[b][i]*W_l1[512+i][j]
  int b = tid >> 4, j = jb * 16 + (tid & 15);
  float a = b_l1[j];
  const float* hr = h0 + b * 512;
  for (int i = 0; i < 512; ++i) a += hr[i] * W_l1[(size_t)(512 + i) * 512 + j];
  hb[b * 512 + j] = a;
}

// fallback LSTM step (small-ws path)
__global__ __launch_bounds__(128) void k_lstm_step(
    const float* __restrict__ hin, const unsigned short* __restrict__ whh,
    const float* __restrict__ gx, int s, float* __restrict__ hout,
    float* __restrict__ c_st) {
  int jb = blockIdx.x;
  int tid = threadIdx.x;
  int lane = tid & 63, kw = tid >> 6;
  int l16 = lane & 15, lk = lane >> 4;
  const float* ap = hin + (size_t)l16 * 512 + kw * 256 + lk * 8;
  const unsigned short* bp[4];
#pragma unroll
  for (int fn = 0; fn < 4; ++fn)
    bp[fn] = whh + (size_t)(fn * 512 + jb * 16 + l16) * 512 + kw * 256 + lk * 8;
  f32x4 acc[4] = {};
  for (int k0 = 0; k0 < 256; k0 += 64) {
#pragma unroll
    for (int kk = 0; kk < 2; ++kk) {
      int ko = k0 + kk * 32;
      float4 x = *(const float4*)(ap + ko);
      float4 y = *(const float4*)(ap + ko + 4);
      float f[8] = {x.x, x.y, x.z, x.w, y.x, y.y, y.z, y.w};
      short8 a8 = mk8(f);
#pragma unroll
      for (int fn = 0; fn < 4; ++fn) {
        short8 b8 = *(const short8*)(bp[fn] + ko);
        acc[fn] = __builtin_amdgcn_mfma_f32_16x16x32_bf16(a8, b8, acc[fn], 0, 0, 0);
      }
    }
  }
  __shared__ float part[4][64][4];
  if (kw == 1) {
#pragma unroll
    for (int fn = 0; fn < 4; ++fn)
#pragma unroll
      for (int r = 0; r < 4; ++r) part[fn][lane][r] = acc[fn][r];
  }
  __syncthreads();
  if (kw == 0 && lk < 2) {
    int j = jb * 16 + l16;
#pragma unroll
    for (int r = 0; r < 4; ++r) {
      int b = lk * 4 + r;
      const float* g = gx + (size_t)(s * 8 + b) * 2048;
      float gi = acc[0][r] + part[0][lane][r] + g[j];
      float gf = acc[1][r] + part[1][lane][r] + g[512 + j];
      float gg = acc[2][r] + part[2][lane][r] + g[1024 + j];
      float go = acc[3][r] + part[3][lane][r] + g[1536 + j];
      float c = sigf(gf) * c_st[b * 512 + j] + sigf(gi) * fast_tanh(gg);
      c_st[b * 512 + j] = c;
      hout[b * 512 + j] = sigf(go) * fast_tanh(c);
    }
  }
}

// MHA per (b,h,qc) (unchanged from r6/r7)
__global__ __launch_bounds__(256) void k_mha(const float* __restrict__ qb,
                                             const float* __restrict__ kb,
                                             const float* __restrict__ vb,
                                             float* __restrict__ ao) {
  int bh = blockIdx.x & 63, qc = blockIdx.x >> 6;
  int b = bh >> 3, h = bh & 7;
  __shared__ float ks[120 * 65];
  __shared__ float vs[120 * 65];
  __shared__ float ps[4][128];
  int tid = threadIdx.x;
  for (int i = 0; i < 30; ++i) {
    int idx = tid + 256 * i;
    int t = idx >> 6, d = idx & 63;
    size_t g = (size_t)(b * 120 + t) * 512 + h * 64 + d;
    ks[t * 65 + d] = kb[g];
    vs[t * 65 + d] = vb[g];
  }
  __syncthreads();
  int wv = tid >> 6, lane = tid & 63;
  for (int i = qc * 30 + wv; i < qc * 30 + 30; i += 4) {
    const float* qrow = qb + (size_t)(b * 120 + i) * 512 + h * 64;
    float s1 = 0, s2 = 0;
    for (int d = 0; d < 64; ++d) {
      float qd = qrow[d];
      s1 += qd * ks[lane * 65 + d];
      if (lane < 56) s2 += qd * ks[(lane + 64) * 65 + d];
    }
    s1 *= 0.125f;
    s2 *= 0.125f;
    if (lane >= 56) s2 = -1e30f;
    float mx = wredmax(fmaxf(s1, s2));
    float e1 = __expf(s1 - mx);
    float e2 = (lane < 56) ? __expf(s2 - mx) : 0.f;
    float sm = wredsum(e1 + e2);
    ps[wv][lane] = e1;
    ps[wv][64 + lane] = e2;
    float o = 0;
    for (int j = 0; j < 120; ++j) o += ps[wv][j] * vs[j * 65 + lane];
    ao[(size_t)(b * 120 + i) * 512 + h * 64 + lane] = o / sm;
  }
}

// LN with optional bf16 dual-write (for win -> winbf)
__global__ __launch_bounds__(256) void k_ln(const float* __restrict__ a,
                                            const float* __restrict__ bsrc,
                                            const float* __restrict__ g,
                                            const float* __restrict__ be,
                                            float* __restrict__ out,
                                            unsigned short* __restrict__ bfout) {
  int row = blockIdx.x * 4 + (threadIdx.x >> 6);
  int lane = threadIdx.x & 63;
  const float* pa = a + (size_t)row * 512;
  const float* pb = bsrc + (size_t)row * 512;
  float z[8];
  float s = 0;
#pragma unroll
  for (int ii = 0; ii < 8; ++ii) {
    int e = lane + 64 * ii;
    z[ii] = pa[e] + pb[e];
    s += z[ii];
  }
  float mean = wredsum(s) * (1.f / 512.f);
  float v = 0;
#pragma unroll
  for (int ii = 0; ii < 8; ++ii) {
    float d = z[ii] - mean;
    v += d * d;
  }
  float rstd = rsqrtf(wredsum(v) * (1.f / 512.f) + 1e-5f);
#pragma unroll
  for (int ii = 0; ii < 8; ++ii) {
    int e = lane + 64 * ii;
    float val = (z[ii] - mean) * rstd * g[e] + be[e];
    out[(size_t)row * 512 + e] = val;
    if (bfout) bfout[(size_t)row * 512 + e] = f2bf(val);
  }
}

__global__ __launch_bounds__(256) void k_hbias(const float* __restrict__ hT,
                                               const float* __restrict__ W_l1,
                                               const float* __restrict__ b_l1,
                                               float* __restrict__ hb) {
  int b = blockIdx.x >> 1, half = blockIdx.x & 1;
  int tid = threadIdx.x;
  __shared__ float hl[512];
  for (int i = tid; i < 512; i += 256) hl[i] = hT[b * 512 + i];
  __syncthreads();
  int j = half * 256 + tid;
  float a = b_l1[j];
  for (int i = 0; i < 512; ++i) a += hl[i] * W_l1[(size_t)(512 + i) * 512 + j];
  hb[b * 512 + j] = a;
}

__global__ __launch_bounds__(256) void k_beta2(
    const float* __restrict__ within, const float* __restrict__ W_tb1,
    const float* __restrict__ w_tb2, const float* __restrict__ tbias,
    float* __restrict__ z2) {
  int bid = blockIdx.x;
  int b = bid / 10, si = bid - b * 10;
  int trow = b * 120 + 11 + 12 * si;
  int tid = threadIdx.x;
  __shared__ float xr[512];
  __shared__ float red[256];
  for (int i = tid; i < 512; i += 256) xr[i] = within[(size_t)trow * 512 + i];
  __syncthreads();
  float val = 0;
  for (int jj = 0; jj < 2; ++jj) {
    int j = tid + jj * 256;
    float a = tbias[b * 512 + j];
    for (int i = 0; i < 512; ++i) a += xr[i] * W_tb1[(size_t)i * 512 + j];
    val += fast_tanh(a) * w_tb2[j];
  }
  red[tid] = val;
  __syncthreads();
  for (int s = 128; s; s >>= 1) {
    if (tid < s) red[tid] += red[tid + s];
    __syncthreads();
  }
  if (tid == 0) z2[bid] = red[0];
}

// MFMA beta1 (unchanged, validated r7)
__global__ __launch_bounds__(256) void k_beta1_bf(
    const unsigned short* __restrict__ winbf, const unsigned short* __restrict__ wl1bf,
    const float* __restrict__ w_l2, const float* __restrict__ hb,
    float* __restrict__ l1) {
  __shared__ float reds[4][64];
  int tid = threadIdx.x;
  int rowbase = blockIdx.x * 64;  // 15 blocks
  int lane = tid & 63, wid = tid >> 6;
  int l16 = lane & 15, lk = lane >> 4;
  const unsigned short* ap[4];
#pragma unroll
  for (int fm = 0; fm < 4; ++fm)
    ap[fm] = winbf + (size_t)(rowbase + fm * 16 + l16) * 512 + lk * 8;
  float ps[4][4] = {};
#pragma unroll
  for (int cs = 0; cs < 2; ++cs) {
    const unsigned short* bp[4];
#pragma unroll
    for (int fn = 0; fn < 4; ++fn)
      bp[fn] = wl1bf + (size_t)(cs * 256 + wid * 64 + fn * 16 + l16) * 512 + lk * 8;
    f32x4 acc[4][4] = {};
    for (int k0 = 0; k0 < 512; k0 += 32) {
      short8 a8[4], b8[4];
#pragma unroll
      for (int fm = 0; fm < 4; ++fm) a8[fm] = *(const short8*)(ap[fm] + k0);
#pragma unroll
      for (int fn = 0; fn < 4; ++fn) b8[fn] = *(const short8*)(bp[fn] + k0);
#pragma unroll
      for (int fm = 0; fm < 4; ++fm)
#pragma unroll
        for (int fn = 0; fn < 4; ++fn)
          acc[fm][fn] = __builtin_amdgcn_mfma_f32_16x16x32_bf16(
              a8[fm], b8[fn], acc[fm][fn], 0, 0, 0);
    }
#pragma unroll
    for (int fm = 0; fm < 4; ++fm)
#pragma unroll
      for (int r = 0; r < 4; ++r) {
        int grow = rowbase + fm * 16 + lk * 4 + r;
        int b = grow / 120;
#pragma unroll
        for (int fn = 0; fn < 4; ++fn) {
          int col = cs * 256 + wid * 64 + fn * 16 + l16;
          ps[fm][r] += fast_tanh(acc[fm][fn][r] + hb[b * 512 + col]) * w_l2[col];
        }
      }
  }
#pragma unroll
  for (int m = 1; m < 16; m <<= 1)
#pragma unroll
    for (int fm = 0; fm < 4; ++fm)
#pragma unroll
      for (int r = 0; r < 4; ++r) ps[fm][r] += __shfl_xor(ps[fm][r], m);
  if (l16 == 0) {
#pragma unroll
    for (int fm = 0; fm < 4; ++fm)
#pragma unroll
      for (int r = 0; r < 4; ++r) reds[wid][fm * 16 + lk * 4 + r] = ps[fm][r];
  }
  __syncthreads();
  if (tid < 64)
    l1[rowbase + tid] = reds[0][tid] + reds[1][tid] + reds[2][tid] + reds[3][tid];
}

// fallback fp32 beta1
__global__ __launch_bounds__(256) void k_beta1(
    const float* __restrict__ within, const float* __restrict__ W_l1,
    const float* __restrict__ w_l2, const float* __restrict__ hb,
    float* __restrict__ l1) {
  int bid = blockIdx.x;
  int r0 = bid * 4;
  int b = r0 / 120;
  int tid = threadIdx.x;
  __shared__ float xr[4][512];
  __shared__ float red[4][256];
  for (int i = tid; i < 2048; i += 256) xr[i >> 9][i & 511] = within[(size_t)r0 * 512 + i];
  __syncthreads();
  float v[4] = {0, 0, 0, 0};
  for (int jj = 0; jj < 2; ++jj) {
    int j = tid + jj * 256;
    float hbv = hb[b * 512 + j];
    float a0 = hbv, a1 = hbv, a2 = hbv, a3 = hbv;
    for (int i = 0; i < 512; ++i) {
      float ww = W_l1[(size_t)i * 512 + j];
      a0 += xr[0][i] * ww;
      a1 += xr[1][i] * ww;
      a2 += xr[2][i] * ww;
      a3 += xr[3][i] * ww;
    }
    float wl = w_l2[j];
    v[0] += fast_tanh(a0) * wl;
    v[1] += fast_tanh(a1) * wl;
    v[2] += fast_tanh(a2) * wl;
    v[3] += fast_tanh(a3) * wl;
  }
#pragma unroll
  for (int r = 0; r < 4; ++r) red[r][tid] = v[r];
  __syncthreads();
  for (int s = 128; s; s >>= 1) {
    if (tid < s)
      for (int r = 0; r < 4; ++r) red[r][tid] += red[r][tid + s];
    __syncthreads();
  }
  if (tid < 4) l1[r0 + tid] = red[tid][0];
}

__global__ __launch_bounds__(256) void k_final(
    const float* __restrict__ l1, const float* __restrict__ z2,
    const float* __restrict__ within, const float* __restrict__ hT,
    const float* __restrict__ cT, float* __restrict__ dout) {
  int b = blockIdx.x;
  int tid = threadIdx.x;
  __shared__ float temp[120];
  __shared__ float b2[10];
  int wv = tid >> 6, lane = tid & 63;
  if (wv == 1) {
    float v = (lane < 10) ? z2[b * 10 + lane] : -1e30f;
    float mx = wredmax(v);
    float e = (lane < 10) ? __expf(v - mx) : 0.f;
    float sm = wredsum(e);
    if (lane < 10) {
      float p = e / sm;
      b2[lane] = p;
      dout[O_B2 + b * 10 + lane] = p;
    }
  }
  if (wv == 0) {
    float v1 = l1[b * 120 + lane];
    float v2 = (lane + 64 < 120) ? l1[b * 120 + 64 + lane] : -1e30f;
    float mx = wredmax(fmaxf(v1, v2));
    float e1 = __expf(v1 - mx);
    float e2 = (lane + 64 < 120) ? __expf(v2 - mx) : 0.f;
    float sm = wredsum(e1 + e2);
    float p1 = e1 / sm;
    dout[O_B1 + b * 120 + lane] = p1;
    temp[lane] = p1;
    if (lane + 64 < 120) {
      float p2 = e2 / sm;
      dout[O_B1 + b * 120 + 64 + lane] = p2;
      temp[64 + lane] = p2;
    }
  }
  __syncthreads();
  for (int t = tid; t < 120; t += 256) temp[t] += b2[t / 12];
  __syncthreads();
  for (int hh = tid; hh < 512; hh += 256) {
    float o = 0;
    for (int t = 0; t < 120; ++t) o += temp[t] * within[(size_t)(b * 120 + t) * 512 + hh];
    dout[O_OUT + b * 512 + hh] = o;
    dout[O_HT + b * 512 + hh] = hT[b * 512 + hh];
    dout[O_CT + b * 512 + hh] = cT[b * 512 + hh];
  }
}

// ---------------------------------------------------------------
extern "C" void kernel_launch(void* const* d_in, const int* in_sizes, int n_in,
                              void* d_out, int out_size, void* d_ws, size_t ws_size,
                              hipStream_t stream) {
  const float* videos = (const float*)d_in[0];
  const float* sub_g  = (const float*)d_in[1];
  const float* obj_g  = (const float*)d_in[2];
  const float* W_ev   = (const float*)d_in[3];
  const float* b_ev   = (const float*)d_in[4];
  const float* W_el   = (const float*)d_in[5];
  const float* b_el   = (const float*)d_in[6];
  const float* W_ew   = (const float*)d_in[7];
  const float* b_ew   = (const float*)d_in[8];
  const float* W_sp1  = (const float*)d_in[9];
  const float* b_sp1  = (const float*)d_in[10];
  const float* w_sp2  = (const float*)d_in[11];
  const float* W_s2o  = (const float*)d_in[12];
  const float* b_s2o  = (const float*)d_in[13];
  const float* W_o2s  = (const float*)d_in[14];
  const float* b_o2s  = (const float*)d_in[15];
  const float* W_tv   = (const float*)d_in[16];
  const float* b_tv   = (const float*)d_in[17];
  const float* Wq     = (const float*)d_in[18];
  const float* bq     = (const float*)d_in[19];
  const float* Wk     = (const float*)d_in[20];
  const float* bk     = (const float*)d_in[21];
  const float* Wv     = (const float*)d_in[22];
  const float* bv     = (const float*)d_in[23];
  const float* Wo     = (const float*)d_in[24];
  const float* bo     = (const float*)d_in[25];
  const float* g1     = (const float*)d_in[26];
  const float* be1    = (const float*)d_in[27];
  const float* Wf1    = (const float*)d_in[28];
  const float* bf1    = (const float*)d_in[29];
  const float* Wf2    = (const float*)d_in[30];
  const float* bf2    = (const float*)d_in[31];
  const float* g2     = (const float*)d_in[32];
  const float* be2    = (const float*)d_in[33];
  const float* W_tr   = (const float*)d_in[34];
  const float* b_tr   = (const float*)d_in[35];
  const float* W_tb1  = (const float*)d_in[36];
  const float* b_tb1  = (const float*)d_in[37];
  const float* w_tb2  = (const float*)d_in[38];
  const float* W_ih   = (const float*)d_in[39];
  const float* W_hh   = (const float*)d_in[40];
  const float* b_ih   = (const float*)d_in[41];
  const float* b_hh   = (const float*)d_in[42];
  const float* W_l1   = (const float*)d_in[43];
  const float* b_l1   = (const float*)d_in[44];
  const float* w_l2   = (const float*)d_in[45];

  float* out = (float*)d_out;
  float* w = (float*)d_ws;

  float* ve_p   = w + OFF_VE;
  float* ssub_p = w + OFF_SSUB;
  float* sobj_p = w + OFF_SOBJ;
  float* wbs_p  = w + OFF_WBS;
  float* wbo_p  = w + OFF_WBO;
  float* tb_p   = w + OFF_TBIAS;
  float* orix_p = w + OFF_ORIX;
  float* x_p    = w + OFF_X;
  float* q_p    = w + OFF_Q;
  float* k_p    = w + OFF_K;
  float* v_p    = w + OFF_V;
  float* ao_p   = w + OFF_AO;
  float* attn_p = w + OFF_ATTN;
  float* x1_p   = w + OFF_X1;
  float* f1_p   = w + OFF_F1;
  float* f2_p   = w + OFF_F2;
  float* win_p  = w + OFF_WIN;
  float* z2_p   = w + OFF_Z2;
  float* h_p    = w + OFF_H0;           // h0[4096], h1[4096], c[4096]
  float* c_p    = h_p + 2 * 4096;
  float* hb_p   = w + OFF_HB;
  float* l1_p   = w + OFF_L1;
  unsigned int* bar_p = (unsigned int*)(w + OFF_BAR);

  unsigned short* wtbase = (unsigned short*)(w + OFF_WT);
  unsigned short* wevbf = wtbase;                    // [256][2048]
  unsigned short* w7bf  = wtbase + 524288;           // 7 x [512][512]
  unsigned short* wtvbf = w7bf;
  unsigned short* wqbf  = w7bf + 1 * 262144;
  unsigned short* wobf  = w7bf + 4 * 262144;
  unsigned short* wf1bf = w7bf + 5 * 262144;
  unsigned short* wf2bf = w7bf + 6 * 262144;
  unsigned short* wsp1bf = w7bf + 7 * 262144;        // [256][256]
  // big-path dedicated buffers
  unsigned short* wihbf  = (unsigned short*)(w + OFF_WIH);
  unsigned short* whhbf  = (unsigned short*)(w + OFF_WHH);
  unsigned short* wl1bf  = (unsigned short*)(w + OFF_WL1B);
  unsigned short* winbf_p = (unsigned short*)(w + OFF_WINBF);
  unsigned short* vebf_p = (unsigned short*)(w + OFF_VEBF);
  float* gx_p = w + OFF_Q;  // aliases dead Q (written post-mha by k_xproj)
  const bool big = ws_size >= (size_t)OFF_END * 4;

  if (big) {
    k_wprep<<<1681, 256, 0, stream>>>(W_ev, W_tv, Wq, Wk, Wv, Wo, Wf1, Wf2,
                                      W_sp1, W_l1, W_ih, W_hh, wevbf, w7bf,
                                      wsp1bf, wl1bf, wihbf, whhbf, h_p, bar_p);
    k_small0<<<8, 256, 0, stream>>>(sub_g, obj_g, W_ew, b_ew, W_sp1, b_sp1,
                                    W_tr, b_tr, W_tb1, b_tb1, wbs_p, wbo_p, tb_p);
    k_gemm_ve_m97<<<1200, 256, 0, stream>>>(videos, wevbf, b_ev, W_el, b_el,
                                            vebf_p);
    k_score_bf<<<600, 256, 0, stream>>>(vebf_p, wsp1bf, w_sp2, wbs_p, wbo_p,
                                        ssub_p, sobj_p);
    k_attend_bf<<<960, 256, 0, stream>>>(ssub_p, sobj_p, vebf_p, W_s2o, b_s2o,
                                         W_o2s, b_o2s, out + O_SATT,
                                         out + O_OATT, orix_p);
    k_gemm_h<<<120, 256, 0, stream>>>(orix_p, wtvbf, b_tv, b_tv, b_tv, x_p, 8, 1);
    k_gemm_h<<<360, 256, 0, stream>>>(x_p, wqbf, bq, bk, bv, q_p, 24, 0);
    k_mha<<<256, 256, 0, stream>>>(q_p, k_p, v_p, ao_p);
    k_gemm_h<<<120, 256, 0, stream>>>(ao_p, wobf, bo, bo, bo, attn_p, 8, 0);
    k_ln<<<240, 256, 0, stream>>>(x_p, attn_p, g1, be1, x1_p, nullptr);
    k_gemm_h<<<120, 256, 0, stream>>>(x1_p, wf1bf, bf1, bf1, bf1, f1_p, 8, 1);
    k_gemm_h<<<120, 256, 0, stream>>>(f1_p, wf2bf, bf2, bf2, bf2, f2_p, 8, 0);
    k_ln<<<240, 256, 0, stream>>>(x1_p, f2_p, g2, be2, win_p, winbf_p);
    k_xproj<<<64, 256, 0, stream>>>(win_p, wihbf, b_ih, b_hh, gx_p);
    k_beta2<<<80, 256, 0, stream>>>(win_p, W_tb1, w_tb2, tb_p, z2_p);
    k_lstm_all<<<32, 128, 0, stream>>>(whhbf, gx_p, h_p, h_p + 4096, c_p,
                                       W_l1, b_l1, hb_p, bar_p);
    k_beta1_bf<<<15, 256, 0, stream>>>(winbf_p, wl1bf, w_l2, hb_p, l1_p);
    k_final<<<8, 256, 0, stream>>>(l1_p, z2_p, win_p, h_p, c_p, out);
  } else {
    // fallback (r6/r7-validated small-ws path)
    unsigned short* wihbf_a = (unsigned short*)(w + OFF_Q + 163840);
    unsigned short* whhbf_a = (unsigned short*)(w + OFF_Q + 688128);
    k_zero<<<48, 256, 0, stream>>>(h_p, 3 * 4096);
    k_small0<<<8, 256, 0, stream>>>(sub_g, obj_g, W_ew, b_ew, W_sp1, b_sp1,
                                    W_tr, b_tr, W_tb1, b_tb1, wbs_p, wbo_p, tb_p);
    k_wconvT<<<128, 256, 0, stream>>>(W_ev, wevbf, 2048, 256);
    k_wconv7<<<448, 256, 0, stream>>>(W_tv, Wq, Wk, Wv, Wo, Wf1, Wf2, w7bf);
    k_gemm_ve_mfma<<<600, 256, 0, stream>>>(videos, wevbf, b_ev, W_el, b_el, ve_p);
    k_score<<<1200, 256, 0, stream>>>(ve_p, W_sp1, w_sp2, wbs_p, wbo_p, ssub_p, sobj_p);
    k_attend<<<960, 256, 0, stream>>>(ssub_p, sobj_p, ve_p, W_s2o, b_s2o, W_o2s,
                                      b_o2s, out + O_SATT, out + O_OATT, orix_p);
    k_gemm_h<<<120, 256, 0, stream>>>(orix_p, wtvbf, b_tv, b_tv, b_tv, x_p, 8, 1);
    k_gemm_h<<<360, 256, 0, stream>>>(x_p, wqbf, bq, bk, bv, q_p, 24, 0);
    k_mha<<<256, 256, 0, stream>>>(q_p, k_p, v_p, ao_p);
    k_gemm_h<<<120, 256, 0, stream>>>(ao_p, wobf, bo, bo, bo, attn_p, 8, 0);
    k_ln<<<240, 256, 0, stream>>>(x_p, attn_p, g1, be1, x1_p, nullptr);
    k_gemm_h<<<120, 256, 0, stream>>>(x1_p, wf1bf, bf1, bf1, bf1, f1_p, 8, 1);
    k_gemm_h<<<120, 256, 0, stream>>>(f1_p, wf2bf, bf2, bf2, bf2, f2_p, 8, 0);
    k_ln<<<240, 256, 0, stream>>>(x1_p, f2_p, g2, be2, win_p, nullptr);
    k_cvt2<<<1024, 256, 0, stream>>>(W_ih, W_hh, wihbf_a, whhbf_a);
    k_xproj<<<64, 256, 0, stream>>>(win_p, wihbf_a, b_ih, b_hh, gx_p);
    k_beta2<<<80, 256, 0, stream>>>(win_p, W_tb1, w_tb2, tb_p, z2_p);
    for (int s = 0; s < 10; ++s) {
      float* hin = h_p + (s & 1) * 4096;
      float* hout = h_p + ((s & 1) ^ 1) * 4096;
      k_lstm_step<<<32, 128, 0, stream>>>(hin, whhbf_a, gx_p, s, hout, c_p);
    }
    k_hbias<<<16, 256, 0, stream>>>(h_p, W_l1, b_l1, hb_p);
    k_beta1<<<240, 256, 0, stream>>>(win_p, W_l1, w_l2, hb_p, l1_p);
    k_final<<<8, 256, 0, stream>>>(l1_p, z2_p, win_p, h_p, c_p, out);
  }
}

// Round 9
// 697.338 us; speedup vs baseline: 1.0166x; 1.0166x over previous
//
#include <hip/hip_runtime.h>
#include <cstddef>
#include <cstdint>

#define B_ 8
#define T_ 120
#define NB_ 40
#define VD_ 2053
#define E_ 256
#define H_ 512
#define M_ 38400   // B*T*NB
#define R_ 960     // B*T

// ---------------- workspace layout (float offsets) ----------------
static constexpr size_t OFF_VE    = 0;                        // 38400*256 (fallback path only)
static constexpr size_t OFF_SSUB  = OFF_VE + (size_t)M_ * E_; // 38400
static constexpr size_t OFF_SOBJ  = OFF_SSUB + M_;
static constexpr size_t OFF_WBS   = OFF_SOBJ + M_;            // 8*256
static constexpr size_t OFF_WBO   = OFF_WBS + B_ * E_;
static constexpr size_t OFF_TBIAS = OFF_WBO + B_ * E_;        // 8*512
static constexpr size_t OFF_ORIX  = OFF_TBIAS + B_ * H_;      // 960*512 each below
static constexpr size_t OFF_X     = OFF_ORIX + (size_t)R_ * H_;
static constexpr size_t OFF_Q     = OFF_X    + (size_t)R_ * H_;
static constexpr size_t OFF_K     = OFF_Q    + (size_t)R_ * H_;
static constexpr size_t OFF_V     = OFF_K    + (size_t)R_ * H_;
static constexpr size_t OFF_AO    = OFF_V    + (size_t)R_ * H_;
static constexpr size_t OFF_ATTN  = OFF_AO   + (size_t)R_ * H_;
static constexpr size_t OFF_X1    = OFF_ATTN + (size_t)R_ * H_;
static constexpr size_t OFF_F1    = OFF_X1   + (size_t)R_ * H_;
static constexpr size_t OFF_F2    = OFF_F1   + (size_t)R_ * H_;
static constexpr size_t OFF_WIN   = OFF_F2   + (size_t)R_ * H_;
static constexpr size_t OFF_WT    = OFF_WIN  + (size_t)R_ * H_; // 2M floats (bf16 weights)
static constexpr size_t OFF_Z2    = OFF_WT + (size_t)1024 * 2048; // 80
static constexpr size_t OFF_H0    = OFF_Z2 + 128;               // h0,h1,c : 3*4096
static constexpr size_t OFF_HB    = OFF_H0 + 3 * 4096;          // 8*512
static constexpr size_t OFF_L1    = OFF_HB + B_ * H_;           // 960
static constexpr size_t OFF_BAR   = OFF_L1 + 960;               // 1 uint (grid barrier)
static constexpr size_t OFF_END0  = OFF_BAR + 4;
// big-ws region (dedicated, non-aliased)
static constexpr size_t OFF_WIH   = (OFF_END0 + 3) & ~(size_t)3;     // 2048*512 ushort
static constexpr size_t OFF_WHH   = OFF_WIH + 524288;
static constexpr size_t OFF_WL1B  = OFF_WHH + 524288;                // 512*512 ushort
static constexpr size_t OFF_WINBF = OFF_WL1B + 131072;               // 960*512 ushort
static constexpr size_t OFF_VEBF  = OFF_WINBF + 245760;              // M*E ushort
static constexpr size_t OFF_END   = OFF_VEBF + (size_t)M_ * E_ / 2;  // ~23.8M floats

// ---------------- d_out layout (float offsets) ----------------
static constexpr size_t O_OUT  = 0;      // 8*512
static constexpr size_t O_HT   = 4096;   // 8*512
static constexpr size_t O_CT   = 8192;   // 8*512
static constexpr size_t O_SATT = 12288;  // 8*120*40
static constexpr size_t O_OATT = 50688;  // 8*120*40
static constexpr size_t O_B1   = 89088;  // 8*120
static constexpr size_t O_B2   = 90048;  // 8*10

#define DEVFN __device__ __forceinline__

typedef __attribute__((ext_vector_type(8))) short short8;
typedef __attribute__((ext_vector_type(4))) float f32x4;

DEVFN float sigf(float x) { return 1.0f / (1.0f + __expf(-x)); }

// inline tanh: no OCML call (round-1 lesson: tanhf caused VGPR spill disaster)
DEVFN float fast_tanh(float x) {
  float e = __expf(2.f * x);
  return 1.f - 2.f / (e + 1.f);
}

// fp32 -> bf16 RNE (validated r3)
DEVFN unsigned short f2bf(float x) {
  unsigned int u = __float_as_uint(x);
  u += 0x7FFFu + ((u >> 16) & 1u);
  return (unsigned short)(u >> 16);
}
DEVFN float bf2f(unsigned short u) { return __uint_as_float((unsigned int)u << 16); }

DEVFN short8 mk8(const float* f) {
  short8 r;
#pragma unroll
  for (int j = 0; j < 8; ++j) r[j] = (short)f2bf(f[j]);
  return r;
}

DEVFN float wredsum(float v) {
#pragma unroll
  for (int m = 32; m; m >>= 1) v += __shfl_xor(v, m);
  return v;
}
DEVFN float wredmax(float v) {
#pragma unroll
  for (int m = 32; m; m >>= 1) v = fmaxf(v, __shfl_xor(v, m));
  return v;
}

// ---------------------------------------------------------------
__global__ __launch_bounds__(256) void k_zero(float* p, int n) {
  int i = blockIdx.x * 256 + threadIdx.x;
  if (i < n) p[i] = 0.f;
}

// Per-batch small precompute (standalone, fallback path)
__global__ __launch_bounds__(256) void k_small0(
    const float* __restrict__ sub_g, const float* __restrict__ obj_g,
    const float* __restrict__ W_ew, const float* __restrict__ b_ew,
    const float* __restrict__ W_sp1, const float* __restrict__ b_sp1,
    const float* __restrict__ W_tr, const float* __restrict__ b_tr,
    const float* __restrict__ W_tb1, const float* __restrict__ b_tb1,
    float* __restrict__ wbs, float* __restrict__ wbo, float* __restrict__ tbias) {
  int b = blockIdx.x, tid = threadIdx.x;
  __shared__ float sg[300], og[300], se[256], oe[256], trl[512];
  for (int i = tid; i < 300; i += 256) { sg[i] = sub_g[b * 300 + i]; og[i] = obj_g[b * 300 + i]; }
  __syncthreads();
  {
    float a1 = b_ew[tid], a2 = a1;
    for (int w = 0; w < 300; ++w) {
      float we = W_ew[w * 256 + tid];
      a1 += sg[w] * we; a2 += og[w] * we;
    }
    se[tid] = fmaxf(a1, 0.f); oe[tid] = fmaxf(a2, 0.f);
  }
  __syncthreads();
  {
    float a1 = b_sp1[tid], a2 = a1;
    for (int e = 0; e < 256; ++e) {
      float ww = W_sp1[(256 + e) * 256 + tid];
      a1 += se[e] * ww; a2 += oe[e] * ww;
    }
    wbs[b * 256 + tid] = a1; wbo[b * 256 + tid] = a2;
  }
  for (int jj = 0; jj < 2; ++jj) {
    int j = tid + jj * 256;
    float a = b_tr[j];
    for (int i = 0; i < 256; ++i) a += se[i] * W_tr[i * 512 + j];
    for (int i = 0; i < 256; ++i) a += oe[i] * W_tr[(256 + i) * 512 + j];
    trl[j] = fmaxf(a, 0.f);
  }
  __syncthreads();
  for (int jj = 0; jj < 2; ++jj) {
    int j = tid + jj * 256;
    float a = b_tb1[j];
    for (int i = 0; i < 512; ++i) a += trl[i] * W_tb1[(size_t)(512 + i) * 512 + j];
    tbias[b * 512 + j] = a;
  }
}

// Unified prep kernel (big path): all weight converts + h/c/bar zero + the
// 8 small0 blocks (independent work, hidden under the 1681 convert blocks).
// Grid 1689.
__global__ __launch_bounds__(256) void k_wprep(
    const float* __restrict__ W_ev, const float* __restrict__ W_tv,
    const float* __restrict__ Wq, const float* __restrict__ Wk,
    const float* __restrict__ Wv, const float* __restrict__ Wo,
    const float* __restrict__ Wf1, const float* __restrict__ Wf2,
    const float* __restrict__ W_sp1, const float* __restrict__ W_l1,
    const float* __restrict__ W_ih, const float* __restrict__ W_hh,
    const float* __restrict__ sub_g, const float* __restrict__ obj_g,
    const float* __restrict__ W_ew, const float* __restrict__ b_ew,
    const float* __restrict__ b_sp1, const float* __restrict__ W_tr,
    const float* __restrict__ b_tr, const float* __restrict__ W_tb1,
    const float* __restrict__ b_tb1,
    unsigned short* __restrict__ wevbf, unsigned short* __restrict__ w7bf,
    unsigned short* __restrict__ wsp1bf, unsigned short* __restrict__ wl1bf,
    unsigned short* __restrict__ wihbf, unsigned short* __restrict__ whhbf,
    float* __restrict__ hz, unsigned int* __restrict__ bar,
    float* __restrict__ wbs, float* __restrict__ wbo, float* __restrict__ tbias) {
  int bid = blockIdx.x, tid = threadIdx.x;
  __shared__ float shm[64 * 65];
  float (*t)[65] = (float(*)[65])shm;
  if (bid < 128) {
    int kb = bid >> 2, nb = bid & 3;
#pragma unroll
    for (int i = 0; i < 16; ++i) {
      int idx = tid + 256 * i; int r = idx >> 6, c = idx & 63;
      t[r][c] = W_ev[(size_t)(kb * 64 + r) * 256 + nb * 64 + c];
    }
    __syncthreads();
#pragma unroll
    for (int i = 0; i < 16; ++i) {
      int idx = tid + 256 * i; int n = idx >> 6, kk = idx & 63;
      wevbf[(size_t)(nb * 64 + n) * 2048 + kb * 64 + kk] = f2bf(t[kk][n]);
    }
  } else if (bid < 576) {
    int b2 = bid - 128;
    int wsel = b2 >> 6, sub = b2 & 63;
    int kb = sub >> 3, nb = sub & 7;
    const float* src = wsel == 0 ? W_tv : wsel == 1 ? Wq : wsel == 2 ? Wk
                     : wsel == 3 ? Wv : wsel == 4 ? Wo : wsel == 5 ? Wf1 : Wf2;
    unsigned short* dst = w7bf + (size_t)wsel * 262144;
#pragma unroll
    for (int i = 0; i < 16; ++i) {
      int idx = tid + 256 * i; int r = idx >> 6, c = idx & 63;
      t[r][c] = src[(size_t)(kb * 64 + r) * 512 + nb * 64 + c];
    }
    __syncthreads();
#pragma unroll
    for (int i = 0; i < 16; ++i) {
      int idx = tid + 256 * i; int n = idx >> 6, kk = idx & 63;
      dst[(size_t)(nb * 64 + n) * 512 + kb * 64 + kk] = f2bf(t[kk][n]);
    }
  } else if (bid < 592) {
    int b2 = bid - 576;
    int kb = b2 >> 2, nb = b2 & 3;
#pragma unroll
    for (int i = 0; i < 16; ++i) {
      int idx = tid + 256 * i; int r = idx >> 6, c = idx & 63;
      t[r][c] = W_sp1[(size_t)(kb * 64 + r) * 256 + nb * 64 + c];
    }
    __syncthreads();
#pragma unroll
    for (int i = 0; i < 16; ++i) {
      int idx = tid + 256 * i; int n = idx >> 6, kk = idx & 63;
      wsp1bf[(size_t)(nb * 64 + n) * 256 + kb * 64 + kk] = f2bf(t[kk][n]);
    }
  } else if (bid < 656) {
    int b2 = bid - 592;
    int kb = b2 >> 3, nb = b2 & 7;
#pragma unroll
    for (int i = 0; i < 16; ++i) {
      int idx = tid + 256 * i; int r = idx >> 6, c = idx & 63;
      t[r][c] = W_l1[(size_t)(kb * 64 + r) * 512 + nb * 64 + c];  // rows 0..511
    }
    __syncthreads();
#pragma unroll
    for (int i = 0; i < 16; ++i) {
      int idx = tid + 256 * i; int n = idx >> 6, kk = idx & 63;
      wl1bf[(size_t)(nb * 64 + n) * 512 + kb * 64 + kk] = f2bf(t[kk][n]);
    }
  } else if (bid < 1680) {
    int i = (bid - 656) * 256 + tid;
    const float* s; unsigned short* d; int off;
    if (i < 131072) { s = W_ih; d = wihbf; off = i * 8; }
    else            { s = W_hh; d = whhbf; off = (i - 131072) * 8; }
    float f[8];
#pragma unroll
    for (int j = 0; j < 8; ++j) f[j] = s[off + j];
    *(short8*)(d + off) = mk8(f);
  } else if (bid == 1680) {
    for (int i = tid; i < 12288; i += 256) hz[i] = 0.f;
    if (tid == 0) *bar = 0u;
  } else {
    // small0 body, b = bid - 1681 (8 blocks)
    int b = bid - 1681;
    float* sg = shm;         // 300
    float* og = shm + 300;   // 300
    float* se = shm + 600;   // 256
    float* oe = shm + 856;   // 256
    float* trl = shm + 1112; // 512
    for (int i = tid; i < 300; i += 256) { sg[i] = sub_g[b * 300 + i]; og[i] = obj_g[b * 300 + i]; }
    __syncthreads();
    {
      float a1 = b_ew[tid], a2 = a1;
      for (int w = 0; w < 300; ++w) {
        float we = W_ew[w * 256 + tid];
        a1 += sg[w] * we; a2 += og[w] * we;
      }
      se[tid] = fmaxf(a1, 0.f); oe[tid] = fmaxf(a2, 0.f);
    }
    __syncthreads();
    {
      float a1 = b_sp1[tid], a2 = a1;
      for (int e = 0; e < 256; ++e) {
        float ww = W_sp1[(256 + e) * 256 + tid];
        a1 += se[e] * ww; a2 += oe[e] * ww;
      }
      wbs[b * 256 + tid] = a1; wbo[b * 256 + tid] = a2;
    }
    for (int jj = 0; jj < 2; ++jj) {
      int j = tid + jj * 256;
      float a = b_tr[j];
      for (int i = 0; i < 256; ++i) a += se[i] * W_tr[i * 512 + j];
      for (int i = 0; i < 256; ++i) a += oe[i] * W_tr[(256 + i) * 512 + j];
      trl[j] = fmaxf(a, 0.f);
    }
    __syncthreads();
    for (int jj = 0; jj < 2; ++jj) {
      int j = tid + jj * 256;
      float a = b_tb1[j];
      for (int i = 0; i < 512; ++i) a += trl[i] * W_tb1[(size_t)(512 + i) * 512 + j];
      tbias[b * 512 + j] = a;
    }
  }
}

// Fallback converters (small-ws path)
__global__ __launch_bounds__(256) void k_wconvT(const float* __restrict__ src,
                                                unsigned short* __restrict__ dst,
                                                int K, int N) {
  __shared__ float t[64][65];
  int nblk = N >> 6;
  int kb = blockIdx.x / nblk, nb = blockIdx.x - kb * nblk;
  int tid = threadIdx.x;
#pragma unroll
  for (int i = 0; i < 16; ++i) {
    int idx = tid + 256 * i;
    int r = idx >> 6, c = idx & 63;
    t[r][c] = src[(size_t)(kb * 64 + r) * N + nb * 64 + c];
  }
  __syncthreads();
#pragma unroll
  for (int i = 0; i < 16; ++i) {
    int idx = tid + 256 * i;
    int n = idx >> 6, kk = idx & 63;
    dst[(size_t)(nb * 64 + n) * K + kb * 64 + kk] = f2bf(t[kk][n]);
  }
}

__global__ __launch_bounds__(256) void k_wconv7(
    const float* __restrict__ w0, const float* __restrict__ w1,
    const float* __restrict__ w2, const float* __restrict__ w3,
    const float* __restrict__ w4, const float* __restrict__ w5,
    const float* __restrict__ w6, unsigned short* __restrict__ dstb) {
  __shared__ float t[64][65];
  int wsel = blockIdx.x >> 6, sub = blockIdx.x & 63;
  int kb = sub >> 3, nb = sub & 7;
  const float* src = wsel == 0 ? w0 : wsel == 1 ? w1 : wsel == 2 ? w2
                   : wsel == 3 ? w3 : wsel == 4 ? w4 : wsel == 5 ? w5 : w6;
  unsigned short* dst = dstb + (size_t)wsel * 262144;
  int tid = threadIdx.x;
#pragma unroll
  for (int i = 0; i < 16; ++i) {
    int idx = tid + 256 * i;
    int r = idx >> 6, c = idx & 63;
    t[r][c] = src[(size_t)(kb * 64 + r) * 512 + nb * 64 + c];
  }
  __syncthreads();
#pragma unroll
  for (int i = 0; i < 16; ++i) {
    int idx = tid + 256 * i;
    int n = idx >> 6, kk = idx & 63;
    dst[(size_t)(nb * 64 + n) * 512 + kb * 64 + kk] = f2bf(t[kk][n]);
  }
}

__global__ __launch_bounds__(256) void k_cvt2(const float* __restrict__ a,
                                              const float* __restrict__ b,
                                              unsigned short* __restrict__ da,
                                              unsigned short* __restrict__ db) {
  int i = blockIdx.x * 256 + threadIdx.x;
  const float* s; unsigned short* d; int off;
  if (i < 131072) { s = a; d = da; off = i * 8; }
  else            { s = b; d = db; off = (i - 131072) * 8; }
  float f[8];
#pragma unroll
  for (int j = 0; j < 8; ++j) f[j] = s[off + j];
  *(short8*)(d + off) = mk8(f);
}

// ve GEMM, m97 structure with FUSED fp32->bf16 A-staging — EXACT r7 form
// (600 blocks x 512 thr, BM=64, BN=256, BK=64, wave 64x32, XOR swizzle).
// r8's BN-split regressed (staging issue traffic x1.7) and was reverted.
__global__ __launch_bounds__(512) void k_gemm_ve_m97(
    const float* __restrict__ videos, const unsigned short* __restrict__ wtbf,
    const float* __restrict__ bev, const float* __restrict__ Wel,
    const float* __restrict__ bel, unsigned short* __restrict__ vebf) {
  __shared__ __align__(16) unsigned short lds[20480];  // A: [0,4096) B: [4096,20480)
  int tid = threadIdx.x;
  int rowbase = blockIdx.x * 64;
  int lane = tid & 63, wid = tid >> 6;
  int l16 = lane & 15, lk = lane >> 4;

  // A staging: thread -> row=tid>>3, kc=tid&7 (8 fp32 -> bf16)
  int arow = tid >> 3, akc = tid & 7;
  const float* apA = videos + (size_t)(rowbase + arow) * VD_ + akc * 8;
  int dstA = arow * 64 + ((akc ^ (arow & 7)) * 8);
  // B staging: 4 chunks/thread
  const unsigned short* spB[4];
  int dstB[4];
#pragma unroll
  for (int i = 0; i < 4; ++i) {
    int g = tid + 512 * i;
    int n = g >> 3, kc = g & 7;
    spB[i] = wtbf + (size_t)n * 2048 + kc * 8;
    dstB[i] = 4096 + n * 64 + ((kc ^ (n & 7)) * 8);
  }
  float fa[8];
  short8 stB[4];
#pragma unroll
  for (int j = 0; j < 8; ++j) fa[j] = apA[j];
#pragma unroll
  for (int i = 0; i < 4; ++i) stB[i] = *(const short8*)(spB[i]);

  f32x4 acc[4][2] = {};
  for (int k0 = 0; k0 < 2048; k0 += 64) {
    short8 ha = mk8(fa);   // convert prev prefetch while waiting
    __syncthreads();       // prev-step readers done; loads drained
    *(short8*)(lds + dstA) = ha;
#pragma unroll
    for (int i = 0; i < 4; ++i) *(short8*)(lds + dstB[i]) = stB[i];
    __syncthreads();       // tile visible
    int kn = (k0 + 64 < 2048) ? k0 + 64 : 0;
#pragma unroll
    for (int j = 0; j < 8; ++j) fa[j] = apA[kn + j];
#pragma unroll
    for (int i = 0; i < 4; ++i) stB[i] = *(const short8*)(spB[i] + kn);
#pragma unroll
    for (int kk = 0; kk < 2; ++kk) {
      short8 a8[4], b8[2];
#pragma unroll
      for (int fm = 0; fm < 4; ++fm) {
        int row = fm * 16 + l16;
        a8[fm] = *(const short8*)(lds + row * 64 + (((kk * 4 + lk) ^ (row & 7)) * 8));
      }
#pragma unroll
      for (int fn = 0; fn < 2; ++fn) {
        int n = wid * 32 + fn * 16 + l16;
        b8[fn] = *(const short8*)(lds + 4096 + n * 64 + (((kk * 4 + lk) ^ (n & 7)) * 8));
      }
#pragma unroll
      for (int fm = 0; fm < 4; ++fm)
#pragma unroll
        for (int fn = 0; fn < 2; ++fn)
          acc[fm][fn] = __builtin_amdgcn_mfma_f32_16x16x32_bf16(
              a8[fm], b8[fn], acc[fm][fn], 0, 0, 0);
    }
  }
  // epilogue: C/D map col=lane&15, row=(lane>>4)*4+reg (validated r3-r7)
  float bevv[2], belv[2], w5[5][2];
#pragma unroll
  for (int fn = 0; fn < 2; ++fn) {
    int col = wid * 32 + fn * 16 + l16;
    bevv[fn] = bev[col]; belv[fn] = bel[col];
#pragma unroll
    for (int kk = 0; kk < 5; ++kk) w5[kk][fn] = Wel[kk * 256 + col];
  }
#pragma unroll
  for (int fm = 0; fm < 4; ++fm) {
#pragma unroll
    for (int r = 0; r < 4; ++r) {
      int grow = rowbase + fm * 16 + lk * 4 + r;
      const float* vt = videos + (size_t)grow * VD_ + 2048;
      float t0 = vt[0], t1 = vt[1], t2 = vt[2], t3 = vt[3], t4 = vt[4];
      unsigned short* vob = vebf + (size_t)grow * 256;
#pragma unroll
      for (int fn = 0; fn < 2; ++fn) {
        int col = wid * 32 + fn * 16 + l16;
        float s2 = belv[fn] + t0 * w5[0][fn] + t1 * w5[1][fn] + t2 * w5[2][fn] +
                   t3 * w5[3][fn] + t4 * w5[4][fn];
        float vvv = fmaxf(acc[fm][fn][r] + bevv[fn], 0.f) + fmaxf(s2, 0.f);
        vob[col] = f2bf(vvv);
      }
    }
  }
}

// MFMA score kernel (unchanged, validated r5-r8)
__global__ __launch_bounds__(256) void k_score_bf(
    const unsigned short* __restrict__ vebf, const unsigned short* __restrict__ wsp1,
    const float* __restrict__ w_sp2, const float* __restrict__ wbs,
    const float* __restrict__ wbo, float* __restrict__ s_sub,
    float* __restrict__ s_obj) {
  __shared__ float reds[4][64], redo_[4][64];
  int tid = threadIdx.x;
  int rowbase = blockIdx.x * 64;
  int lane = tid & 63, wid = tid >> 6;
  int l16 = lane & 15, lk = lane >> 4;
  const unsigned short* ap[4];
  const unsigned short* bp[4];
#pragma unroll
  for (int fm = 0; fm < 4; ++fm)
    ap[fm] = vebf + (size_t)(rowbase + fm * 16 + l16) * 256 + lk * 8;
#pragma unroll
  for (int fn = 0; fn < 4; ++fn)
    bp[fn] = wsp1 + (size_t)(wid * 64 + fn * 16 + l16) * 256 + lk * 8;
  f32x4 acc[4][4] = {};
#pragma unroll 2
  for (int k0 = 0; k0 < 256; k0 += 32) {
    short8 a8[4], b8[4];
#pragma unroll
    for (int fm = 0; fm < 4; ++fm) a8[fm] = *(const short8*)(ap[fm] + k0);
#pragma unroll
    for (int fn = 0; fn < 4; ++fn) b8[fn] = *(const short8*)(bp[fn] + k0);
#pragma unroll
    for (int fm = 0; fm < 4; ++fm)
#pragma unroll
      for (int fn = 0; fn < 4; ++fn)
        acc[fm][fn] = __builtin_amdgcn_mfma_f32_16x16x32_bf16(
            a8[fm], b8[fn], acc[fm][fn], 0, 0, 0);
  }
  int b = rowbase / 4800;
  float w2[4], bs[4], bo[4];
#pragma unroll
  for (int fn = 0; fn < 4; ++fn) {
    int col = wid * 64 + fn * 16 + l16;
    w2[fn] = w_sp2[col];
    bs[fn] = wbs[b * 256 + col];
    bo[fn] = wbo[b * 256 + col];
  }
  float ps[4][4], po[4][4];
#pragma unroll
  for (int fm = 0; fm < 4; ++fm)
#pragma unroll
    for (int r = 0; r < 4; ++r) {
      float aps = 0, apo = 0;
#pragma unroll
      for (int fn = 0; fn < 4; ++fn) {
        float t = acc[fm][fn][r];
        aps += fast_tanh(t + bs[fn]) * w2[fn];
        apo += fast_tanh(t + bo[fn]) * w2[fn];
      }
      ps[fm][r] = aps;
      po[fm][r] = apo;
    }
#pragma unroll
  for (int m = 1; m < 16; m <<= 1) {
#pragma unroll
    for (int fm = 0; fm < 4; ++fm)
#pragma unroll
      for (int r = 0; r < 4; ++r) {
        ps[fm][r] += __shfl_xor(ps[fm][r], m);
        po[fm][r] += __shfl_xor(po[fm][r], m);
      }
  }
  if (l16 == 0) {
#pragma unroll
    for (int fm = 0; fm < 4; ++fm)
#pragma unroll
      for (int r = 0; r < 4; ++r) {
        int row = fm * 16 + lk * 4 + r;
        reds[wid][row] = ps[fm][r];
        redo_[wid][row] = po[fm][r];
      }
  }
  __syncthreads();
  if (tid < 64) {
    float s1 = reds[0][tid] + reds[1][tid] + reds[2][tid] + reds[3][tid];
    float s2 = redo_[0][tid] + redo_[1][tid] + redo_[2][tid] + redo_[3][tid];
    s_sub[rowbase + tid] = s1;
    s_obj[rowbase + tid] = s2;
  }
}

// attend from bf16 ve (unchanged, validated r6-r8)
__global__ __launch_bounds__(256) void k_attend_bf(
    const float* __restrict__ s_sub, const float* __restrict__ s_obj,
    const unsigned short* __restrict__ vebf, const float* __restrict__ W_s2o,
    const float* __restrict__ b_s2o, const float* __restrict__ W_o2s,
    const float* __restrict__ b_o2s, float* __restrict__ out_satt,
    float* __restrict__ out_oatt, float* __restrict__ orix) {
  int row = blockIdx.x;
  int tid = threadIdx.x;
  __shared__ float alds[2][40];
  int wv = tid >> 6, lane = tid & 63;
  if (wv < 2) {
    const float* sarr = (wv ? s_obj : s_sub) + row * 40;
    float v = (lane < 40) ? sarr[lane] : -1e30f;
    float mx = wredmax(v);
    float e = (lane < 40) ? __expf(v - mx) : 0.f;
    float sm = wredsum(e);
    float p = e / sm;
    if (lane < 40) {
      alds[wv][lane] = p;
      (wv ? out_oatt : out_satt)[row * 40 + lane] = p;
    }
  }
  __syncthreads();
  int e = tid;
  const unsigned short* vrow = vebf + (size_t)row * 40 * 256;
  float sf = 0, of = 0, s2o = b_s2o[e], o2s = b_o2s[e];
  for (int n = 0; n < 40; ++n) {
    float as = alds[0][n], aob = alds[1][n];
    float vv = bf2f(vrow[n * 256 + e]);
    sf += as * vv;
    of += aob * vv;
    s2o += as * W_s2o[n * 256 + e];
    o2s += aob * W_o2s[n * 256 + e];
  }
  s2o = fmaxf(s2o, 0.f);
  o2s = fmaxf(o2s, 0.f);
  orix[(size_t)row * 512 + e] = sf + o2s;
  orix[(size_t)row * 512 + 256 + e] = of + s2o;
}

// --------- fallback kernels (small-ws path, r6/r7-validated) -------
__global__ __launch_bounds__(256) void k_gemm_ve_mfma(
    const float* __restrict__ videos, const unsigned short* __restrict__ wtbf,
    const float* __restrict__ bev, const float* __restrict__ Wel,
    const float* __restrict__ bel, float* __restrict__ ve) {
  int tid = threadIdx.x;
  int rowbase = blockIdx.x * 64;
  int lane = tid & 63, wid = tid >> 6;
  int l16 = lane & 15, lk = lane >> 4;
  const float* ap[4];
  const unsigned short* bp[4];
#pragma unroll
  for (int fm = 0; fm < 4; ++fm)
    ap[fm] = videos + (size_t)(rowbase + fm * 16 + l16) * VD_ + lk * 8;
#pragma unroll
  for (int fn = 0; fn < 4; ++fn)
    bp[fn] = wtbf + (size_t)(wid * 64 + fn * 16 + l16) * 2048 + lk * 8;
  f32x4 acc[4][4] = {};
  for (int k0 = 0; k0 < 2048; k0 += 64) {
#pragma unroll
    for (int kk = 0; kk < 2; ++kk) {
      int ko = k0 + kk * 32;
      short8 a8[4], b8[4];
#pragma unroll
      for (int fm = 0; fm < 4; ++fm) {
        const float* a = ap[fm] + ko;
        float f[8];
#pragma unroll
        for (int j = 0; j < 8; ++j) f[j] = a[j];
        a8[fm] = mk8(f);
      }
#pragma unroll
      for (int fn = 0; fn < 4; ++fn) b8[fn] = *(const short8*)(bp[fn] + ko);
#pragma unroll
      for (int fm = 0; fm < 4; ++fm)
#pragma unroll
        for (int fn = 0; fn < 4; ++fn)
          acc[fm][fn] = __builtin_amdgcn_mfma_f32_16x16x32_bf16(
              a8[fm], b8[fn], acc[fm][fn], 0, 0, 0);
    }
    if ((k0 & 255) == 192) __builtin_amdgcn_s_barrier();
  }
  float bevv[4], belv[4], w5[5][4];
#pragma unroll
  for (int fn = 0; fn < 4; ++fn) {
    int col = wid * 64 + fn * 16 + l16;
    bevv[fn] = bev[col]; belv[fn] = bel[col];
#pragma unroll
    for (int kk = 0; kk < 5; ++kk) w5[kk][fn] = Wel[kk * 256 + col];
  }
#pragma unroll
  for (int fm = 0; fm < 4; ++fm) {
#pragma unroll
    for (int r = 0; r < 4; ++r) {
      int grow = rowbase + fm * 16 + lk * 4 + r;
      const float* vt = videos + (size_t)grow * VD_ + 2048;
      float t0 = vt[0], t1 = vt[1], t2 = vt[2], t3 = vt[3], t4 = vt[4];
      float* vo = ve + (size_t)grow * 256;
#pragma unroll
      for (int fn = 0; fn < 4; ++fn) {
        int col = wid * 64 + fn * 16 + l16;
        float s2 = belv[fn] + t0 * w5[0][fn] + t1 * w5[1][fn] + t2 * w5[2][fn] +
                   t3 * w5[3][fn] + t4 * w5[4][fn];
        vo[col] = fmaxf(acc[fm][fn][r] + bevv[fn], 0.f) + fmaxf(s2, 0.f);
      }
    }
  }
}

__global__ __launch_bounds__(256) void k_score(
    const float* __restrict__ ve, const float* __restrict__ W_sp1,
    const float* __restrict__ w_sp2, const float* __restrict__ wbs,
    const float* __restrict__ wbo, float* __restrict__ s_sub,
    float* __restrict__ s_obj) {
  __shared__ float vel[32][264];
  int tid = threadIdx.x;
  int rowbase = blockIdx.x * 32;
  for (int i = tid; i < 2048; i += 256) {
    int r = i >> 6, c = (i & 63) << 2;
    *(float4*)&vel[r][c] = *(const float4*)&ve[(size_t)(rowbase + r) * 256 + c];
  }
  __syncthreads();
  int wv = tid >> 6, lane = tid & 63;
  int r0 = wv * 8;
  float acc[8][4] = {};
  for (int k = 0; k < 256; ++k) {
    float w4[4];
#pragma unroll
    for (int c = 0; c < 4; ++c) w4[c] = W_sp1[(size_t)k * 256 + c * 64 + lane];
#pragma unroll
    for (int m = 0; m < 8; ++m) {
      float a = vel[r0 + m][k];
#pragma unroll
      for (int c = 0; c < 4; ++c) acc[m][c] += a * w4[c];
    }
  }
  int b = rowbase / 4800;
  float w2[4], bs[4], bo[4];
#pragma unroll
  for (int c = 0; c < 4; ++c) {
    int col = c * 64 + lane;
    w2[c] = w_sp2[col];
    bs[c] = wbs[b * 256 + col];
    bo[c] = wbo[b * 256 + col];
  }
#pragma unroll
  for (int m = 0; m < 8; ++m) {
    float ps = 0, po = 0;
#pragma unroll
    for (int c = 0; c < 4; ++c) {
      float t = acc[m][c];
      ps += fast_tanh(t + bs[c]) * w2[c];
      po += fast_tanh(t + bo[c]) * w2[c];
    }
    ps = wredsum(ps);
    po = wredsum(po);
    if (lane == 0) {
      s_sub[rowbase + r0 + m] = ps;
      s_obj[rowbase + r0 + m] = po;
    }
  }
}

__global__ __launch_bounds__(256) void k_attend(
    const float* __restrict__ s_sub, const float* __restrict__ s_obj,
    const float* __restrict__ ve, const float* __restrict__ W_s2o,
    const float* __restrict__ b_s2o, const float* __restrict__ W_o2s,
    const float* __restrict__ b_o2s, float* __restrict__ out_satt,
    float* __restrict__ out_oatt, float* __restrict__ orix) {
  int row = blockIdx.x;
  int tid = threadIdx.x;
  __shared__ float alds[2][40];
  int wv = tid >> 6, lane = tid & 63;
  if (wv < 2) {
    const float* sarr = (wv ? s_obj : s_sub) + row * 40;
    float v = (lane < 40) ? sarr[lane] : -1e30f;
    float mx = wredmax(v);
    float e = (lane < 40) ? __expf(v - mx) : 0.f;
    float sm = wredsum(e);
    float p = e / sm;
    if (lane < 40) {
      alds[wv][lane] = p;
      (wv ? out_oatt : out_satt)[row * 40 + lane] = p;
    }
  }
  __syncthreads();
  int e = tid;
  const float* vrow = ve + (size_t)row * 40 * 256;
  float sf = 0, of = 0, s2o = b_s2o[e], o2s = b_o2s[e];
  for (int n = 0; n < 40; ++n) {
    float as = alds[0][n], aob = alds[1][n];
    float vv = vrow[n * 256 + e];
    sf += as * vv;
    of += aob * vv;
    s2o += as * W_s2o[n * 256 + e];
    o2s += aob * W_o2s[n * 256 + e];
  }
  s2o = fmaxf(s2o, 0.f);
  o2s = fmaxf(o2s, 0.f);
  orix[(size_t)row * 512 + e] = sf + o2s;
  orix[(size_t)row * 512 + 256 + e] = of + s2o;
}

// Generic H-GEMM, LDS-free MFMA (unchanged)
__global__ __launch_bounds__(256) void k_gemm_h(
    const float* __restrict__ A, const unsigned short* __restrict__ WT,
    const float* __restrict__ b0, const float* __restrict__ b1,
    const float* __restrict__ b2, float* __restrict__ Cbase, int ntiles,
    int relu) {
  int tid = threadIdx.x;
  int bid = blockIdx.x;
  int mt = bid / ntiles, nt = bid - mt * ntiles;
  int rowbase = mt * 64;
  int lane = tid & 63, wid = tid >> 6;
  int wrow = wid >> 1, wcol = wid & 1;
  int l16 = lane & 15, lk = lane >> 4;
  const float* ap[2];
  const unsigned short* bp[2];
#pragma unroll
  for (int fm = 0; fm < 2; ++fm)
    ap[fm] = A + (size_t)(rowbase + wrow * 32 + fm * 16 + l16) * 512 + lk * 8;
#pragma unroll
  for (int fn = 0; fn < 2; ++fn)
    bp[fn] = WT + (size_t)(nt * 64 + wcol * 32 + fn * 16 + l16) * 512 + lk * 8;
  f32x4 acc[2][2] = {};
  for (int k0 = 0; k0 < 512; k0 += 64) {
#pragma unroll
    for (int kk = 0; kk < 2; ++kk) {
      int ko = k0 + kk * 32;
      short8 a8[2], b8[2];
#pragma unroll
      for (int fm = 0; fm < 2; ++fm) {
        float4 x = *(const float4*)(ap[fm] + ko);
        float4 y = *(const float4*)(ap[fm] + ko + 4);
        float f[8] = {x.x, x.y, x.z, x.w, y.x, y.y, y.z, y.w};
        a8[fm] = mk8(f);
      }
#pragma unroll
      for (int fn = 0; fn < 2; ++fn) b8[fn] = *(const short8*)(bp[fn] + ko);
#pragma unroll
      for (int fm = 0; fm < 2; ++fm)
#pragma unroll
        for (int fn = 0; fn < 2; ++fn)
          acc[fm][fn] = __builtin_amdgcn_mfma_f32_16x16x32_bf16(
              a8[fm], b8[fn], acc[fm][fn], 0, 0, 0);
    }
  }
#pragma unroll
  for (int fn = 0; fn < 2; ++fn) {
    int cg = nt * 64 + wcol * 32 + fn * 16 + l16;
    int third = cg >> 9, c = cg & 511;
    const float* bb = third == 0 ? b0 : (third == 1 ? b1 : b2);
    float bv = bb[c];
    float* outp = Cbase + (size_t)third * ((size_t)R_ * H_);
#pragma unroll
    for (int fm = 0; fm < 2; ++fm) {
#pragma unroll
      for (int r = 0; r < 4; ++r) {
        int grow = rowbase + wrow * 32 + fm * 16 + lk * 4 + r;
        float v = acc[fm][fn][r] + bv;
        if (relu) v = fmaxf(v, 0.f);
        outp[(size_t)grow * 512 + c] = v;
      }
    }
  }
}

// Merged xproj (bid<64) + beta2 (bid>=64): independent consumers of win.
__global__ __launch_bounds__(256) void k_xb(
    const float* __restrict__ win, const unsigned short* __restrict__ wih,
    const float* __restrict__ b_ih, const float* __restrict__ b_hh,
    float* __restrict__ gx, const float* __restrict__ W_tb1,
    const float* __restrict__ w_tb2, const float* __restrict__ tbias,
    float* __restrict__ z2) {
  __shared__ float xr[512];
  __shared__ float red[256];
  int bid0 = blockIdx.x;
  int tid = threadIdx.x;
  if (bid0 < 64) {
    int bid = bid0;
    int mt = bid >> 5, nt = bid & 31;
    int lane = tid & 63, wid = tid >> 6;
    int wrow = wid >> 1, wcol = wid & 1;
    int l16 = lane & 15, lk = lane >> 4;
    const float* ap[2];
    bool av[2];
#pragma unroll
    for (int fm = 0; fm < 2; ++fm) {
      int base = mt * 64 + wrow * 32 + fm * 16;
      av[fm] = base < 80;
      int grow = base + l16;
      int s = grow >> 3, b = grow & 7;
      ap[fm] = av[fm] ? (win + (size_t)(b * 120 + 11 + 12 * s) * 512 + lk * 8)
                      : win;
    }
    const unsigned short* bp[2];
#pragma unroll
    for (int fn = 0; fn < 2; ++fn)
      bp[fn] = wih + (size_t)(nt * 64 + wcol * 32 + fn * 16 + l16) * 512 + lk * 8;
    f32x4 acc[2][2] = {};
    for (int k0 = 0; k0 < 512; k0 += 64) {
#pragma unroll
      for (int kk = 0; kk < 2; ++kk) {
        int ko = k0 + kk * 32;
        short8 a8[2], b8[2];
#pragma unroll
        for (int fm = 0; fm < 2; ++fm) {
          if (av[fm]) {
            float4 x = *(const float4*)(ap[fm] + ko);
            float4 y = *(const float4*)(ap[fm] + ko + 4);
            float f[8] = {x.x, x.y, x.z, x.w, y.x, y.y, y.z, y.w};
            a8[fm] = mk8(f);
          } else {
            a8[fm] = short8{0, 0, 0, 0, 0, 0, 0, 0};
          }
        }
#pragma unroll
        for (int fn = 0; fn < 2; ++fn) b8[fn] = *(const short8*)(bp[fn] + ko);
#pragma unroll
        for (int fm = 0; fm < 2; ++fm)
#pragma unroll
          for (int fn = 0; fn < 2; ++fn)
            acc[fm][fn] = __builtin_amdgcn_mfma_f32_16x16x32_bf16(
                a8[fm], b8[fn], acc[fm][fn], 0, 0, 0);
      }
    }
#pragma unroll
    for (int fn = 0; fn < 2; ++fn) {
      int cg = nt * 64 + wcol * 32 + fn * 16 + l16;
      float bv = b_ih[cg] + b_hh[cg];
#pragma unroll
      for (int fm = 0; fm < 2; ++fm) {
        if (!av[fm]) continue;
#pragma unroll
        for (int r = 0; r < 4; ++r) {
          int grow = mt * 64 + wrow * 32 + fm * 16 + lk * 4 + r;
          if (grow < 80) gx[(size_t)grow * 2048 + cg] = acc[fm][fn][r] + bv;
        }
      }
    }
  } else {
    int bid = bid0 - 64;  // 0..79
    int b = bid / 10, si = bid - b * 10;
    int trow = b * 120 + 11 + 12 * si;
    for (int i = tid; i < 512; i += 256) xr[i] = win[(size_t)trow * 512 + i];
    __syncthreads();
    float val = 0;
    for (int jj = 0; jj < 2; ++jj) {
      int j = tid + jj * 256;
      float a = tbias[b * 512 + j];
      for (int i = 0; i < 512; ++i) a += xr[i] * W_tb1[(size_t)i * 512 + j];
      val += fast_tanh(a) * w_tb2[j];
    }
    red[tid] = val;
    __syncthreads();
    for (int s = 128; s; s >>= 1) {
      if (tid < s) red[tid] += red[tid + s];
      __syncthreads();
    }
    if (tid == 0) z2[bid] = red[0];
  }
}

// standalone xproj / beta2 (fallback path)
__global__ __launch_bounds__(256) void k_xproj(
    const float* __restrict__ win, const unsigned short* __restrict__ wih,
    const float* __restrict__ b_ih, const float* __restrict__ b_hh,
    float* __restrict__ gx) {
  int bid = blockIdx.x;
  int mt = bid >> 5, nt = bid & 31;
  int tid = threadIdx.x;
  int lane = tid & 63, wid = tid >> 6;
  int wrow = wid >> 1, wcol = wid & 1;
  int l16 = lane & 15, lk = lane >> 4;
  const float* ap[2];
  bool av[2];
#pragma unroll
  for (int fm = 0; fm < 2; ++fm) {
    int base = mt * 64 + wrow * 32 + fm * 16;
    av[fm] = base < 80;
    int grow = base + l16;
    int s = grow >> 3, b = grow & 7;
    ap[fm] = av[fm] ? (win + (size_t)(b * 120 + 11 + 12 * s) * 512 + lk * 8)
                    : win;
  }
  const unsigned short* bp[2];
#pragma unroll
  for (int fn = 0; fn < 2; ++fn)
    bp[fn] = wih + (size_t)(nt * 64 + wcol * 32 + fn * 16 + l16) * 512 + lk * 8;
  f32x4 acc[2][2] = {};
  for (int k0 = 0; k0 < 512; k0 += 64) {
#pragma unroll
    for (int kk = 0; kk < 2; ++kk) {
      int ko = k0 + kk * 32;
      short8 a8[2], b8[2];
#pragma unroll
      for (int fm = 0; fm < 2; ++fm) {
        if (av[fm]) {
          float4 x = *(const float4*)(ap[fm] + ko);
          float4 y = *(const float4*)(ap[fm] + ko + 4);
          float f[8] = {x.x, x.y, x.z, x.w, y.x, y.y, y.z, y.w};
          a8[fm] = mk8(f);
        } else {
          a8[fm] = short8{0, 0, 0, 0, 0, 0, 0, 0};
        }
      }
#pragma unroll
      for (int fn = 0; fn < 2; ++fn) b8[fn] = *(const short8*)(bp[fn] + ko);
#pragma unroll
      for (int fm = 0; fm < 2; ++fm)
#pragma unroll
        for (int fn = 0; fn < 2; ++fn)
          acc[fm][fn] = __builtin_amdgcn_mfma_f32_16x16x32_bf16(
              a8[fm], b8[fn], acc[fm][fn], 0, 0, 0);
    }
  }
#pragma unroll
  for (int fn = 0; fn < 2; ++fn) {
    int cg = nt * 64 + wcol * 32 + fn * 16 + l16;
    float bv = b_ih[cg] + b_hh[cg];
#pragma unroll
    for (int fm = 0; fm < 2; ++fm) {
      if (!av[fm]) continue;
#pragma unroll
      for (int r = 0; r < 4; ++r) {
        int grow = mt * 64 + wrow * 32 + fm * 16 + lk * 4 + r;
        if (grow < 80) gx[(size_t)grow * 2048 + cg] = acc[fm][fn][r] + bv;
      }
    }
  }
}

__global__ __launch_bounds__(256) void k_beta2(
    const float* __restrict__ within, const float* __restrict__ W_tb1,
    const float* __restrict__ w_tb2, const float* __restrict__ tbias,
    float* __restrict__ z2) {
  int bid = blockIdx.x;
  int b = bid / 10, si = bid - b * 10;
  int trow = b * 120 + 11 + 12 * si;
  int tid = threadIdx.x;
  __shared__ float xr[512];
  __shared__ float red[256];
  for (int i = tid; i < 512; i += 256) xr[i] = within[(size_t)trow * 512 + i];
  __syncthreads();
  float val = 0;
  for (int jj = 0; jj < 2; ++jj) {
    int j = tid + jj * 256;
    float a = tbias[b * 512 + j];
    for (int i = 0; i < 512; ++i) a += xr[i] * W_tb1[(size_t)i * 512 + j];
    val += fast_tanh(a) * w_tb2[j];
  }
  red[tid] = val;
  __syncthreads();
  for (int s = 128; s; s >>= 1) {
    if (tid < s) red[tid] += red[tid + s];
    __syncthreads();
  }
  if (tid == 0) z2[bid] = red[0];
}

// Persistent LSTM (r8): all 10 steps, grid-sync via release/acquire barrier.
// 32 blocks x 128 thr, trivially co-resident. bar zeroed each call by k_wprep.
// Epilogue folds k_hbias.
__global__ __launch_bounds__(128) void k_lstm_all(
    const unsigned short* __restrict__ whh, const float* __restrict__ gx,
    float* __restrict__ h0, float* __restrict__ h1, float* __restrict__ c_st,
    const float* __restrict__ W_l1, const float* __restrict__ b_l1,
    float* __restrict__ hb, unsigned int* __restrict__ bar) {
  int jb = blockIdx.x;
  int tid = threadIdx.x;
  int lane = tid & 63, kw = tid >> 6;
  int l16 = lane & 15, lk = lane >> 4;
  const unsigned short* bp[4];
#pragma unroll
  for (int fn = 0; fn < 4; ++fn)
    bp[fn] = whh + (size_t)(fn * 512 + jb * 16 + l16) * 512 + kw * 256 + lk * 8;
  __shared__ float part[4][64][4];
  for (int s = 0; s < 10; ++s) {
    const float* hin = (s & 1) ? h1 : h0;
    float* hout = (s & 1) ? h0 : h1;
    const float* ap = hin + (size_t)l16 * 512 + kw * 256 + lk * 8;
    f32x4 acc[4] = {};
    for (int k0 = 0; k0 < 256; k0 += 64) {
#pragma unroll
      for (int kk = 0; kk < 2; ++kk) {
        int ko = k0 + kk * 32;
        float4 x = *(const float4*)(ap + ko);
        float4 y = *(const float4*)(ap + ko + 4);
        float f[8] = {x.x, x.y, x.z, x.w, y.x, y.y, y.z, y.w};
        short8 a8 = mk8(f);
#pragma unroll
        for (int fn = 0; fn < 4; ++fn) {
          short8 b8 = *(const short8*)(bp[fn] + ko);
          acc[fn] = __builtin_amdgcn_mfma_f32_16x16x32_bf16(a8, b8, acc[fn], 0, 0, 0);
        }
      }
    }
    if (kw == 1) {
#pragma unroll
      for (int fn = 0; fn < 4; ++fn)
#pragma unroll
        for (int r = 0; r < 4; ++r) part[fn][lane][r] = acc[fn][r];
    }
    __syncthreads();
    if (kw == 0 && lk < 2) {
      int j = jb * 16 + l16;
#pragma unroll
      for (int r = 0; r < 4; ++r) {
        int b = lk * 4 + r;
        const float* g = gx + (size_t)(s * 8 + b) * 2048;
        float gi = acc[0][r] + part[0][lane][r] + g[j];
        float gf = acc[1][r] + part[1][lane][r] + g[512 + j];
        float gg = acc[2][r] + part[2][lane][r] + g[1024 + j];
        float go = acc[3][r] + part[3][lane][r] + g[1536 + j];
        float c = sigf(gf) * c_st[b * 512 + j] + sigf(gi) * fast_tanh(gg);
        c_st[b * 512 + j] = c;
        hout[b * 512 + j] = sigf(go) * fast_tanh(c);
      }
    }
    __syncthreads();
    __threadfence();
    __syncthreads();
    if (tid == 0) {
      atomicAdd(bar, 1u);
      while (atomicAdd(bar, 0u) < 32u * (unsigned)(s + 1)) {}
    }
    __syncthreads();
    __threadfence();
  }
  // hbias epilogue: hb[b][j] = b_l1[j] + sum_i hT[b][i]*W_l1[512+i][j]
  int b = tid >> 4, j = jb * 16 + (tid & 15);
  float a = b_l1[j];
  const float* hr = h0 + b * 512;
  for (int i = 0; i < 512; ++i) a += hr[i] * W_l1[(size_t)(512 + i) * 512 + j];
  hb[b * 512 + j] = a;
}

// fallback LSTM step
__global__ __launch_bounds__(128) void k_lstm_step(
    const float* __restrict__ hin, const unsigned short* __restrict__ whh,
    const float* __restrict__ gx, int s, float* __restrict__ hout,
    float* __restrict__ c_st) {
  int jb = blockIdx.x;
  int tid = threadIdx.x;
  int lane = tid & 63, kw = tid >> 6;
  int l16 = lane & 15, lk = lane >> 4;
  const float* ap = hin + (size_t)l16 * 512 + kw * 256 + lk * 8;
  const unsigned short* bp[4];
#pragma unroll
  for (int fn = 0; fn < 4; ++fn)
    bp[fn] = whh + (size_t)(fn * 512 + jb * 16 + l16) * 512 + kw * 256 + lk * 8;
  f32x4 acc[4] = {};
  for (int k0 = 0; k0 < 256; k0 += 64) {
#pragma unroll
    for (int kk = 0; kk < 2; ++kk) {
      int ko = k0 + kk * 32;
      float4 x = *(const float4*)(ap + ko);
      float4 y = *(const float4*)(ap + ko + 4);
      float f[8] = {x.x, x.y, x.z, x.w, y.x, y.y, y.z, y.w};
      short8 a8 = mk8(f);
#pragma unroll
      for (int fn = 0; fn < 4; ++fn) {
        short8 b8 = *(const short8*)(bp[fn] + ko);
        acc[fn] = __builtin_amdgcn_mfma_f32_16x16x32_bf16(a8, b8, acc[fn], 0, 0, 0);
      }
    }
  }
  __shared__ float part[4][64][4];
  if (kw == 1) {
#pragma unroll
    for (int fn = 0; fn < 4; ++fn)
#pragma unroll
      for (int r = 0; r < 4; ++r) part[fn][lane][r] = acc[fn][r];
  }
  __syncthreads();
  if (kw == 0 && lk < 2) {
    int j = jb * 16 + l16;
#pragma unroll
    for (int r = 0; r < 4; ++r) {
      int b = lk * 4 + r;
      const float* g = gx + (size_t)(s * 8 + b) * 2048;
      float gi = acc[0][r] + part[0][lane][r] + g[j];
      float gf = acc[1][r] + part[1][lane][r] + g[512 + j];
      float gg = acc[2][r] + part[2][lane][r] + g[1024 + j];
      float go = acc[3][r] + part[3][lane][r] + g[1536 + j];
      float c = sigf(gf) * c_st[b * 512 + j] + sigf(gi) * fast_tanh(gg);
      c_st[b * 512 + j] = c;
      hout[b * 512 + j] = sigf(go) * fast_tanh(c);
    }
  }
}

// MHA per (b,h,qc) (unchanged from r6-r8)
__global__ __launch_bounds__(256) void k_mha(const float* __restrict__ qb,
                                             const float* __restrict__ kb,
                                             const float* __restrict__ vb,
                                             float* __restrict__ ao) {
  int bh = blockIdx.x & 63, qc = blockIdx.x >> 6;
  int b = bh >> 3, h = bh & 7;
  __shared__ float ks[120 * 65];
  __shared__ float vs[120 * 65];
  __shared__ float ps[4][128];
  int tid = threadIdx.x;
  for (int i = 0; i < 30; ++i) {
    int idx = tid + 256 * i;
    int t = idx >> 6, d = idx & 63;
    size_t g = (size_t)(b * 120 + t) * 512 + h * 64 + d;
    ks[t * 65 + d] = kb[g];
    vs[t * 65 + d] = vb[g];
  }
  __syncthreads();
  int wv = tid >> 6, lane = tid & 63;
  for (int i = qc * 30 + wv; i < qc * 30 + 30; i += 4) {
    const float* qrow = qb + (size_t)(b * 120 + i) * 512 + h * 64;
    float s1 = 0, s2 = 0;
    for (int d = 0; d < 64; ++d) {
      float qd = qrow[d];
      s1 += qd * ks[lane * 65 + d];
      if (lane < 56) s2 += qd * ks[(lane + 64) * 65 + d];
    }
    s1 *= 0.125f;
    s2 *= 0.125f;
    if (lane >= 56) s2 = -1e30f;
    float mx = wredmax(fmaxf(s1, s2));
    float e1 = __expf(s1 - mx);
    float e2 = (lane < 56) ? __expf(s2 - mx) : 0.f;
    float sm = wredsum(e1 + e2);
    ps[wv][lane] = e1;
    ps[wv][64 + lane] = e2;
    float o = 0;
    for (int j = 0; j < 120; ++j) o += ps[wv][j] * vs[j * 65 + lane];
    ao[(size_t)(b * 120 + i) * 512 + h * 64 + lane] = o / sm;
  }
}

// LN with optional bf16 dual-write (for win -> winbf)
__global__ __launch_bounds__(256) void k_ln(const float* __restrict__ a,
                                            const float* __restrict__ bsrc,
                                            const float* __restrict__ g,
                                            const float* __restrict__ be,
                                            float* __restrict__ out,
                                            unsigned short* __restrict__ bfout) {
  int row = blockIdx.x * 4 + (threadIdx.x >> 6);
  int lane = threadIdx.x & 63;
  const float* pa = a + (size_t)row * 512;
  const float* pb = bsrc + (size_t)row * 512;
  float z[8];
  float s = 0;
#pragma unroll
  for (int ii = 0; ii < 8; ++ii) {
    int e = lane + 64 * ii;
    z[ii] = pa[e] + pb[e];
    s += z[ii];
  }
  float mean = wredsum(s) * (1.f / 512.f);
  float v = 0;
#pragma unroll
  for (int ii = 0; ii < 8; ++ii) {
    float d = z[ii] - mean;
    v += d * d;
  }
  float rstd = rsqrtf(wredsum(v) * (1.f / 512.f) + 1e-5f);
#pragma unroll
  for (int ii = 0; ii < 8; ++ii) {
    int e = lane + 64 * ii;
    float val = (z[ii] - mean) * rstd * g[e] + be[e];
    out[(size_t)row * 512 + e] = val;
    if (bfout) bfout[(size_t)row * 512 + e] = f2bf(val);
  }
}

__global__ __launch_bounds__(256) void k_hbias(const float* __restrict__ hT,
                                               const float* __restrict__ W_l1,
                                               const float* __restrict__ b_l1,
                                               float* __restrict__ hb) {
  int b = blockIdx.x >> 1, half = blockIdx.x & 1;
  int tid = threadIdx.x;
  __shared__ float hl[512];
  for (int i = tid; i < 512; i += 256) hl[i] = hT[b * 512 + i];
  __syncthreads();
  int j = half * 256 + tid;
  float a = b_l1[j];
  for (int i = 0; i < 512; ++i) a += hl[i] * W_l1[(size_t)(512 + i) * 512 + j];
  hb[b * 512 + j] = a;
}

// MFMA beta1 (unchanged, validated r7/r8)
__global__ __launch_bounds__(256) void k_beta1_bf(
    const unsigned short* __restrict__ winbf, const unsigned short* __restrict__ wl1bf,
    const float* __restrict__ w_l2, const float* __restrict__ hb,
    float* __restrict__ l1) {
  __shared__ float reds[4][64];
  int tid = threadIdx.x;
  int rowbase = blockIdx.x * 64;  // 15 blocks
  int lane = tid & 63, wid = tid >> 6;
  int l16 = lane & 15, lk = lane >> 4;
  const unsigned short* ap[4];
#pragma unroll
  for (int fm = 0; fm < 4; ++fm)
    ap[fm] = winbf + (size_t)(rowbase + fm * 16 + l16) * 512 + lk * 8;
  float ps[4][4] = {};
#pragma unroll
  for (int cs = 0; cs < 2; ++cs) {
    const unsigned short* bp[4];
#pragma unroll
    for (int fn = 0; fn < 4; ++fn)
      bp[fn] = wl1bf + (size_t)(cs * 256 + wid * 64 + fn * 16 + l16) * 512 + lk * 8;
    f32x4 acc[4][4] = {};
    for (int k0 = 0; k0 < 512; k0 += 32) {
      short8 a8[4], b8[4];
#pragma unroll
      for (int fm = 0; fm < 4; ++fm) a8[fm] = *(const short8*)(ap[fm] + k0);
#pragma unroll
      for (int fn = 0; fn < 4; ++fn) b8[fn] = *(const short8*)(bp[fn] + k0);
#pragma unroll
      for (int fm = 0; fm < 4; ++fm)
#pragma unroll
        for (int fn = 0; fn < 4; ++fn)
          acc[fm][fn] = __builtin_amdgcn_mfma_f32_16x16x32_bf16(
              a8[fm], b8[fn], acc[fm][fn], 0, 0, 0);
    }
#pragma unroll
    for (int fm = 0; fm < 4; ++fm)
#pragma unroll
      for (int r = 0; r < 4; ++r) {
        int grow = rowbase + fm * 16 + lk * 4 + r;
        int b = grow / 120;
#pragma unroll
        for (int fn = 0; fn < 4; ++fn) {
          int col = cs * 256 + wid * 64 + fn * 16 + l16;
          ps[fm][r] += fast_tanh(acc[fm][fn][r] + hb[b * 512 + col]) * w_l2[col];
        }
      }
  }
#pragma unroll
  for (int m = 1; m < 16; m <<= 1)
#pragma unroll
    for (int fm = 0; fm < 4; ++fm)
#pragma unroll
      for (int r = 0; r < 4; ++r) ps[fm][r] += __shfl_xor(ps[fm][r], m);
  if (l16 == 0) {
#pragma unroll
    for (int fm = 0; fm < 4; ++fm)
#pragma unroll
      for (int r = 0; r < 4; ++r) reds[wid][fm * 16 + lk * 4 + r] = ps[fm][r];
  }
  __syncthreads();
  if (tid < 64)
    l1[rowbase + tid] = reds[0][tid] + reds[1][tid] + reds[2][tid] + reds[3][tid];
}

// fallback fp32 beta1
__global__ __launch_bounds__(256) void k_beta1(
    const float* __restrict__ within, const float* __restrict__ W_l1,
    const float* __restrict__ w_l2, const float* __restrict__ hb,
    float* __restrict__ l1) {
  int bid = blockIdx.x;
  int r0 = bid * 4;
  int b = r0 / 120;
  int tid = threadIdx.x;
  __shared__ float xr[4][512];
  __shared__ float red[4][256];
  for (int i = tid; i < 2048; i += 256) xr[i >> 9][i & 511] = within[(size_t)r0 * 512 + i];
  __syncthreads();
  float v[4] = {0, 0, 0, 0};
  for (int jj = 0; jj < 2; ++jj) {
    int j = tid + jj * 256;
    float hbv = hb[b * 512 + j];
    float a0 = hbv, a1 = hbv, a2 = hbv, a3 = hbv;
    for (int i = 0; i < 512; ++i) {
      float ww = W_l1[(size_t)i * 512 + j];
      a0 += xr[0][i] * ww;
      a1 += xr[1][i] * ww;
      a2 += xr[2][i] * ww;
      a3 += xr[3][i] * ww;
    }
    float wl = w_l2[j];
    v[0] += fast_tanh(a0) * wl;
    v[1] += fast_tanh(a1) * wl;
    v[2] += fast_tanh(a2) * wl;
    v[3] += fast_tanh(a3) * wl;
  }
#pragma unroll
  for (int r = 0; r < 4; ++r) red[r][tid] = v[r];
  __syncthreads();
  for (int s = 128; s; s >>= 1) {
    if (tid < s)
      for (int r = 0; r < 4; ++r) red[r][tid] += red[r][tid + s];
    __syncthreads();
  }
  if (tid < 4) l1[r0 + tid] = red[tid][0];
}

__global__ __launch_bounds__(256) void k_final(
    const float* __restrict__ l1, const float* __restrict__ z2,
    const float* __restrict__ within, const float* __restrict__ hT,
    const float* __restrict__ cT, float* __restrict__ dout) {
  int b = blockIdx.x;
  int tid = threadIdx.x;
  __shared__ float temp[120];
  __shared__ float b2[10];
  int wv = tid >> 6, lane = tid & 63;
  if (wv == 1) {
    float v = (lane < 10) ? z2[b * 10 + lane] : -1e30f;
    float mx = wredmax(v);
    float e = (lane < 10) ? __expf(v - mx) : 0.f;
    float sm = wredsum(e);
    if (lane < 10) {
      float p = e / sm;
      b2[lane] = p;
      dout[O_B2 + b * 10 + lane] = p;
    }
  }
  if (wv == 0) {
    float v1 = l1[b * 120 + lane];
    float v2 = (lane + 64 < 120) ? l1[b * 120 + 64 + lane] : -1e30f;
    float mx = wredmax(fmaxf(v1, v2));
    float e1 = __expf(v1 - mx);
    float e2 = (lane + 64 < 120) ? __expf(v2 - mx) : 0.f;
    float sm = wredsum(e1 + e2);
    float p1 = e1 / sm;
    dout[O_B1 + b * 120 + lane] = p1;
    temp[lane] = p1;
    if (lane + 64 < 120) {
      float p2 = e2 / sm;
      dout[O_B1 + b * 120 + 64 + lane] = p2;
      temp[64 + lane] = p2;
    }
  }
  __syncthreads();
  for (int t = tid; t < 120; t += 256) temp[t] += b2[t / 12];
  __syncthreads();
  for (int hh = tid; hh < 512; hh += 256) {
    float o = 0;
    for (int t = 0; t < 120; ++t) o += temp[t] * within[(size_t)(b * 120 + t) * 512 + hh];
    dout[O_OUT + b * 512 + hh] = o;
    dout[O_HT + b * 512 + hh] = hT[b * 512 + hh];
    dout[O_CT + b * 512 + hh] = cT[b * 512 + hh];
  }
}

// ---------------------------------------------------------------
extern "C" void kernel_launch(void* const* d_in, const int* in_sizes, int n_in,
                              void* d_out, int out_size, void* d_ws, size_t ws_size,
                              hipStream_t stream) {
  const float* videos = (const float*)d_in[0];
  const float* sub_g  = (const float*)d_in[1];
  const float* obj_g  = (const float*)d_in[2];
  const float* W_ev   = (const float*)d_in[3];
  const float* b_ev   = (const float*)d_in[4];
  const float* W_el   = (const float*)d_in[5];
  const float* b_el   = (const float*)d_in[6];
  const float* W_ew   = (const float*)d_in[7];
  const float* b_ew   = (const float*)d_in[8];
  const float* W_sp1  = (const float*)d_in[9];
  const float* b_sp1  = (const float*)d_in[10];
  const float* w_sp2  = (const float*)d_in[11];
  const float* W_s2o  = (const float*)d_in[12];
  const float* b_s2o  = (const float*)d_in[13];
  const float* W_o2s  = (const float*)d_in[14];
  const float* b_o2s  = (const float*)d_in[15];
  const float* W_tv   = (const float*)d_in[16];
  const float* b_tv   = (const float*)d_in[17];
  const float* Wq     = (const float*)d_in[18];
  const float* bq     = (const float*)d_in[19];
  const float* Wk     = (const float*)d_in[20];
  const float* bk     = (const float*)d_in[21];
  const float* Wv     = (const float*)d_in[22];
  const float* bv     = (const float*)d_in[23];
  const float* Wo     = (const float*)d_in[24];
  const float* bo     = (const float*)d_in[25];
  const float* g1     = (const float*)d_in[26];
  const float* be1    = (const float*)d_in[27];
  const float* Wf1    = (const float*)d_in[28];
  const float* bf1    = (const float*)d_in[29];
  const float* Wf2    = (const float*)d_in[30];
  const float* bf2    = (const float*)d_in[31];
  const float* g2     = (const float*)d_in[32];
  const float* be2    = (const float*)d_in[33];
  const float* W_tr   = (const float*)d_in[34];
  const float* b_tr   = (const float*)d_in[35];
  const float* W_tb1  = (const float*)d_in[36];
  const float* b_tb1  = (const float*)d_in[37];
  const float* w_tb2  = (const float*)d_in[38];
  const float* W_ih   = (const float*)d_in[39];
  const float* W_hh   = (const float*)d_in[40];
  const float* b_ih   = (const float*)d_in[41];
  const float* b_hh   = (const float*)d_in[42];
  const float* W_l1   = (const float*)d_in[43];
  const float* b_l1   = (const float*)d_in[44];
  const float* w_l2   = (const float*)d_in[45];

  float* out = (float*)d_out;
  float* w = (float*)d_ws;

  float* ve_p   = w + OFF_VE;
  float* ssub_p = w + OFF_SSUB;
  float* sobj_p = w + OFF_SOBJ;
  float* wbs_p  = w + OFF_WBS;
  float* wbo_p  = w + OFF_WBO;
  float* tb_p   = w + OFF_TBIAS;
  float* orix_p = w + OFF_ORIX;
  float* x_p    = w + OFF_X;
  float* q_p    = w + OFF_Q;
  float* k_p    = w + OFF_K;
  float* v_p    = w + OFF_V;
  float* ao_p   = w + OFF_AO;
  float* attn_p = w + OFF_ATTN;
  float* x1_p   = w + OFF_X1;
  float* f1_p   = w + OFF_F1;
  float* f2_p   = w + OFF_F2;
  float* win_p  = w + OFF_WIN;
  float* z2_p   = w + OFF_Z2;
  float* h_p    = w + OFF_H0;           // h0[4096], h1[4096], c[4096]
  float* c_p    = h_p + 2 * 4096;
  float* hb_p   = w + OFF_HB;
  float* l1_p   = w + OFF_L1;
  unsigned int* bar_p = (unsigned int*)(w + OFF_BAR);

  unsigned short* wtbase = (unsigned short*)(w + OFF_WT);
  unsigned short* wevbf = wtbase;                    // [256][2048]
  unsigned short* w7bf  = wtbase + 524288;           // 7 x [512][512]
  unsigned short* wtvbf = w7bf;
  unsigned short* wqbf  = w7bf + 1 * 262144;
  unsigned short* wobf  = w7bf + 4 * 262144;
  unsigned short* wf1bf = w7bf + 5 * 262144;
  unsigned short* wf2bf = w7bf + 6 * 262144;
  unsigned short* wsp1bf = w7bf + 7 * 262144;        // [256][256]
  // big-path dedicated buffers
  unsigned short* wihbf  = (unsigned short*)(w + OFF_WIH);
  unsigned short* whhbf  = (unsigned short*)(w + OFF_WHH);
  unsigned short* wl1bf  = (unsigned short*)(w + OFF_WL1B);
  unsigned short* winbf_p = (unsigned short*)(w + OFF_WINBF);
  unsigned short* vebf_p = (unsigned short*)(w + OFF_VEBF);
  float* gx_p = w + OFF_Q;  // aliases dead Q (written post-mha by k_xb)
  const bool big = ws_size >= (size_t)OFF_END * 4;

  if (big) {
    k_wprep<<<1689, 256, 0, stream>>>(W_ev, W_tv, Wq, Wk, Wv, Wo, Wf1, Wf2,
                                      W_sp1, W_l1, W_ih, W_hh, sub_g, obj_g,
                                      W_ew, b_ew, b_sp1, W_tr, b_tr, W_tb1,
                                      b_tb1, wevbf, w7bf, wsp1bf, wl1bf, wihbf,
                                      whhbf, h_p, bar_p, wbs_p, wbo_p, tb_p);
    k_gemm_ve_m97<<<600, 512, 0, stream>>>(videos, wevbf, b_ev, W_el, b_el,
                                           vebf_p);
    k_score_bf<<<600, 256, 0, stream>>>(vebf_p, wsp1bf, w_sp2, wbs_p, wbo_p,
                                        ssub_p, sobj_p);
    k_attend_bf<<<960, 256, 0, stream>>>(ssub_p, sobj_p, vebf_p, W_s2o, b_s2o,
                                         W_o2s, b_o2s, out + O_SATT,
                                         out + O_OATT, orix_p);
    k_gemm_h<<<120, 256, 0, stream>>>(orix_p, wtvbf, b_tv, b_tv, b_tv, x_p, 8, 1);
    k_gemm_h<<<360, 256, 0, stream>>>(x_p, wqbf, bq, bk, bv, q_p, 24, 0);
    k_mha<<<256, 256, 0, stream>>>(q_p, k_p, v_p, ao_p);
    k_gemm_h<<<120, 256, 0, stream>>>(ao_p, wobf, bo, bo, bo, attn_p, 8, 0);
    k_ln<<<240, 256, 0, stream>>>(x_p, attn_p, g1, be1, x1_p, nullptr);
    k_gemm_h<<<120, 256, 0, stream>>>(x1_p, wf1bf, bf1, bf1, bf1, f1_p, 8, 1);
    k_gemm_h<<<120, 256, 0, stream>>>(f1_p, wf2bf, bf2, bf2, bf2, f2_p, 8, 0);
    k_ln<<<240, 256, 0, stream>>>(x1_p, f2_p, g2, be2, win_p, winbf_p);
    k_xb<<<144, 256, 0, stream>>>(win_p, wihbf, b_ih, b_hh, gx_p, W_tb1, w_tb2,
                                  tb_p, z2_p);
    k_lstm_all<<<32, 128, 0, stream>>>(whhbf, gx_p, h_p, h_p + 4096, c_p,
                                       W_l1, b_l1, hb_p, bar_p);
    k_beta1_bf<<<15, 256, 0, stream>>>(winbf_p, wl1bf, w_l2, hb_p, l1_p);
    k_final<<<8, 256, 0, stream>>>(l1_p, z2_p, win_p, h_p, c_p, out);
  } else {
    // fallback (r6/r7-validated small-ws path)
    unsigned short* wihbf_a = (unsigned short*)(w + OFF_Q + 163840);
    unsigned short* whhbf_a = (unsigned short*)(w + OFF_Q + 688128);
    k_zero<<<48, 256, 0, stream>>>(h_p, 3 * 4096);
    k_small0<<<8, 256, 0, stream>>>(sub_g, obj_g, W_ew, b_ew, W_sp1, b_sp1,
                                    W_tr, b_tr, W_tb1, b_tb1, wbs_p, wbo_p, tb_p);
    k_wconvT<<<128, 256, 0, stream>>>(W_ev, wevbf, 2048, 256);
    k_wconv7<<<448, 256, 0, stream>>>(W_tv, Wq, Wk, Wv, Wo, Wf1, Wf2, w7bf);
    k_gemm_ve_mfma<<<600, 256, 0, stream>>>(videos, wevbf, b_ev, W_el, b_el, ve_p);
    k_score<<<1200, 256, 0, stream>>>(ve_p, W_sp1, w_sp2, wbs_p, wbo_p, ssub_p, sobj_p);
    k_attend<<<960, 256, 0, stream>>>(ssub_p, sobj_p, ve_p, W_s2o, b_s2o, W_o2s,
                                      b_o2s, out + O_SATT, out + O_OATT, orix_p);
    k_gemm_h<<<120, 256, 0, stream>>>(orix_p, wtvbf, b_tv, b_tv, b_tv, x_p, 8, 1);
    k_gemm_h<<<360, 256, 0, stream>>>(x_p, wqbf, bq, bk, bv, q_p, 24, 0);
    k_mha<<<256, 256, 0, stream>>>(q_p, k_p, v_p, ao_p);
    k_gemm_h<<<120, 256, 0, stream>>>(ao_p, wobf, bo, bo, bo, attn_p, 8, 0);
    k_ln<<<240, 256, 0, stream>>>(x_p, attn_p, g1, be1, x1_p, nullptr);
    k_gemm_h<<<120, 256, 0, stream>>>(x1_p, wf1bf, bf1, bf1, bf1, f1_p, 8, 1);
    k_gemm_h<<<120, 256, 0, stream>>>(f1_p, wf2bf, bf2, bf2, bf2, f2_p, 8, 0);
    k_ln<<<240, 256, 0, stream>>>(x1_p, f2_p, g2, be2, win_p, nullptr);
    k_cvt2<<<1024, 256, 0, stream>>>(W_ih, W_hh, wihbf_a, whhbf_a);
    k_xproj<<<64, 256, 0, stream>>>(win_p, wihbf_a, b_ih, b_hh, gx_p);
    k_beta2<<<80, 256, 0, stream>>>(win_p, W_tb1, w_tb2, tb_p, z2_p);
    for (int s = 0; s < 10; ++s) {
      float* hin = h_p + (s & 1) * 4096;
      float* hout = h_p + ((s & 1) ^ 1) * 4096;
      k_lstm_step<<<32, 128, 0, stream>>>(hin, whhbf_a, gx_p, s, hout, c_p);
    }
    k_hbias<<<16, 256, 0, stream>>>(h_p, W_l1, b_l1, hb_p);
    k_beta1<<<240, 256, 0, stream>>>(win_p, W_l1, w_l2, hb_p, l1_p);
    k_final<<<8, 256, 0, stream>>>(l1_p, z2_p, win_p, h_p, c_p, out);
  }
}

// Round 10
// 633.614 us; speedup vs baseline: 1.1188x; 1.1006x over previous
//
#include <hip/hip_runtime.h>
#include <cstddef>
#include <cstdint>

#define B_ 8
#define T_ 120
#define NB_ 40
#define VD_ 2053
#define E_ 256
#define H_ 512
#define M_ 38400   // B*T*NB
#define R_ 960     // B*T

// ---------------- workspace layout (float offsets) ----------------
static constexpr size_t OFF_VE    = 0;                        // 38400*256 (fallback path only)
static constexpr size_t OFF_SSUB  = OFF_VE + (size_t)M_ * E_; // 38400
static constexpr size_t OFF_SOBJ  = OFF_SSUB + M_;
static constexpr size_t OFF_WBS   = OFF_SOBJ + M_;            // 8*256
static constexpr size_t OFF_WBO   = OFF_WBS + B_ * E_;
static constexpr size_t OFF_TBIAS = OFF_WBO + B_ * E_;        // 8*512
static constexpr size_t OFF_ORIX  = OFF_TBIAS + B_ * H_;      // 960*512 each below
static constexpr size_t OFF_X     = OFF_ORIX + (size_t)R_ * H_;
static constexpr size_t OFF_Q     = OFF_X    + (size_t)R_ * H_;
static constexpr size_t OFF_K     = OFF_Q    + (size_t)R_ * H_;
static constexpr size_t OFF_V     = OFF_K    + (size_t)R_ * H_;
static constexpr size_t OFF_AO    = OFF_V    + (size_t)R_ * H_;
static constexpr size_t OFF_ATTN  = OFF_AO   + (size_t)R_ * H_;
static constexpr size_t OFF_X1    = OFF_ATTN + (size_t)R_ * H_;
static constexpr size_t OFF_F1    = OFF_X1   + (size_t)R_ * H_;
static constexpr size_t OFF_F2    = OFF_F1   + (size_t)R_ * H_;
static constexpr size_t OFF_WIN   = OFF_F2   + (size_t)R_ * H_;
static constexpr size_t OFF_WT    = OFF_WIN  + (size_t)R_ * H_; // 2M floats (bf16 weights)
static constexpr size_t OFF_Z2    = OFF_WT + (size_t)1024 * 2048; // 80
static constexpr size_t OFF_H0    = OFF_Z2 + 128;               // h0,h1,c : 3*4096
static constexpr size_t OFF_HB    = OFF_H0 + 3 * 4096;          // 8*512
static constexpr size_t OFF_L1    = OFF_HB + B_ * H_;           // 960
static constexpr size_t OFF_BAR   = OFF_L1 + 960;               // 1 uint (unused, kept for layout)
static constexpr size_t OFF_END0  = OFF_BAR + 4;
// big-ws region (dedicated, non-aliased)
static constexpr size_t OFF_WIH   = (OFF_END0 + 3) & ~(size_t)3;     // 2048*512 ushort
static constexpr size_t OFF_WHH   = OFF_WIH + 524288;
static constexpr size_t OFF_WL1B  = OFF_WHH + 524288;                // 512*512 ushort
static constexpr size_t OFF_WINBF = OFF_WL1B + 131072;               // 960*512 ushort
static constexpr size_t OFF_VEBF  = OFF_WINBF + 245760;              // M*E ushort
static constexpr size_t OFF_END   = OFF_VEBF + (size_t)M_ * E_ / 2;  // ~23.8M floats

// ---------------- d_out layout (float offsets) ----------------
static constexpr size_t O_OUT  = 0;      // 8*512
static constexpr size_t O_HT   = 4096;   // 8*512
static constexpr size_t O_CT   = 8192;   // 8*512
static constexpr size_t O_SATT = 12288;  // 8*120*40
static constexpr size_t O_OATT = 50688;  // 8*120*40
static constexpr size_t O_B1   = 89088;  // 8*120
static constexpr size_t O_B2   = 90048;  // 8*10

#define DEVFN __device__ __forceinline__

typedef __attribute__((ext_vector_type(8))) short short8;
typedef __attribute__((ext_vector_type(4))) float f32x4;

DEVFN float sigf(float x) { return 1.0f / (1.0f + __expf(-x)); }

// inline tanh: no OCML call (round-1 lesson: tanhf caused VGPR spill disaster)
DEVFN float fast_tanh(float x) {
  float e = __expf(2.f * x);
  return 1.f - 2.f / (e + 1.f);
}

// fp32 -> bf16 RNE (validated r3)
DEVFN unsigned short f2bf(float x) {
  unsigned int u = __float_as_uint(x);
  u += 0x7FFFu + ((u >> 16) & 1u);
  return (unsigned short)(u >> 16);
}
DEVFN float bf2f(unsigned short u) { return __uint_as_float((unsigned int)u << 16); }

DEVFN short8 mk8(const float* f) {
  short8 r;
#pragma unroll
  for (int j = 0; j < 8; ++j) r[j] = (short)f2bf(f[j]);
  return r;
}

DEVFN float wredsum(float v) {
#pragma unroll
  for (int m = 32; m; m >>= 1) v += __shfl_xor(v, m);
  return v;
}
DEVFN float wredmax(float v) {
#pragma unroll
  for (int m = 32; m; m >>= 1) v = fmaxf(v, __shfl_xor(v, m));
  return v;
}

// ---------------------------------------------------------------
__global__ __launch_bounds__(256) void k_zero(float* p, int n) {
  int i = blockIdx.x * 256 + threadIdx.x;
  if (i < n) p[i] = 0.f;
}

// Per-batch small precompute (standalone, fallback path)
__global__ __launch_bounds__(256) void k_small0(
    const float* __restrict__ sub_g, const float* __restrict__ obj_g,
    const float* __restrict__ W_ew, const float* __restrict__ b_ew,
    const float* __restrict__ W_sp1, const float* __restrict__ b_sp1,
    const float* __restrict__ W_tr, const float* __restrict__ b_tr,
    const float* __restrict__ W_tb1, const float* __restrict__ b_tb1,
    float* __restrict__ wbs, float* __restrict__ wbo, float* __restrict__ tbias) {
  int b = blockIdx.x, tid = threadIdx.x;
  __shared__ float sg[300], og[300], se[256], oe[256], trl[512];
  for (int i = tid; i < 300; i += 256) { sg[i] = sub_g[b * 300 + i]; og[i] = obj_g[b * 300 + i]; }
  __syncthreads();
  {
    float a1 = b_ew[tid], a2 = a1;
    for (int w = 0; w < 300; ++w) {
      float we = W_ew[w * 256 + tid];
      a1 += sg[w] * we; a2 += og[w] * we;
    }
    se[tid] = fmaxf(a1, 0.f); oe[tid] = fmaxf(a2, 0.f);
  }
  __syncthreads();
  {
    float a1 = b_sp1[tid], a2 = a1;
    for (int e = 0; e < 256; ++e) {
      float ww = W_sp1[(256 + e) * 256 + tid];
      a1 += se[e] * ww; a2 += oe[e] * ww;
    }
    wbs[b * 256 + tid] = a1; wbo[b * 256 + tid] = a2;
  }
  for (int jj = 0; jj < 2; ++jj) {
    int j = tid + jj * 256;
    float a = b_tr[j];
    for (int i = 0; i < 256; ++i) a += se[i] * W_tr[i * 512 + j];
    for (int i = 0; i < 256; ++i) a += oe[i] * W_tr[(256 + i) * 512 + j];
    trl[j] = fmaxf(a, 0.f);
  }
  __syncthreads();
  for (int jj = 0; jj < 2; ++jj) {
    int j = tid + jj * 256;
    float a = b_tb1[j];
    for (int i = 0; i < 512; ++i) a += trl[i] * W_tb1[(size_t)(512 + i) * 512 + j];
    tbias[b * 512 + j] = a;
  }
}

// Unified prep kernel (big path): all weight converts + h/c zero + the
// 8 small0 blocks (independent work, hidden under the 1681 convert blocks).
// Grid 1689.
__global__ __launch_bounds__(256) void k_wprep(
    const float* __restrict__ W_ev, const float* __restrict__ W_tv,
    const float* __restrict__ Wq, const float* __restrict__ Wk,
    const float* __restrict__ Wv, const float* __restrict__ Wo,
    const float* __restrict__ Wf1, const float* __restrict__ Wf2,
    const float* __restrict__ W_sp1, const float* __restrict__ W_l1,
    const float* __restrict__ W_ih, const float* __restrict__ W_hh,
    const float* __restrict__ sub_g, const float* __restrict__ obj_g,
    const float* __restrict__ W_ew, const float* __restrict__ b_ew,
    const float* __restrict__ b_sp1, const float* __restrict__ W_tr,
    const float* __restrict__ b_tr, const float* __restrict__ W_tb1,
    const float* __restrict__ b_tb1,
    unsigned short* __restrict__ wevbf, unsigned short* __restrict__ w7bf,
    unsigned short* __restrict__ wsp1bf, unsigned short* __restrict__ wl1bf,
    unsigned short* __restrict__ wihbf, unsigned short* __restrict__ whhbf,
    float* __restrict__ hz,
    float* __restrict__ wbs, float* __restrict__ wbo, float* __restrict__ tbias) {
  int bid = blockIdx.x, tid = threadIdx.x;
  __shared__ float shm[64 * 65];
  float (*t)[65] = (float(*)[65])shm;
  if (bid < 128) {
    int kb = bid >> 2, nb = bid & 3;
#pragma unroll
    for (int i = 0; i < 16; ++i) {
      int idx = tid + 256 * i; int r = idx >> 6, c = idx & 63;
      t[r][c] = W_ev[(size_t)(kb * 64 + r) * 256 + nb * 64 + c];
    }
    __syncthreads();
#pragma unroll
    for (int i = 0; i < 16; ++i) {
      int idx = tid + 256 * i; int n = idx >> 6, kk = idx & 63;
      wevbf[(size_t)(nb * 64 + n) * 2048 + kb * 64 + kk] = f2bf(t[kk][n]);
    }
  } else if (bid < 576) {
    int b2 = bid - 128;
    int wsel = b2 >> 6, sub = b2 & 63;
    int kb = sub >> 3, nb = sub & 7;
    const float* src = wsel == 0 ? W_tv : wsel == 1 ? Wq : wsel == 2 ? Wk
                     : wsel == 3 ? Wv : wsel == 4 ? Wo : wsel == 5 ? Wf1 : Wf2;
    unsigned short* dst = w7bf + (size_t)wsel * 262144;
#pragma unroll
    for (int i = 0; i < 16; ++i) {
      int idx = tid + 256 * i; int r = idx >> 6, c = idx & 63;
      t[r][c] = src[(size_t)(kb * 64 + r) * 512 + nb * 64 + c];
    }
    __syncthreads();
#pragma unroll
    for (int i = 0; i < 16; ++i) {
      int idx = tid + 256 * i; int n = idx >> 6, kk = idx & 63;
      dst[(size_t)(nb * 64 + n) * 512 + kb * 64 + kk] = f2bf(t[kk][n]);
    }
  } else if (bid < 592) {
    int b2 = bid - 576;
    int kb = b2 >> 2, nb = b2 & 3;
#pragma unroll
    for (int i = 0; i < 16; ++i) {
      int idx = tid + 256 * i; int r = idx >> 6, c = idx & 63;
      t[r][c] = W_sp1[(size_t)(kb * 64 + r) * 256 + nb * 64 + c];
    }
    __syncthreads();
#pragma unroll
    for (int i = 0; i < 16; ++i) {
      int idx = tid + 256 * i; int n = idx >> 6, kk = idx & 63;
      wsp1bf[(size_t)(nb * 64 + n) * 256 + kb * 64 + kk] = f2bf(t[kk][n]);
    }
  } else if (bid < 656) {
    int b2 = bid - 592;
    int kb = b2 >> 3, nb = b2 & 7;
#pragma unroll
    for (int i = 0; i < 16; ++i) {
      int idx = tid + 256 * i; int r = idx >> 6, c = idx & 63;
      t[r][c] = W_l1[(size_t)(kb * 64 + r) * 512 + nb * 64 + c];  // rows 0..511
    }
    __syncthreads();
#pragma unroll
    for (int i = 0; i < 16; ++i) {
      int idx = tid + 256 * i; int n = idx >> 6, kk = idx & 63;
      wl1bf[(size_t)(nb * 64 + n) * 512 + kb * 64 + kk] = f2bf(t[kk][n]);
    }
  } else if (bid < 1680) {
    int i = (bid - 656) * 256 + tid;
    const float* s; unsigned short* d; int off;
    if (i < 131072) { s = W_ih; d = wihbf; off = i * 8; }
    else            { s = W_hh; d = whhbf; off = (i - 131072) * 8; }
    float f[8];
#pragma unroll
    for (int j = 0; j < 8; ++j) f[j] = s[off + j];
    *(short8*)(d + off) = mk8(f);
  } else if (bid == 1680) {
    for (int i = tid; i < 12288; i += 256) hz[i] = 0.f;
  } else {
    // small0 body, b = bid - 1681 (8 blocks)
    int b = bid - 1681;
    float* sg = shm;         // 300
    float* og = shm + 300;   // 300
    float* se = shm + 600;   // 256
    float* oe = shm + 856;   // 256
    float* trl = shm + 1112; // 512
    for (int i = tid; i < 300; i += 256) { sg[i] = sub_g[b * 300 + i]; og[i] = obj_g[b * 300 + i]; }
    __syncthreads();
    {
      float a1 = b_ew[tid], a2 = a1;
      for (int w = 0; w < 300; ++w) {
        float we = W_ew[w * 256 + tid];
        a1 += sg[w] * we; a2 += og[w] * we;
      }
      se[tid] = fmaxf(a1, 0.f); oe[tid] = fmaxf(a2, 0.f);
    }
    __syncthreads();
    {
      float a1 = b_sp1[tid], a2 = a1;
      for (int e = 0; e < 256; ++e) {
        float ww = W_sp1[(256 + e) * 256 + tid];
        a1 += se[e] * ww; a2 += oe[e] * ww;
      }
      wbs[b * 256 + tid] = a1; wbo[b * 256 + tid] = a2;
    }
    for (int jj = 0; jj < 2; ++jj) {
      int j = tid + jj * 256;
      float a = b_tr[j];
      for (int i = 0; i < 256; ++i) a += se[i] * W_tr[i * 512 + j];
      for (int i = 0; i < 256; ++i) a += oe[i] * W_tr[(256 + i) * 512 + j];
      trl[j] = fmaxf(a, 0.f);
    }
    __syncthreads();
    for (int jj = 0; jj < 2; ++jj) {
      int j = tid + jj * 256;
      float a = b_tb1[j];
      for (int i = 0; i < 512; ++i) a += trl[i] * W_tb1[(size_t)(512 + i) * 512 + j];
      tbias[b * 512 + j] = a;
    }
  }
}

// Fallback converters (small-ws path)
__global__ __launch_bounds__(256) void k_wconvT(const float* __restrict__ src,
                                                unsigned short* __restrict__ dst,
                                                int K, int N) {
  __shared__ float t[64][65];
  int nblk = N >> 6;
  int kb = blockIdx.x / nblk, nb = blockIdx.x - kb * nblk;
  int tid = threadIdx.x;
#pragma unroll
  for (int i = 0; i < 16; ++i) {
    int idx = tid + 256 * i;
    int r = idx >> 6, c = idx & 63;
    t[r][c] = src[(size_t)(kb * 64 + r) * N + nb * 64 + c];
  }
  __syncthreads();
#pragma unroll
  for (int i = 0; i < 16; ++i) {
    int idx = tid + 256 * i;
    int n = idx >> 6, kk = idx & 63;
    dst[(size_t)(nb * 64 + n) * K + kb * 64 + kk] = f2bf(t[kk][n]);
  }
}

__global__ __launch_bounds__(256) void k_wconv7(
    const float* __restrict__ w0, const float* __restrict__ w1,
    const float* __restrict__ w2, const float* __restrict__ w3,
    const float* __restrict__ w4, const float* __restrict__ w5,
    const float* __restrict__ w6, unsigned short* __restrict__ dstb) {
  __shared__ float t[64][65];
  int wsel = blockIdx.x >> 6, sub = blockIdx.x & 63;
  int kb = sub >> 3, nb = sub & 7;
  const float* src = wsel == 0 ? w0 : wsel == 1 ? w1 : wsel == 2 ? w2
                   : wsel == 3 ? w3 : wsel == 4 ? w4 : wsel == 5 ? w5 : w6;
  unsigned short* dst = dstb + (size_t)wsel * 262144;
  int tid = threadIdx.x;
#pragma unroll
  for (int i = 0; i < 16; ++i) {
    int idx = tid + 256 * i;
    int r = idx >> 6, c = idx & 63;
    t[r][c] = src[(size_t)(kb * 64 + r) * 512 + nb * 64 + c];
  }
  __syncthreads();
#pragma unroll
  for (int i = 0; i < 16; ++i) {
    int idx = tid + 256 * i;
    int n = idx >> 6, kk = idx & 63;
    dst[(size_t)(nb * 64 + n) * 512 + kb * 64 + kk] = f2bf(t[kk][n]);
  }
}

__global__ __launch_bounds__(256) void k_cvt2(const float* __restrict__ a,
                                              const float* __restrict__ b,
                                              unsigned short* __restrict__ da,
                                              unsigned short* __restrict__ db) {
  int i = blockIdx.x * 256 + threadIdx.x;
  const float* s; unsigned short* d; int off;
  if (i < 131072) { s = a; d = da; off = i * 8; }
  else            { s = b; d = db; off = (i - 131072) * 8; }
  float f[8];
#pragma unroll
  for (int j = 0; j < 8; ++j) f[j] = s[off + j];
  *(short8*)(d + off) = mk8(f);
}

// ve GEMM, m97 structure with FUSED fp32->bf16 A-staging — EXACT r7 form
// (600 blocks x 512 thr, BM=64, BN=256, BK=64, wave 64x32, XOR swizzle).
__global__ __launch_bounds__(512) void k_gemm_ve_m97(
    const float* __restrict__ videos, const unsigned short* __restrict__ wtbf,
    const float* __restrict__ bev, const float* __restrict__ Wel,
    const float* __restrict__ bel, unsigned short* __restrict__ vebf) {
  __shared__ __align__(16) unsigned short lds[20480];  // A: [0,4096) B: [4096,20480)
  int tid = threadIdx.x;
  int rowbase = blockIdx.x * 64;
  int lane = tid & 63, wid = tid >> 6;
  int l16 = lane & 15, lk = lane >> 4;

  // A staging: thread -> row=tid>>3, kc=tid&7 (8 fp32 -> bf16)
  int arow = tid >> 3, akc = tid & 7;
  const float* apA = videos + (size_t)(rowbase + arow) * VD_ + akc * 8;
  int dstA = arow * 64 + ((akc ^ (arow & 7)) * 8);
  // B staging: 4 chunks/thread
  const unsigned short* spB[4];
  int dstB[4];
#pragma unroll
  for (int i = 0; i < 4; ++i) {
    int g = tid + 512 * i;
    int n = g >> 3, kc = g & 7;
    spB[i] = wtbf + (size_t)n * 2048 + kc * 8;
    dstB[i] = 4096 + n * 64 + ((kc ^ (n & 7)) * 8);
  }
  float fa[8];
  short8 stB[4];
#pragma unroll
  for (int j = 0; j < 8; ++j) fa[j] = apA[j];
#pragma unroll
  for (int i = 0; i < 4; ++i) stB[i] = *(const short8*)(spB[i]);

  f32x4 acc[4][2] = {};
  for (int k0 = 0; k0 < 2048; k0 += 64) {
    short8 ha = mk8(fa);   // convert prev prefetch while waiting
    __syncthreads();       // prev-step readers done; loads drained
    *(short8*)(lds + dstA) = ha;
#pragma unroll
    for (int i = 0; i < 4; ++i) *(short8*)(lds + dstB[i]) = stB[i];
    __syncthreads();       // tile visible
    int kn = (k0 + 64 < 2048) ? k0 + 64 : 0;
#pragma unroll
    for (int j = 0; j < 8; ++j) fa[j] = apA[kn + j];
#pragma unroll
    for (int i = 0; i < 4; ++i) stB[i] = *(const short8*)(spB[i] + kn);
#pragma unroll
    for (int kk = 0; kk < 2; ++kk) {
      short8 a8[4], b8[2];
#pragma unroll
      for (int fm = 0; fm < 4; ++fm) {
        int row = fm * 16 + l16;
        a8[fm] = *(const short8*)(lds + row * 64 + (((kk * 4 + lk) ^ (row & 7)) * 8));
      }
#pragma unroll
      for (int fn = 0; fn < 2; ++fn) {
        int n = wid * 32 + fn * 16 + l16;
        b8[fn] = *(const short8*)(lds + 4096 + n * 64 + (((kk * 4 + lk) ^ (n & 7)) * 8));
      }
#pragma unroll
      for (int fm = 0; fm < 4; ++fm)
#pragma unroll
        for (int fn = 0; fn < 2; ++fn)
          acc[fm][fn] = __builtin_amdgcn_mfma_f32_16x16x32_bf16(
              a8[fm], b8[fn], acc[fm][fn], 0, 0, 0);
    }
  }
  // epilogue: C/D map col=lane&15, row=(lane>>4)*4+reg (validated r3-r9)
  float bevv[2], belv[2], w5[5][2];
#pragma unroll
  for (int fn = 0; fn < 2; ++fn) {
    int col = wid * 32 + fn * 16 + l16;
    bevv[fn] = bev[col]; belv[fn] = bel[col];
#pragma unroll
    for (int kk = 0; kk < 5; ++kk) w5[kk][fn] = Wel[kk * 256 + col];
  }
#pragma unroll
  for (int fm = 0; fm < 4; ++fm) {
#pragma unroll
    for (int r = 0; r < 4; ++r) {
      int grow = rowbase + fm * 16 + lk * 4 + r;
      const float* vt = videos + (size_t)grow * VD_ + 2048;
      float t0 = vt[0], t1 = vt[1], t2 = vt[2], t3 = vt[3], t4 = vt[4];
      unsigned short* vob = vebf + (size_t)grow * 256;
#pragma unroll
      for (int fn = 0; fn < 2; ++fn) {
        int col = wid * 32 + fn * 16 + l16;
        float s2 = belv[fn] + t0 * w5[0][fn] + t1 * w5[1][fn] + t2 * w5[2][fn] +
                   t3 * w5[3][fn] + t4 * w5[4][fn];
        float vvv = fmaxf(acc[fm][fn][r] + bevv[fn], 0.f) + fmaxf(s2, 0.f);
        vob[col] = f2bf(vvv);
      }
    }
  }
}

// MFMA score kernel (unchanged, validated r5-r9)
__global__ __launch_bounds__(256) void k_score_bf(
    const unsigned short* __restrict__ vebf, const unsigned short* __restrict__ wsp1,
    const float* __restrict__ w_sp2, const float* __restrict__ wbs,
    const float* __restrict__ wbo, float* __restrict__ s_sub,
    float* __restrict__ s_obj) {
  __shared__ float reds[4][64], redo_[4][64];
  int tid = threadIdx.x;
  int rowbase = blockIdx.x * 64;
  int lane = tid & 63, wid = tid >> 6;
  int l16 = lane & 15, lk = lane >> 4;
  const unsigned short* ap[4];
  const unsigned short* bp[4];
#pragma unroll
  for (int fm = 0; fm < 4; ++fm)
    ap[fm] = vebf + (size_t)(rowbase + fm * 16 + l16) * 256 + lk * 8;
#pragma unroll
  for (int fn = 0; fn < 4; ++fn)
    bp[fn] = wsp1 + (size_t)(wid * 64 + fn * 16 + l16) * 256 + lk * 8;
  f32x4 acc[4][4] = {};
#pragma unroll 2
  for (int k0 = 0; k0 < 256; k0 += 32) {
    short8 a8[4], b8[4];
#pragma unroll
    for (int fm = 0; fm < 4; ++fm) a8[fm] = *(const short8*)(ap[fm] + k0);
#pragma unroll
    for (int fn = 0; fn < 4; ++fn) b8[fn] = *(const short8*)(bp[fn] + k0);
#pragma unroll
    for (int fm = 0; fm < 4; ++fm)
#pragma unroll
      for (int fn = 0; fn < 4; ++fn)
        acc[fm][fn] = __builtin_amdgcn_mfma_f32_16x16x32_bf16(
            a8[fm], b8[fn], acc[fm][fn], 0, 0, 0);
  }
  int b = rowbase / 4800;
  float w2[4], bs[4], bo[4];
#pragma unroll
  for (int fn = 0; fn < 4; ++fn) {
    int col = wid * 64 + fn * 16 + l16;
    w2[fn] = w_sp2[col];
    bs[fn] = wbs[b * 256 + col];
    bo[fn] = wbo[b * 256 + col];
  }
  float ps[4][4], po[4][4];
#pragma unroll
  for (int fm = 0; fm < 4; ++fm)
#pragma unroll
    for (int r = 0; r < 4; ++r) {
      float aps = 0, apo = 0;
#pragma unroll
      for (int fn = 0; fn < 4; ++fn) {
        float t = acc[fm][fn][r];
        aps += fast_tanh(t + bs[fn]) * w2[fn];
        apo += fast_tanh(t + bo[fn]) * w2[fn];
      }
      ps[fm][r] = aps;
      po[fm][r] = apo;
    }
#pragma unroll
  for (int m = 1; m < 16; m <<= 1) {
#pragma unroll
    for (int fm = 0; fm < 4; ++fm)
#pragma unroll
      for (int r = 0; r < 4; ++r) {
        ps[fm][r] += __shfl_xor(ps[fm][r], m);
        po[fm][r] += __shfl_xor(po[fm][r], m);
      }
  }
  if (l16 == 0) {
#pragma unroll
    for (int fm = 0; fm < 4; ++fm)
#pragma unroll
      for (int r = 0; r < 4; ++r) {
        int row = fm * 16 + lk * 4 + r;
        reds[wid][row] = ps[fm][r];
        redo_[wid][row] = po[fm][r];
      }
  }
  __syncthreads();
  if (tid < 64) {
    float s1 = reds[0][tid] + reds[1][tid] + reds[2][tid] + reds[3][tid];
    float s2 = redo_[0][tid] + redo_[1][tid] + redo_[2][tid] + redo_[3][tid];
    s_sub[rowbase + tid] = s1;
    s_obj[rowbase + tid] = s2;
  }
}

// attend from bf16 ve (unchanged, validated r6-r9)
__global__ __launch_bounds__(256) void k_attend_bf(
    const float* __restrict__ s_sub, const float* __restrict__ s_obj,
    const unsigned short* __restrict__ vebf, const float* __restrict__ W_s2o,
    const float* __restrict__ b_s2o, const float* __restrict__ W_o2s,
    const float* __restrict__ b_o2s, float* __restrict__ out_satt,
    float* __restrict__ out_oatt, float* __restrict__ orix) {
  int row = blockIdx.x;
  int tid = threadIdx.x;
  __shared__ float alds[2][40];
  int wv = tid >> 6, lane = tid & 63;
  if (wv < 2) {
    const float* sarr = (wv ? s_obj : s_sub) + row * 40;
    float v = (lane < 40) ? sarr[lane] : -1e30f;
    float mx = wredmax(v);
    float e = (lane < 40) ? __expf(v - mx) : 0.f;
    float sm = wredsum(e);
    float p = e / sm;
    if (lane < 40) {
      alds[wv][lane] = p;
      (wv ? out_oatt : out_satt)[row * 40 + lane] = p;
    }
  }
  __syncthreads();
  int e = tid;
  const unsigned short* vrow = vebf + (size_t)row * 40 * 256;
  float sf = 0, of = 0, s2o = b_s2o[e], o2s = b_o2s[e];
  for (int n = 0; n < 40; ++n) {
    float as = alds[0][n], aob = alds[1][n];
    float vv = bf2f(vrow[n * 256 + e]);
    sf += as * vv;
    of += aob * vv;
    s2o += as * W_s2o[n * 256 + e];
    o2s += aob * W_o2s[n * 256 + e];
  }
  s2o = fmaxf(s2o, 0.f);
  o2s = fmaxf(o2s, 0.f);
  orix[(size_t)row * 512 + e] = sf + o2s;
  orix[(size_t)row * 512 + 256 + e] = of + s2o;
}

// --------- fallback kernels (small-ws path, r6/r7-validated) -------
__global__ __launch_bounds__(256) void k_gemm_ve_mfma(
    const float* __restrict__ videos, const unsigned short* __restrict__ wtbf,
    const float* __restrict__ bev, const float* __restrict__ Wel,
    const float* __restrict__ bel, float* __restrict__ ve) {
  int tid = threadIdx.x;
  int rowbase = blockIdx.x * 64;
  int lane = tid & 63, wid = tid >> 6;
  int l16 = lane & 15, lk = lane >> 4;
  const float* ap[4];
  const unsigned short* bp[4];
#pragma unroll
  for (int fm = 0; fm < 4; ++fm)
    ap[fm] = videos + (size_t)(rowbase + fm * 16 + l16) * VD_ + lk * 8;
#pragma unroll
  for (int fn = 0; fn < 4; ++fn)
    bp[fn] = wtbf + (size_t)(wid * 64 + fn * 16 + l16) * 2048 + lk * 8;
  f32x4 acc[4][4] = {};
  for (int k0 = 0; k0 < 2048; k0 += 64) {
#pragma unroll
    for (int kk = 0; kk < 2; ++kk) {
      int ko = k0 + kk * 32;
      short8 a8[4], b8[4];
#pragma unroll
      for (int fm = 0; fm < 4; ++fm) {
        const float* a = ap[fm] + ko;
        float f[8];
#pragma unroll
        for (int j = 0; j < 8; ++j) f[j] = a[j];
        a8[fm] = mk8(f);
      }
#pragma unroll
      for (int fn = 0; fn < 4; ++fn) b8[fn] = *(const short8*)(bp[fn] + ko);
#pragma unroll
      for (int fm = 0; fm < 4; ++fm)
#pragma unroll
        for (int fn = 0; fn < 4; ++fn)
          acc[fm][fn] = __builtin_amdgcn_mfma_f32_16x16x32_bf16(
              a8[fm], b8[fn], acc[fm][fn], 0, 0, 0);
    }
    if ((k0 & 255) == 192) __builtin_amdgcn_s_barrier();
  }
  float bevv[4], belv[4], w5[5][4];
#pragma unroll
  for (int fn = 0; fn < 4; ++fn) {
    int col = wid * 64 + fn * 16 + l16;
    bevv[fn] = bev[col]; belv[fn] = bel[col];
#pragma unroll
    for (int kk = 0; kk < 5; ++kk) w5[kk][fn] = Wel[kk * 256 + col];
  }
#pragma unroll
  for (int fm = 0; fm < 4; ++fm) {
#pragma unroll
    for (int r = 0; r < 4; ++r) {
      int grow = rowbase + fm * 16 + lk * 4 + r;
      const float* vt = videos + (size_t)grow * VD_ + 2048;
      float t0 = vt[0], t1 = vt[1], t2 = vt[2], t3 = vt[3], t4 = vt[4];
      float* vo = ve + (size_t)grow * 256;
#pragma unroll
      for (int fn = 0; fn < 4; ++fn) {
        int col = wid * 64 + fn * 16 + l16;
        float s2 = belv[fn] + t0 * w5[0][fn] + t1 * w5[1][fn] + t2 * w5[2][fn] +
                   t3 * w5[3][fn] + t4 * w5[4][fn];
        vo[col] = fmaxf(acc[fm][fn][r] + bevv[fn], 0.f) + fmaxf(s2, 0.f);
      }
    }
  }
}

__global__ __launch_bounds__(256) void k_score(
    const float* __restrict__ ve, const float* __restrict__ W_sp1,
    const float* __restrict__ w_sp2, const float* __restrict__ wbs,
    const float* __restrict__ wbo, float* __restrict__ s_sub,
    float* __restrict__ s_obj) {
  __shared__ float vel[32][264];
  int tid = threadIdx.x;
  int rowbase = blockIdx.x * 32;
  for (int i = tid; i < 2048; i += 256) {
    int r = i >> 6, c = (i & 63) << 2;
    *(float4*)&vel[r][c] = *(const float4*)&ve[(size_t)(rowbase + r) * 256 + c];
  }
  __syncthreads();
  int wv = tid >> 6, lane = tid & 63;
  int r0 = wv * 8;
  float acc[8][4] = {};
  for (int k = 0; k < 256; ++k) {
    float w4[4];
#pragma unroll
    for (int c = 0; c < 4; ++c) w4[c] = W_sp1[(size_t)k * 256 + c * 64 + lane];
#pragma unroll
    for (int m = 0; m < 8; ++m) {
      float a = vel[r0 + m][k];
#pragma unroll
      for (int c = 0; c < 4; ++c) acc[m][c] += a * w4[c];
    }
  }
  int b = rowbase / 4800;
  float w2[4], bs[4], bo[4];
#pragma unroll
  for (int c = 0; c < 4; ++c) {
    int col = c * 64 + lane;
    w2[c] = w_sp2[col];
    bs[c] = wbs[b * 256 + col];
    bo[c] = wbo[b * 256 + col];
  }
#pragma unroll
  for (int m = 0; m < 8; ++m) {
    float ps = 0, po = 0;
#pragma unroll
    for (int c = 0; c < 4; ++c) {
      float t = acc[m][c];
      ps += fast_tanh(t + bs[c]) * w2[c];
      po += fast_tanh(t + bo[c]) * w2[c];
    }
    ps = wredsum(ps);
    po = wredsum(po);
    if (lane == 0) {
      s_sub[rowbase + r0 + m] = ps;
      s_obj[rowbase + r0 + m] = po;
    }
  }
}

__global__ __launch_bounds__(256) void k_attend(
    const float* __restrict__ s_sub, const float* __restrict__ s_obj,
    const float* __restrict__ ve, const float* __restrict__ W_s2o,
    const float* __restrict__ b_s2o, const float* __restrict__ W_o2s,
    const float* __restrict__ b_o2s, float* __restrict__ out_satt,
    float* __restrict__ out_oatt, float* __restrict__ orix) {
  int row = blockIdx.x;
  int tid = threadIdx.x;
  __shared__ float alds[2][40];
  int wv = tid >> 6, lane = tid & 63;
  if (wv < 2) {
    const float* sarr = (wv ? s_obj : s_sub) + row * 40;
    float v = (lane < 40) ? sarr[lane] : -1e30f;
    float mx = wredmax(v);
    float e = (lane < 40) ? __expf(v - mx) : 0.f;
    float sm = wredsum(e);
    float p = e / sm;
    if (lane < 40) {
      alds[wv][lane] = p;
      (wv ? out_oatt : out_satt)[row * 40 + lane] = p;
    }
  }
  __syncthreads();
  int e = tid;
  const float* vrow = ve + (size_t)row * 40 * 256;
  float sf = 0, of = 0, s2o = b_s2o[e], o2s = b_o2s[e];
  for (int n = 0; n < 40; ++n) {
    float as = alds[0][n], aob = alds[1][n];
    float vv = vrow[n * 256 + e];
    sf += as * vv;
    of += aob * vv;
    s2o += as * W_s2o[n * 256 + e];
    o2s += aob * W_o2s[n * 256 + e];
  }
  s2o = fmaxf(s2o, 0.f);
  o2s = fmaxf(o2s, 0.f);
  orix[(size_t)row * 512 + e] = sf + o2s;
  orix[(size_t)row * 512 + 256 + e] = of + s2o;
}

// Generic H-GEMM, LDS-free MFMA (unchanged)
__global__ __launch_bounds__(256) void k_gemm_h(
    const float* __restrict__ A, const unsigned short* __restrict__ WT,
    const float* __restrict__ b0, const float* __restrict__ b1,
    const float* __restrict__ b2, float* __restrict__ Cbase, int ntiles,
    int relu) {
  int tid = threadIdx.x;
  int bid = blockIdx.x;
  int mt = bid / ntiles, nt = bid - mt * ntiles;
  int rowbase = mt * 64;
  int lane = tid & 63, wid = tid >> 6;
  int wrow = wid >> 1, wcol = wid & 1;
  int l16 = lane & 15, lk = lane >> 4;
  const float* ap[2];
  const unsigned short* bp[2];
#pragma unroll
  for (int fm = 0; fm < 2; ++fm)
    ap[fm] = A + (size_t)(rowbase + wrow * 32 + fm * 16 + l16) * 512 + lk * 8;
#pragma unroll
  for (int fn = 0; fn < 2; ++fn)
    bp[fn] = WT + (size_t)(nt * 64 + wcol * 32 + fn * 16 + l16) * 512 + lk * 8;
  f32x4 acc[2][2] = {};
  for (int k0 = 0; k0 < 512; k0 += 64) {
#pragma unroll
    for (int kk = 0; kk < 2; ++kk) {
      int ko = k0 + kk * 32;
      short8 a8[2], b8[2];
#pragma unroll
      for (int fm = 0; fm < 2; ++fm) {
        float4 x = *(const float4*)(ap[fm] + ko);
        float4 y = *(const float4*)(ap[fm] + ko + 4);
        float f[8] = {x.x, x.y, x.z, x.w, y.x, y.y, y.z, y.w};
        a8[fm] = mk8(f);
      }
#pragma unroll
      for (int fn = 0; fn < 2; ++fn) b8[fn] = *(const short8*)(bp[fn] + ko);
#pragma unroll
      for (int fm = 0; fm < 2; ++fm)
#pragma unroll
        for (int fn = 0; fn < 2; ++fn)
          acc[fm][fn] = __builtin_amdgcn_mfma_f32_16x16x32_bf16(
              a8[fm], b8[fn], acc[fm][fn], 0, 0, 0);
    }
  }
#pragma unroll
  for (int fn = 0; fn < 2; ++fn) {
    int cg = nt * 64 + wcol * 32 + fn * 16 + l16;
    int third = cg >> 9, c = cg & 511;
    const float* bb = third == 0 ? b0 : (third == 1 ? b1 : b2);
    float bv = bb[c];
    float* outp = Cbase + (size_t)third * ((size_t)R_ * H_);
#pragma unroll
    for (int fm = 0; fm < 2; ++fm) {
#pragma unroll
      for (int r = 0; r < 4; ++r) {
        int grow = rowbase + wrow * 32 + fm * 16 + lk * 4 + r;
        float v = acc[fm][fn][r] + bv;
        if (relu) v = fmaxf(v, 0.f);
        outp[(size_t)grow * 512 + c] = v;
      }
    }
  }
}

// Merged xproj (bid<64) + beta2 (bid>=64): independent consumers of win.
__global__ __launch_bounds__(256) void k_xb(
    const float* __restrict__ win, const unsigned short* __restrict__ wih,
    const float* __restrict__ b_ih, const float* __restrict__ b_hh,
    float* __restrict__ gx, const float* __restrict__ W_tb1,
    const float* __restrict__ w_tb2, const float* __restrict__ tbias,
    float* __restrict__ z2) {
  __shared__ float xr[512];
  __shared__ float red[256];
  int bid0 = blockIdx.x;
  int tid = threadIdx.x;
  if (bid0 < 64) {
    int bid = bid0;
    int mt = bid >> 5, nt = bid & 31;
    int lane = tid & 63, wid = tid >> 6;
    int wrow = wid >> 1, wcol = wid & 1;
    int l16 = lane & 15, lk = lane >> 4;
    const float* ap[2];
    bool av[2];
#pragma unroll
    for (int fm = 0; fm < 2; ++fm) {
      int base = mt * 64 + wrow * 32 + fm * 16;
      av[fm] = base < 80;
      int grow = base + l16;
      int s = grow >> 3, b = grow & 7;
      ap[fm] = av[fm] ? (win + (size_t)(b * 120 + 11 + 12 * s) * 512 + lk * 8)
                      : win;
    }
    const unsigned short* bp[2];
#pragma unroll
    for (int fn = 0; fn < 2; ++fn)
      bp[fn] = wih + (size_t)(nt * 64 + wcol * 32 + fn * 16 + l16) * 512 + lk * 8;
    f32x4 acc[2][2] = {};
    for (int k0 = 0; k0 < 512; k0 += 64) {
#pragma unroll
      for (int kk = 0; kk < 2; ++kk) {
        int ko = k0 + kk * 32;
        short8 a8[2], b8[2];
#pragma unroll
        for (int fm = 0; fm < 2; ++fm) {
          if (av[fm]) {
            float4 x = *(const float4*)(ap[fm] + ko);
            float4 y = *(const float4*)(ap[fm] + ko + 4);
            float f[8] = {x.x, x.y, x.z, x.w, y.x, y.y, y.z, y.w};
            a8[fm] = mk8(f);
          } else {
            a8[fm] = short8{0, 0, 0, 0, 0, 0, 0, 0};
          }
        }
#pragma unroll
        for (int fn = 0; fn < 2; ++fn) b8[fn] = *(const short8*)(bp[fn] + ko);
#pragma unroll
        for (int fm = 0; fm < 2; ++fm)
#pragma unroll
          for (int fn = 0; fn < 2; ++fn)
            acc[fm][fn] = __builtin_amdgcn_mfma_f32_16x16x32_bf16(
                a8[fm], b8[fn], acc[fm][fn], 0, 0, 0);
      }
    }
#pragma unroll
    for (int fn = 0; fn < 2; ++fn) {
      int cg = nt * 64 + wcol * 32 + fn * 16 + l16;
      float bv = b_ih[cg] + b_hh[cg];
#pragma unroll
      for (int fm = 0; fm < 2; ++fm) {
        if (!av[fm]) continue;
#pragma unroll
        for (int r = 0; r < 4; ++r) {
          int grow = mt * 64 + wrow * 32 + fm * 16 + lk * 4 + r;
          if (grow < 80) gx[(size_t)grow * 2048 + cg] = acc[fm][fn][r] + bv;
        }
      }
    }
  } else {
    int bid = bid0 - 64;  // 0..79
    int b = bid / 10, si = bid - b * 10;
    int trow = b * 120 + 11 + 12 * si;
    for (int i = tid; i < 512; i += 256) xr[i] = win[(size_t)trow * 512 + i];
    __syncthreads();
    float val = 0;
    for (int jj = 0; jj < 2; ++jj) {
      int j = tid + jj * 256;
      float a = tbias[b * 512 + j];
      for (int i = 0; i < 512; ++i) a += xr[i] * W_tb1[(size_t)i * 512 + j];
      val += fast_tanh(a) * w_tb2[j];
    }
    red[tid] = val;
    __syncthreads();
    for (int s = 128; s; s >>= 1) {
      if (tid < s) red[tid] += red[tid + s];
      __syncthreads();
    }
    if (tid == 0) z2[bid] = red[0];
  }
}

// standalone xproj / beta2 (fallback path)
__global__ __launch_bounds__(256) void k_xproj(
    const float* __restrict__ win, const unsigned short* __restrict__ wih,
    const float* __restrict__ b_ih, const float* __restrict__ b_hh,
    float* __restrict__ gx) {
  int bid = blockIdx.x;
  int mt = bid >> 5, nt = bid & 31;
  int tid = threadIdx.x;
  int lane = tid & 63, wid = tid >> 6;
  int wrow = wid >> 1, wcol = wid & 1;
  int l16 = lane & 15, lk = lane >> 4;
  const float* ap[2];
  bool av[2];
#pragma unroll
  for (int fm = 0; fm < 2; ++fm) {
    int base = mt * 64 + wrow * 32 + fm * 16;
    av[fm] = base < 80;
    int grow = base + l16;
    int s = grow >> 3, b = grow & 7;
    ap[fm] = av[fm] ? (win + (size_t)(b * 120 + 11 + 12 * s) * 512 + lk * 8)
                    : win;
  }
  const unsigned short* bp[2];
#pragma unroll
  for (int fn = 0; fn < 2; ++fn)
    bp[fn] = wih + (size_t)(nt * 64 + wcol * 32 + fn * 16 + l16) * 512 + lk * 8;
  f32x4 acc[2][2] = {};
  for (int k0 = 0; k0 < 512; k0 += 64) {
#pragma unroll
    for (int kk = 0; kk < 2; ++kk) {
      int ko = k0 + kk * 32;
      short8 a8[2], b8[2];
#pragma unroll
      for (int fm = 0; fm < 2; ++fm) {
        if (av[fm]) {
          float4 x = *(const float4*)(ap[fm] + ko);
          float4 y = *(const float4*)(ap[fm] + ko + 4);
          float f[8] = {x.x, x.y, x.z, x.w, y.x, y.y, y.z, y.w};
          a8[fm] = mk8(f);
        } else {
          a8[fm] = short8{0, 0, 0, 0, 0, 0, 0, 0};
        }
      }
#pragma unroll
      for (int fn = 0; fn < 2; ++fn) b8[fn] = *(const short8*)(bp[fn] + ko);
#pragma unroll
      for (int fm = 0; fm < 2; ++fm)
#pragma unroll
        for (int fn = 0; fn < 2; ++fn)
          acc[fm][fn] = __builtin_amdgcn_mfma_f32_16x16x32_bf16(
              a8[fm], b8[fn], acc[fm][fn], 0, 0, 0);
    }
  }
#pragma unroll
  for (int fn = 0; fn < 2; ++fn) {
    int cg = nt * 64 + wcol * 32 + fn * 16 + l16;
    float bv = b_ih[cg] + b_hh[cg];
#pragma unroll
    for (int fm = 0; fm < 2; ++fm) {
      if (!av[fm]) continue;
#pragma unroll
      for (int r = 0; r < 4; ++r) {
        int grow = mt * 64 + wrow * 32 + fm * 16 + lk * 4 + r;
        if (grow < 80) gx[(size_t)grow * 2048 + cg] = acc[fm][fn][r] + bv;
      }
    }
  }
}

__global__ __launch_bounds__(256) void k_beta2(
    const float* __restrict__ within, const float* __restrict__ W_tb1,
    const float* __restrict__ w_tb2, const float* __restrict__ tbias,
    float* __restrict__ z2) {
  int bid = blockIdx.x;
  int b = bid / 10, si = bid - b * 10;
  int trow = b * 120 + 11 + 12 * si;
  int tid = threadIdx.x;
  __shared__ float xr[512];
  __shared__ float red[256];
  for (int i = tid; i < 512; i += 256) xr[i] = within[(size_t)trow * 512 + i];
  __syncthreads();
  float val = 0;
  for (int jj = 0; jj < 2; ++jj) {
    int j = tid + jj * 256;
    float a = tbias[b * 512 + j];
    for (int i = 0; i < 512; ++i) a += xr[i] * W_tb1[(size_t)i * 512 + j];
    val += fast_tanh(a) * w_tb2[j];
  }
  red[tid] = val;
  __syncthreads();
  for (int s = 128; s; s >>= 1) {
    if (tid < s) red[tid] += red[tid + s];
    __syncthreads();
  }
  if (tid == 0) z2[bid] = red[0];
}

// LSTM step (r7-validated; persistent variant REVERTED in r10 — its spin
// barrier cost more than 10 graph-replayed launches)
__global__ __launch_bounds__(128) void k_lstm_step(
    const float* __restrict__ hin, const unsigned short* __restrict__ whh,
    const float* __restrict__ gx, int s, float* __restrict__ hout,
    float* __restrict__ c_st) {
  int jb = blockIdx.x;
  int tid = threadIdx.x;
  int lane = tid & 63, kw = tid >> 6;
  int l16 = lane & 15, lk = lane >> 4;
  const float* ap = hin + (size_t)l16 * 512 + kw * 256 + lk * 8;
  const unsigned short* bp[4];
#pragma unroll
  for (int fn = 0; fn < 4; ++fn)
    bp[fn] = whh + (size_t)(fn * 512 + jb * 16 + l16) * 512 + kw * 256 + lk * 8;
  f32x4 acc[4] = {};
  for (int k0 = 0; k0 < 256; k0 += 64) {
#pragma unroll
    for (int kk = 0; kk < 2; ++kk) {
      int ko = k0 + kk * 32;
      float4 x = *(const float4*)(ap + ko);
      float4 y = *(const float4*)(ap + ko + 4);
      float f[8] = {x.x, x.y, x.z, x.w, y.x, y.y, y.z, y.w};
      short8 a8 = mk8(f);
#pragma unroll
      for (int fn = 0; fn < 4; ++fn) {
        short8 b8 = *(const short8*)(bp[fn] + ko);
        acc[fn] = __builtin_amdgcn_mfma_f32_16x16x32_bf16(a8, b8, acc[fn], 0, 0, 0);
      }
    }
  }
  __shared__ float part[4][64][4];
  if (kw == 1) {
#pragma unroll
    for (int fn = 0; fn < 4; ++fn)
#pragma unroll
      for (int r = 0; r < 4; ++r) part[fn][lane][r] = acc[fn][r];
  }
  __syncthreads();
  if (kw == 0 && lk < 2) {
    int j = jb * 16 + l16;
#pragma unroll
    for (int r = 0; r < 4; ++r) {
      int b = lk * 4 + r;
      const float* g = gx + (size_t)(s * 8 + b) * 2048;
      float gi = acc[0][r] + part[0][lane][r] + g[j];
      float gf = acc[1][r] + part[1][lane][r] + g[512 + j];
      float gg = acc[2][r] + part[2][lane][r] + g[1024 + j];
      float go = acc[3][r] + part[3][lane][r] + g[1536 + j];
      float c = sigf(gf) * c_st[b * 512 + j] + sigf(gi) * fast_tanh(gg);
      c_st[b * 512 + j] = c;
      hout[b * 512 + j] = sigf(go) * fast_tanh(c);
    }
  }
}

// MHA per (b,h,qc) (unchanged from r6-r9)
__global__ __launch_bounds__(256) void k_mha(const float* __restrict__ qb,
                                             const float* __restrict__ kb,
                                             const float* __restrict__ vb,
                                             float* __restrict__ ao) {
  int bh = blockIdx.x & 63, qc = blockIdx.x >> 6;
  int b = bh >> 3, h = bh & 7;
  __shared__ float ks[120 * 65];
  __shared__ float vs[120 * 65];
  __shared__ float ps[4][128];
  int tid = threadIdx.x;
  for (int i = 0; i < 30; ++i) {
    int idx = tid + 256 * i;
    int t = idx >> 6, d = idx & 63;
    size_t g = (size_t)(b * 120 + t) * 512 + h * 64 + d;
    ks[t * 65 + d] = kb[g];
    vs[t * 65 + d] = vb[g];
  }
  __syncthreads();
  int wv = tid >> 6, lane = tid & 63;
  for (int i = qc * 30 + wv; i < qc * 30 + 30; i += 4) {
    const float* qrow = qb + (size_t)(b * 120 + i) * 512 + h * 64;
    float s1 = 0, s2 = 0;
    for (int d = 0; d < 64; ++d) {
      float qd = qrow[d];
      s1 += qd * ks[lane * 65 + d];
      if (lane < 56) s2 += qd * ks[(lane + 64) * 65 + d];
    }
    s1 *= 0.125f;
    s2 *= 0.125f;
    if (lane >= 56) s2 = -1e30f;
    float mx = wredmax(fmaxf(s1, s2));
    float e1 = __expf(s1 - mx);
    float e2 = (lane < 56) ? __expf(s2 - mx) : 0.f;
    float sm = wredsum(e1 + e2);
    ps[wv][lane] = e1;
    ps[wv][64 + lane] = e2;
    float o = 0;
    for (int j = 0; j < 120; ++j) o += ps[wv][j] * vs[j * 65 + lane];
    ao[(size_t)(b * 120 + i) * 512 + h * 64 + lane] = o / sm;
  }
}

// LN with optional bf16 dual-write (for win -> winbf)
__global__ __launch_bounds__(256) void k_ln(const float* __restrict__ a,
                                            const float* __restrict__ bsrc,
                                            const float* __restrict__ g,
                                            const float* __restrict__ be,
                                            float* __restrict__ out,
                                            unsigned short* __restrict__ bfout) {
  int row = blockIdx.x * 4 + (threadIdx.x >> 6);
  int lane = threadIdx.x & 63;
  const float* pa = a + (size_t)row * 512;
  const float* pb = bsrc + (size_t)row * 512;
  float z[8];
  float s = 0;
#pragma unroll
  for (int ii = 0; ii < 8; ++ii) {
    int e = lane + 64 * ii;
    z[ii] = pa[e] + pb[e];
    s += z[ii];
  }
  float mean = wredsum(s) * (1.f / 512.f);
  float v = 0;
#pragma unroll
  for (int ii = 0; ii < 8; ++ii) {
    float d = z[ii] - mean;
    v += d * d;
  }
  float rstd = rsqrtf(wredsum(v) * (1.f / 512.f) + 1e-5f);
#pragma unroll
  for (int ii = 0; ii < 8; ++ii) {
    int e = lane + 64 * ii;
    float val = (z[ii] - mean) * rstd * g[e] + be[e];
    out[(size_t)row * 512 + e] = val;
    if (bfout) bfout[(size_t)row * 512 + e] = f2bf(val);
  }
}

__global__ __launch_bounds__(256) void k_hbias(const float* __restrict__ hT,
                                               const float* __restrict__ W_l1,
                                               const float* __restrict__ b_l1,
                                               float* __restrict__ hb) {
  int b = blockIdx.x >> 1, half = blockIdx.x & 1;
  int tid = threadIdx.x;
  __shared__ float hl[512];
  for (int i = tid; i < 512; i += 256) hl[i] = hT[b * 512 + i];
  __syncthreads();
  int j = half * 256 + tid;
  float a = b_l1[j];
  for (int i = 0; i < 512; ++i) a += hl[i] * W_l1[(size_t)(512 + i) * 512 + j];
  hb[b * 512 + j] = a;
}

// MFMA beta1 (unchanged, validated r7-r9)
__global__ __launch_bounds__(256) void k_beta1_bf(
    const unsigned short* __restrict__ winbf, const unsigned short* __restrict__ wl1bf,
    const float* __restrict__ w_l2, const float* __restrict__ hb,
    float* __restrict__ l1) {
  __shared__ float reds[4][64];
  int tid = threadIdx.x;
  int rowbase = blockIdx.x * 64;  // 15 blocks
  int lane = tid & 63, wid = tid >> 6;
  int l16 = lane & 15, lk = lane >> 4;
  const unsigned short* ap[4];
#pragma unroll
  for (int fm = 0; fm < 4; ++fm)
    ap[fm] = winbf + (size_t)(rowbase + fm * 16 + l16) * 512 + lk * 8;
  float ps[4][4] = {};
#pragma unroll
  for (int cs = 0; cs < 2; ++cs) {
    const unsigned short* bp[4];
#pragma unroll
    for (int fn = 0; fn < 4; ++fn)
      bp[fn] = wl1bf + (size_t)(cs * 256 + wid * 64 + fn * 16 + l16) * 512 + lk * 8;
    f32x4 acc[4][4] = {};
    for (int k0 = 0; k0 < 512; k0 += 32) {
      short8 a8[4], b8[4];
#pragma unroll
      for (int fm = 0; fm < 4; ++fm) a8[fm] = *(const short8*)(ap[fm] + k0);
#pragma unroll
      for (int fn = 0; fn < 4; ++fn) b8[fn] = *(const short8*)(bp[fn] + k0);
#pragma unroll
      for (int fm = 0; fm < 4; ++fm)
#pragma unroll
        for (int fn = 0; fn < 4; ++fn)
          acc[fm][fn] = __builtin_amdgcn_mfma_f32_16x16x32_bf16(
              a8[fm], b8[fn], acc[fm][fn], 0, 0, 0);
    }
#pragma unroll
    for (int fm = 0; fm < 4; ++fm)
#pragma unroll
      for (int r = 0; r < 4; ++r) {
        int grow = rowbase + fm * 16 + lk * 4 + r;
        int b = grow / 120;
#pragma unroll
        for (int fn = 0; fn < 4; ++fn) {
          int col = cs * 256 + wid * 64 + fn * 16 + l16;
          ps[fm][r] += fast_tanh(acc[fm][fn][r] + hb[b * 512 + col]) * w_l2[col];
        }
      }
  }
#pragma unroll
  for (int m = 1; m < 16; m <<= 1)
#pragma unroll
    for (int fm = 0; fm < 4; ++fm)
#pragma unroll
      for (int r = 0; r < 4; ++r) ps[fm][r] += __shfl_xor(ps[fm][r], m);
  if (l16 == 0) {
#pragma unroll
    for (int fm = 0; fm < 4; ++fm)
#pragma unroll
      for (int r = 0; r < 4; ++r) reds[wid][fm * 16 + lk * 4 + r] = ps[fm][r];
  }
  __syncthreads();
  if (tid < 64)
    l1[rowbase + tid] = reds[0][tid] + reds[1][tid] + reds[2][tid] + reds[3][tid];
}

// fallback fp32 beta1
__global__ __launch_bounds__(256) void k_beta1(
    const float* __restrict__ within, const float* __restrict__ W_l1,
    const float* __restrict__ w_l2, const float* __restrict__ hb,
    float* __restrict__ l1) {
  int bid = blockIdx.x;
  int r0 = bid * 4;
  int b = r0 / 120;
  int tid = threadIdx.x;
  __shared__ float xr[4][512];
  __shared__ float red[4][256];
  for (int i = tid; i < 2048; i += 256) xr[i >> 9][i & 511] = within[(size_t)r0 * 512 + i];
  __syncthreads();
  float v[4] = {0, 0, 0, 0};
  for (int jj = 0; jj < 2; ++jj) {
    int j = tid + jj * 256;
    float hbv = hb[b * 512 + j];
    float a0 = hbv, a1 = hbv, a2 = hbv, a3 = hbv;
    for (int i = 0; i < 512; ++i) {
      float ww = W_l1[(size_t)i * 512 + j];
      a0 += xr[0][i] * ww;
      a1 += xr[1][i] * ww;
      a2 += xr[2][i] * ww;
      a3 += xr[3][i] * ww;
    }
    float wl = w_l2[j];
    v[0] += fast_tanh(a0) * wl;
    v[1] += fast_tanh(a1) * wl;
    v[2] += fast_tanh(a2) * wl;
    v[3] += fast_tanh(a3) * wl;
  }
#pragma unroll
  for (int r = 0; r < 4; ++r) red[r][tid] = v[r];
  __syncthreads();
  for (int s = 128; s; s >>= 1) {
    if (tid < s)
      for (int r = 0; r < 4; ++r) red[r][tid] += red[r][tid + s];
    __syncthreads();
  }
  if (tid < 4) l1[r0 + tid] = red[tid][0];
}

__global__ __launch_bounds__(256) void k_final(
    const float* __restrict__ l1, const float* __restrict__ z2,
    const float* __restrict__ within, const float* __restrict__ hT,
    const float* __restrict__ cT, float* __restrict__ dout) {
  int b = blockIdx.x;
  int tid = threadIdx.x;
  __shared__ float temp[120];
  __shared__ float b2[10];
  int wv = tid >> 6, lane = tid & 63;
  if (wv == 1) {
    float v = (lane < 10) ? z2[b * 10 + lane] : -1e30f;
    float mx = wredmax(v);
    float e = (lane < 10) ? __expf(v - mx) : 0.f;
    float sm = wredsum(e);
    if (lane < 10) {
      float p = e / sm;
      b2[lane] = p;
      dout[O_B2 + b * 10 + lane] = p;
    }
  }
  if (wv == 0) {
    float v1 = l1[b * 120 + lane];
    float v2 = (lane + 64 < 120) ? l1[b * 120 + 64 + lane] : -1e30f;
    float mx = wredmax(fmaxf(v1, v2));
    float e1 = __expf(v1 - mx);
    float e2 = (lane + 64 < 120) ? __expf(v2 - mx) : 0.f;
    float sm = wredsum(e1 + e2);
    float p1 = e1 / sm;
    dout[O_B1 + b * 120 + lane] = p1;
    temp[lane] = p1;
    if (lane + 64 < 120) {
      float p2 = e2 / sm;
      dout[O_B1 + b * 120 + 64 + lane] = p2;
      temp[64 + lane] = p2;
    }
  }
  __syncthreads();
  for (int t = tid; t < 120; t += 256) temp[t] += b2[t / 12];
  __syncthreads();
  for (int hh = tid; hh < 512; hh += 256) {
    float o = 0;
    for (int t = 0; t < 120; ++t) o += temp[t] * within[(size_t)(b * 120 + t) * 512 + hh];
    dout[O_OUT + b * 512 + hh] = o;
    dout[O_HT + b * 512 + hh] = hT[b * 512 + hh];
    dout[O_CT + b * 512 + hh] = cT[b * 512 + hh];
  }
}

// ---------------------------------------------------------------
extern "C" void kernel_launch(void* const* d_in, const int* in_sizes, int n_in,
                              void* d_out, int out_size, void* d_ws, size_t ws_size,
                              hipStream_t stream) {
  const float* videos = (const float*)d_in[0];
  const float* sub_g  = (const float*)d_in[1];
  const float* obj_g  = (const float*)d_in[2];
  const float* W_ev   = (const float*)d_in[3];
  const float* b_ev   = (const float*)d_in[4];
  const float* W_el   = (const float*)d_in[5];
  const float* b_el   = (const float*)d_in[6];
  const float* W_ew   = (const float*)d_in[7];
  const float* b_ew   = (const float*)d_in[8];
  const float* W_sp1  = (const float*)d_in[9];
  const float* b_sp1  = (const float*)d_in[10];
  const float* w_sp2  = (const float*)d_in[11];
  const float* W_s2o  = (const float*)d_in[12];
  const float* b_s2o  = (const float*)d_in[13];
  const float* W_o2s  = (const float*)d_in[14];
  const float* b_o2s  = (const float*)d_in[15];
  const float* W_tv   = (const float*)d_in[16];
  const float* b_tv   = (const float*)d_in[17];
  const float* Wq     = (const float*)d_in[18];
  const float* bq     = (const float*)d_in[19];
  const float* Wk     = (const float*)d_in[20];
  const float* bk     = (const float*)d_in[21];
  const float* Wv     = (const float*)d_in[22];
  const float* bv     = (const float*)d_in[23];
  const float* Wo     = (const float*)d_in[24];
  const float* bo     = (const float*)d_in[25];
  const float* g1     = (const float*)d_in[26];
  const float* be1    = (const float*)d_in[27];
  const float* Wf1    = (const float*)d_in[28];
  const float* bf1    = (const float*)d_in[29];
  const float* Wf2    = (const float*)d_in[30];
  const float* bf2    = (const float*)d_in[31];
  const float* g2     = (const float*)d_in[32];
  const float* be2    = (const float*)d_in[33];
  const float* W_tr   = (const float*)d_in[34];
  const float* b_tr   = (const float*)d_in[35];
  const float* W_tb1  = (const float*)d_in[36];
  const float* b_tb1  = (const float*)d_in[37];
  const float* w_tb2  = (const float*)d_in[38];
  const float* W_ih   = (const float*)d_in[39];
  const float* W_hh   = (const float*)d_in[40];
  const float* b_ih   = (const float*)d_in[41];
  const float* b_hh   = (const float*)d_in[42];
  const float* W_l1   = (const float*)d_in[43];
  const float* b_l1   = (const float*)d_in[44];
  const float* w_l2   = (const float*)d_in[45];

  float* out = (float*)d_out;
  float* w = (float*)d_ws;

  float* ve_p   = w + OFF_VE;
  float* ssub_p = w + OFF_SSUB;
  float* sobj_p = w + OFF_SOBJ;
  float* wbs_p  = w + OFF_WBS;
  float* wbo_p  = w + OFF_WBO;
  float* tb_p   = w + OFF_TBIAS;
  float* orix_p = w + OFF_ORIX;
  float* x_p    = w + OFF_X;
  float* q_p    = w + OFF_Q;
  float* k_p    = w + OFF_K;
  float* v_p    = w + OFF_V;
  float* ao_p   = w + OFF_AO;
  float* attn_p = w + OFF_ATTN;
  float* x1_p   = w + OFF_X1;
  float* f1_p   = w + OFF_F1;
  float* f2_p   = w + OFF_F2;
  float* win_p  = w + OFF_WIN;
  float* z2_p   = w + OFF_Z2;
  float* h_p    = w + OFF_H0;           // h0[4096], h1[4096], c[4096]
  float* c_p    = h_p + 2 * 4096;
  float* hb_p   = w + OFF_HB;
  float* l1_p   = w + OFF_L1;

  unsigned short* wtbase = (unsigned short*)(w + OFF_WT);
  unsigned short* wevbf = wtbase;                    // [256][2048]
  unsigned short* w7bf  = wtbase + 524288;           // 7 x [512][512]
  unsigned short* wtvbf = w7bf;
  unsigned short* wqbf  = w7bf + 1 * 262144;
  unsigned short* wobf  = w7bf + 4 * 262144;
  unsigned short* wf1bf = w7bf + 5 * 262144;
  unsigned short* wf2bf = w7bf + 6 * 262144;
  unsigned short* wsp1bf = w7bf + 7 * 262144;        // [256][256]
  // big-path dedicated buffers
  unsigned short* wihbf  = (unsigned short*)(w + OFF_WIH);
  unsigned short* whhbf  = (unsigned short*)(w + OFF_WHH);
  unsigned short* wl1bf  = (unsigned short*)(w + OFF_WL1B);
  unsigned short* winbf_p = (unsigned short*)(w + OFF_WINBF);
  unsigned short* vebf_p = (unsigned short*)(w + OFF_VEBF);
  float* gx_p = w + OFF_Q;  // aliases dead Q (written post-mha by k_xb)
  const bool big = ws_size >= (size_t)OFF_END * 4;

  if (big) {
    k_wprep<<<1689, 256, 0, stream>>>(W_ev, W_tv, Wq, Wk, Wv, Wo, Wf1, Wf2,
                                      W_sp1, W_l1, W_ih, W_hh, sub_g, obj_g,
                                      W_ew, b_ew, b_sp1, W_tr, b_tr, W_tb1,
                                      b_tb1, wevbf, w7bf, wsp1bf, wl1bf, wihbf,
                                      whhbf, h_p, wbs_p, wbo_p, tb_p);
    k_gemm_ve_m97<<<600, 512, 0, stream>>>(videos, wevbf, b_ev, W_el, b_el,
                                           vebf_p);
    k_score_bf<<<600, 256, 0, stream>>>(vebf_p, wsp1bf, w_sp2, wbs_p, wbo_p,
                                        ssub_p, sobj_p);
    k_attend_bf<<<960, 256, 0, stream>>>(ssub_p, sobj_p, vebf_p, W_s2o, b_s2o,
                                         W_o2s, b_o2s, out + O_SATT,
                                         out + O_OATT, orix_p);
    k_gemm_h<<<120, 256, 0, stream>>>(orix_p, wtvbf, b_tv, b_tv, b_tv, x_p, 8, 1);
    k_gemm_h<<<360, 256, 0, stream>>>(x_p, wqbf, bq, bk, bv, q_p, 24, 0);
    k_mha<<<256, 256, 0, stream>>>(q_p, k_p, v_p, ao_p);
    k_gemm_h<<<120, 256, 0, stream>>>(ao_p, wobf, bo, bo, bo, attn_p, 8, 0);
    k_ln<<<240, 256, 0, stream>>>(x_p, attn_p, g1, be1, x1_p, nullptr);
    k_gemm_h<<<120, 256, 0, stream>>>(x1_p, wf1bf, bf1, bf1, bf1, f1_p, 8, 1);
    k_gemm_h<<<120, 256, 0, stream>>>(f1_p, wf2bf, bf2, bf2, bf2, f2_p, 8, 0);
    k_ln<<<240, 256, 0, stream>>>(x1_p, f2_p, g2, be2, win_p, winbf_p);
    k_xb<<<144, 256, 0, stream>>>(win_p, wihbf, b_ih, b_hh, gx_p, W_tb1, w_tb2,
                                  tb_p, z2_p);
    for (int s = 0; s < 10; ++s) {
      float* hin = h_p + (s & 1) * 4096;
      float* hout = h_p + ((s & 1) ^ 1) * 4096;
      k_lstm_step<<<32, 128, 0, stream>>>(hin, whhbf, gx_p, s, hout, c_p);
    }
    k_hbias<<<16, 256, 0, stream>>>(h_p, W_l1, b_l1, hb_p);
    k_beta1_bf<<<15, 256, 0, stream>>>(winbf_p, wl1bf, w_l2, hb_p, l1_p);
    k_final<<<8, 256, 0, stream>>>(l1_p, z2_p, win_p, h_p, c_p, out);
  } else {
    // fallback (r6/r7-validated small-ws path)
    unsigned short* wihbf_a = (unsigned short*)(w + OFF_Q + 163840);
    unsigned short* whhbf_a = (unsigned short*)(w + OFF_Q + 688128);
    k_zero<<<48, 256, 0, stream>>>(h_p, 3 * 4096);
    k_small0<<<8, 256, 0, stream>>>(sub_g, obj_g, W_ew, b_ew, W_sp1, b_sp1,
                                    W_tr, b_tr, W_tb1, b_tb1, wbs_p, wbo_p, tb_p);
    k_wconvT<<<128, 256, 0, stream>>>(W_ev, wevbf, 2048, 256);
    k_wconv7<<<448, 256, 0, stream>>>(W_tv, Wq, Wk, Wv, Wo, Wf1, Wf2, w7bf);
    k_gemm_ve_mfma<<<600, 256, 0, stream>>>(videos, wevbf, b_ev, W_el, b_el, ve_p);
    k_score<<<1200, 256, 0, stream>>>(ve_p, W_sp1, w_sp2, wbs_p, wbo_p, ssub_p, sobj_p);
    k_attend<<<960, 256, 0, stream>>>(ssub_p, sobj_p, ve_p, W_s2o, b_s2o, W_o2s,
                                      b_o2s, out + O_SATT, out + O_OATT, orix_p);
    k_gemm_h<<<120, 256, 0, stream>>>(orix_p, wtvbf, b_tv, b_tv, b_tv, x_p, 8, 1);
    k_gemm_h<<<360, 256, 0, stream>>>(x_p, wqbf, bq, bk, bv, q_p, 24, 0);
    k_mha<<<256, 256, 0, stream>>>(q_p, k_p, v_p, ao_p);
    k_gemm_h<<<120, 256, 0, stream>>>(ao_p, wobf, bo, bo, bo, attn_p, 8, 0);
    k_ln<<<240, 256, 0, stream>>>(x_p, attn_p, g1, be1, x1_p, nullptr);
    k_gemm_h<<<120, 256, 0, stream>>>(x1_p, wf1bf, bf1, bf1, bf1, f1_p, 8, 1);
    k_gemm_h<<<120, 256, 0, stream>>>(f1_p, wf2bf, bf2, bf2, bf2, f2_p, 8, 0);
    k_ln<<<240, 256, 0, stream>>>(x1_p, f2_p, g2, be2, win_p, nullptr);
    k_cvt2<<<1024, 256, 0, stream>>>(W_ih, W_hh, wihbf_a, whhbf_a);
    k_xproj<<<64, 256, 0, stream>>>(win_p, wihbf_a, b_ih, b_hh, gx_p);
    k_beta2<<<80, 256, 0, stream>>>(win_p, W_tb1, w_tb2, tb_p, z2_p);
    for (int s = 0; s < 10; ++s) {
      float* hin = h_p + (s & 1) * 4096;
      float* hout = h_p + ((s & 1) ^ 1) * 4096;
      k_lstm_step<<<32, 128, 0, stream>>>(hin, whhbf_a, gx_p, s, hout, c_p);
    }
    k_hbias<<<16, 256, 0, stream>>>(h_p, W_l1, b_l1, hb_p);
    k_beta1<<<240, 256, 0, stream>>>(win_p, W_l1, w_l2, hb_p, l1_p);
    k_final<<<8, 256, 0, stream>>>(l1_p, z2_p, win_p, h_p, c_p, out);
  }
}

// Round 11
// 630.956 us; speedup vs baseline: 1.1235x; 1.0042x over previous
//
#include <hip/hip_runtime.h>
#include <cstddef>
#include <cstdint>

#define B_ 8
#define T_ 120
#define NB_ 40
#define VD_ 2053
#define E_ 256
#define H_ 512
#define M_ 38400   // B*T*NB
#define R_ 960     // B*T

// ---------------- workspace layout (float offsets) ----------------
static constexpr size_t OFF_VE    = 0;                        // 38400*256 (fallback path only)
static constexpr size_t OFF_SSUB  = OFF_VE + (size_t)M_ * E_; // 38400
static constexpr size_t OFF_SOBJ  = OFF_SSUB + M_;
static constexpr size_t OFF_WBS   = OFF_SOBJ + M_;            // 8*256
static constexpr size_t OFF_WBO   = OFF_WBS + B_ * E_;
static constexpr size_t OFF_TBIAS = OFF_WBO + B_ * E_;        // 8*512
static constexpr size_t OFF_ORIX  = OFF_TBIAS + B_ * H_;      // 960*512 each below
static constexpr size_t OFF_X     = OFF_ORIX + (size_t)R_ * H_;
static constexpr size_t OFF_Q     = OFF_X    + (size_t)R_ * H_;
static constexpr size_t OFF_K     = OFF_Q    + (size_t)R_ * H_;
static constexpr size_t OFF_V     = OFF_K    + (size_t)R_ * H_;
static constexpr size_t OFF_AO    = OFF_V    + (size_t)R_ * H_;
static constexpr size_t OFF_ATTN  = OFF_AO   + (size_t)R_ * H_;
static constexpr size_t OFF_X1    = OFF_ATTN + (size_t)R_ * H_;
static constexpr size_t OFF_F1    = OFF_X1   + (size_t)R_ * H_;
static constexpr size_t OFF_F2    = OFF_F1   + (size_t)R_ * H_;
static constexpr size_t OFF_WIN   = OFF_F2   + (size_t)R_ * H_;
static constexpr size_t OFF_WT    = OFF_WIN  + (size_t)R_ * H_; // 2M floats (bf16 weights)
static constexpr size_t OFF_Z2    = OFF_WT + (size_t)1024 * 2048; // 80
static constexpr size_t OFF_H0    = OFF_Z2 + 128;               // h0,h1,c : 3*4096
static constexpr size_t OFF_HB    = OFF_H0 + 3 * 4096;          // 8*512
static constexpr size_t OFF_L1    = OFF_HB + B_ * H_;           // 960
static constexpr size_t OFF_BAR   = OFF_L1 + 960;               // 1 uint (unused, kept for layout)
static constexpr size_t OFF_END0  = OFF_BAR + 4;
// big-ws region (dedicated, non-aliased)
static constexpr size_t OFF_WIH   = (OFF_END0 + 3) & ~(size_t)3;     // 2048*512 ushort
static constexpr size_t OFF_WHH   = OFF_WIH + 524288;
static constexpr size_t OFF_WL1B  = OFF_WHH + 524288;                // 512*512 ushort
static constexpr size_t OFF_WINBF = OFF_WL1B + 131072;               // 960*512 ushort
static constexpr size_t OFF_VEBF  = OFF_WINBF + 245760;              // M*E ushort
static constexpr size_t OFF_END   = OFF_VEBF + (size_t)M_ * E_ / 2;  // ~23.8M floats

// ---------------- d_out layout (float offsets) ----------------
static constexpr size_t O_OUT  = 0;      // 8*512
static constexpr size_t O_HT   = 4096;   // 8*512
static constexpr size_t O_CT   = 8192;   // 8*512
static constexpr size_t O_SATT = 12288;  // 8*120*40
static constexpr size_t O_OATT = 50688;  // 8*120*40
static constexpr size_t O_B1   = 89088;  // 8*120
static constexpr size_t O_B2   = 90048;  // 8*10

#define DEVFN __device__ __forceinline__

typedef __attribute__((ext_vector_type(8))) short short8;
typedef __attribute__((ext_vector_type(4))) float f32x4;

DEVFN float sigf(float x) { return 1.0f / (1.0f + __expf(-x)); }

// inline tanh: no OCML call (round-1 lesson: tanhf caused VGPR spill disaster)
DEVFN float fast_tanh(float x) {
  float e = __expf(2.f * x);
  return 1.f - 2.f / (e + 1.f);
}

// fp32 -> bf16 RNE (validated r3)
DEVFN unsigned short f2bf(float x) {
  unsigned int u = __float_as_uint(x);
  u += 0x7FFFu + ((u >> 16) & 1u);
  return (unsigned short)(u >> 16);
}
DEVFN float bf2f(unsigned short u) { return __uint_as_float((unsigned int)u << 16); }

DEVFN short8 mk8(const float* f) {
  short8 r;
#pragma unroll
  for (int j = 0; j < 8; ++j) r[j] = (short)f2bf(f[j]);
  return r;
}

DEVFN float wredsum(float v) {
#pragma unroll
  for (int m = 32; m; m >>= 1) v += __shfl_xor(v, m);
  return v;
}
DEVFN float wredmax(float v) {
#pragma unroll
  for (int m = 32; m; m >>= 1) v = fmaxf(v, __shfl_xor(v, m));
  return v;
}

// ---------------------------------------------------------------
__global__ __launch_bounds__(256) void k_zero(float* p, int n) {
  int i = blockIdx.x * 256 + threadIdx.x;
  if (i < n) p[i] = 0.f;
}

// Per-batch small precompute (standalone, fallback path)
__global__ __launch_bounds__(256) void k_small0(
    const float* __restrict__ sub_g, const float* __restrict__ obj_g,
    const float* __restrict__ W_ew, const float* __restrict__ b_ew,
    const float* __restrict__ W_sp1, const float* __restrict__ b_sp1,
    const float* __restrict__ W_tr, const float* __restrict__ b_tr,
    const float* __restrict__ W_tb1, const float* __restrict__ b_tb1,
    float* __restrict__ wbs, float* __restrict__ wbo, float* __restrict__ tbias) {
  int b = blockIdx.x, tid = threadIdx.x;
  __shared__ float sg[300], og[300], se[256], oe[256], trl[512];
  for (int i = tid; i < 300; i += 256) { sg[i] = sub_g[b * 300 + i]; og[i] = obj_g[b * 300 + i]; }
  __syncthreads();
  {
    float a1 = b_ew[tid], a2 = a1;
    for (int w = 0; w < 300; ++w) {
      float we = W_ew[w * 256 + tid];
      a1 += sg[w] * we; a2 += og[w] * we;
    }
    se[tid] = fmaxf(a1, 0.f); oe[tid] = fmaxf(a2, 0.f);
  }
  __syncthreads();
  {
    float a1 = b_sp1[tid], a2 = a1;
    for (int e = 0; e < 256; ++e) {
      float ww = W_sp1[(256 + e) * 256 + tid];
      a1 += se[e] * ww; a2 += oe[e] * ww;
    }
    wbs[b * 256 + tid] = a1; wbo[b * 256 + tid] = a2;
  }
  for (int jj = 0; jj < 2; ++jj) {
    int j = tid + jj * 256;
    float a = b_tr[j];
    for (int i = 0; i < 256; ++i) a += se[i] * W_tr[i * 512 + j];
    for (int i = 0; i < 256; ++i) a += oe[i] * W_tr[(256 + i) * 512 + j];
    trl[j] = fmaxf(a, 0.f);
  }
  __syncthreads();
  for (int jj = 0; jj < 2; ++jj) {
    int j = tid + jj * 256;
    float a = b_tb1[j];
    for (int i = 0; i < 512; ++i) a += trl[i] * W_tb1[(size_t)(512 + i) * 512 + j];
    tbias[b * 512 + j] = a;
  }
}

// Unified prep kernel (big path): all weight converts + h/c zero + the
// 8 small0 blocks. Grid 1689.  (r10-validated)
__global__ __launch_bounds__(256) void k_wprep(
    const float* __restrict__ W_ev, const float* __restrict__ W_tv,
    const float* __restrict__ Wq, const float* __restrict__ Wk,
    const float* __restrict__ Wv, const float* __restrict__ Wo,
    const float* __restrict__ Wf1, const float* __restrict__ Wf2,
    const float* __restrict__ W_sp1, const float* __restrict__ W_l1,
    const float* __restrict__ W_ih, const float* __restrict__ W_hh,
    const float* __restrict__ sub_g, const float* __restrict__ obj_g,
    const float* __restrict__ W_ew, const float* __restrict__ b_ew,
    const float* __restrict__ b_sp1, const float* __restrict__ W_tr,
    const float* __restrict__ b_tr, const float* __restrict__ W_tb1,
    const float* __restrict__ b_tb1,
    unsigned short* __restrict__ wevbf, unsigned short* __restrict__ w7bf,
    unsigned short* __restrict__ wsp1bf, unsigned short* __restrict__ wl1bf,
    unsigned short* __restrict__ wihbf, unsigned short* __restrict__ whhbf,
    float* __restrict__ hz,
    float* __restrict__ wbs, float* __restrict__ wbo, float* __restrict__ tbias) {
  int bid = blockIdx.x, tid = threadIdx.x;
  __shared__ float shm[64 * 65];
  float (*t)[65] = (float(*)[65])shm;
  if (bid < 128) {
    int kb = bid >> 2, nb = bid & 3;
#pragma unroll
    for (int i = 0; i < 16; ++i) {
      int idx = tid + 256 * i; int r = idx >> 6, c = idx & 63;
      t[r][c] = W_ev[(size_t)(kb * 64 + r) * 256 + nb * 64 + c];
    }
    __syncthreads();
#pragma unroll
    for (int i = 0; i < 16; ++i) {
      int idx = tid + 256 * i; int n = idx >> 6, kk = idx & 63;
      wevbf[(size_t)(nb * 64 + n) * 2048 + kb * 64 + kk] = f2bf(t[kk][n]);
    }
  } else if (bid < 576) {
    int b2 = bid - 128;
    int wsel = b2 >> 6, sub = b2 & 63;
    int kb = sub >> 3, nb = sub & 7;
    const float* src = wsel == 0 ? W_tv : wsel == 1 ? Wq : wsel == 2 ? Wk
                     : wsel == 3 ? Wv : wsel == 4 ? Wo : wsel == 5 ? Wf1 : Wf2;
    unsigned short* dst = w7bf + (size_t)wsel * 262144;
#pragma unroll
    for (int i = 0; i < 16; ++i) {
      int idx = tid + 256 * i; int r = idx >> 6, c = idx & 63;
      t[r][c] = src[(size_t)(kb * 64 + r) * 512 + nb * 64 + c];
    }
    __syncthreads();
#pragma unroll
    for (int i = 0; i < 16; ++i) {
      int idx = tid + 256 * i; int n = idx >> 6, kk = idx & 63;
      dst[(size_t)(nb * 64 + n) * 512 + kb * 64 + kk] = f2bf(t[kk][n]);
    }
  } else if (bid < 592) {
    int b2 = bid - 576;
    int kb = b2 >> 2, nb = b2 & 3;
#pragma unroll
    for (int i = 0; i < 16; ++i) {
      int idx = tid + 256 * i; int r = idx >> 6, c = idx & 63;
      t[r][c] = W_sp1[(size_t)(kb * 64 + r) * 256 + nb * 64 + c];
    }
    __syncthreads();
#pragma unroll
    for (int i = 0; i < 16; ++i) {
      int idx = tid + 256 * i; int n = idx >> 6, kk = idx & 63;
      wsp1bf[(size_t)(nb * 64 + n) * 256 + kb * 64 + kk] = f2bf(t[kk][n]);
    }
  } else if (bid < 656) {
    int b2 = bid - 592;
    int kb = b2 >> 3, nb = b2 & 7;
#pragma unroll
    for (int i = 0; i < 16; ++i) {
      int idx = tid + 256 * i; int r = idx >> 6, c = idx & 63;
      t[r][c] = W_l1[(size_t)(kb * 64 + r) * 512 + nb * 64 + c];  // rows 0..511
    }
    __syncthreads();
#pragma unroll
    for (int i = 0; i < 16; ++i) {
      int idx = tid + 256 * i; int n = idx >> 6, kk = idx & 63;
      wl1bf[(size_t)(nb * 64 + n) * 512 + kb * 64 + kk] = f2bf(t[kk][n]);
    }
  } else if (bid < 1680) {
    int i = (bid - 656) * 256 + tid;
    const float* s; unsigned short* d; int off;
    if (i < 131072) { s = W_ih; d = wihbf; off = i * 8; }
    else            { s = W_hh; d = whhbf; off = (i - 131072) * 8; }
    float f[8];
#pragma unroll
    for (int j = 0; j < 8; ++j) f[j] = s[off + j];
    *(short8*)(d + off) = mk8(f);
  } else if (bid == 1680) {
    for (int i = tid; i < 12288; i += 256) hz[i] = 0.f;
  } else {
    // small0 body, b = bid - 1681 (8 blocks)
    int b = bid - 1681;
    float* sg = shm;         // 300
    float* og = shm + 300;   // 300
    float* se = shm + 600;   // 256
    float* oe = shm + 856;   // 256
    float* trl = shm + 1112; // 512
    for (int i = tid; i < 300; i += 256) { sg[i] = sub_g[b * 300 + i]; og[i] = obj_g[b * 300 + i]; }
    __syncthreads();
    {
      float a1 = b_ew[tid], a2 = a1;
      for (int w = 0; w < 300; ++w) {
        float we = W_ew[w * 256 + tid];
        a1 += sg[w] * we; a2 += og[w] * we;
      }
      se[tid] = fmaxf(a1, 0.f); oe[tid] = fmaxf(a2, 0.f);
    }
    __syncthreads();
    {
      float a1 = b_sp1[tid], a2 = a1;
      for (int e = 0; e < 256; ++e) {
        float ww = W_sp1[(256 + e) * 256 + tid];
        a1 += se[e] * ww; a2 += oe[e] * ww;
      }
      wbs[b * 256 + tid] = a1; wbo[b * 256 + tid] = a2;
    }
    for (int jj = 0; jj < 2; ++jj) {
      int j = tid + jj * 256;
      float a = b_tr[j];
      for (int i = 0; i < 256; ++i) a += se[i] * W_tr[i * 512 + j];
      for (int i = 0; i < 256; ++i) a += oe[i] * W_tr[(256 + i) * 512 + j];
      trl[j] = fmaxf(a, 0.f);
    }
    __syncthreads();
    for (int jj = 0; jj < 2; ++jj) {
      int j = tid + jj * 256;
      float a = b_tb1[j];
      for (int i = 0; i < 512; ++i) a += trl[i] * W_tb1[(size_t)(512 + i) * 512 + j];
      tbias[b * 512 + j] = a;
    }
  }
}

// Fallback converters (small-ws path)
__global__ __launch_bounds__(256) void k_wconvT(const float* __restrict__ src,
                                                unsigned short* __restrict__ dst,
                                                int K, int N) {
  __shared__ float t[64][65];
  int nblk = N >> 6;
  int kb = blockIdx.x / nblk, nb = blockIdx.x - kb * nblk;
  int tid = threadIdx.x;
#pragma unroll
  for (int i = 0; i < 16; ++i) {
    int idx = tid + 256 * i;
    int r = idx >> 6, c = idx & 63;
    t[r][c] = src[(size_t)(kb * 64 + r) * N + nb * 64 + c];
  }
  __syncthreads();
#pragma unroll
  for (int i = 0; i < 16; ++i) {
    int idx = tid + 256 * i;
    int n = idx >> 6, kk = idx & 63;
    dst[(size_t)(nb * 64 + n) * K + kb * 64 + kk] = f2bf(t[kk][n]);
  }
}

__global__ __launch_bounds__(256) void k_wconv7(
    const float* __restrict__ w0, const float* __restrict__ w1,
    const float* __restrict__ w2, const float* __restrict__ w3,
    const float* __restrict__ w4, const float* __restrict__ w5,
    const float* __restrict__ w6, unsigned short* __restrict__ dstb) {
  __shared__ float t[64][65];
  int wsel = blockIdx.x >> 6, sub = blockIdx.x & 63;
  int kb = sub >> 3, nb = sub & 7;
  const float* src = wsel == 0 ? w0 : wsel == 1 ? w1 : wsel == 2 ? w2
                   : wsel == 3 ? w3 : wsel == 4 ? w4 : wsel == 5 ? w5 : w6;
  unsigned short* dst = dstb + (size_t)wsel * 262144;
  int tid = threadIdx.x;
#pragma unroll
  for (int i = 0; i < 16; ++i) {
    int idx = tid + 256 * i;
    int r = idx >> 6, c = idx & 63;
    t[r][c] = src[(size_t)(kb * 64 + r) * 512 + nb * 64 + c];
  }
  __syncthreads();
#pragma unroll
  for (int i = 0; i < 16; ++i) {
    int idx = tid + 256 * i;
    int n = idx >> 6, kk = idx & 63;
    dst[(size_t)(nb * 64 + n) * 512 + kb * 64 + kk] = f2bf(t[kk][n]);
  }
}

__global__ __launch_bounds__(256) void k_cvt2(const float* __restrict__ a,
                                              const float* __restrict__ b,
                                              unsigned short* __restrict__ da,
                                              unsigned short* __restrict__ db) {
  int i = blockIdx.x * 256 + threadIdx.x;
  const float* s; unsigned short* d; int off;
  if (i < 131072) { s = a; d = da; off = i * 8; }
  else            { s = b; d = db; off = (i - 131072) * 8; }
  float f[8];
#pragma unroll
  for (int j = 0; j < 8; ++j) f[j] = s[off + j];
  *(short8*)(d + off) = mk8(f);
}

// ve GEMM, m97 structure + 2-DEEP A prefetch (r11): A loads now span TWO
// K-steps (HBM ~900cyc > one MFMA phase ~400cyc), statically double-buffered
// in registers (fa0/fa1, unrolled 2-half loop per rule #20). B stays 1-deep
// (L2-resident). Everything else identical to r7/r10-validated form.
#define VESTEP(FA, KA, KB)                                                 \
  {                                                                        \
    short8 ha = mk8(FA);                                                   \
    __syncthreads();                                                       \
    *(short8*)(lds + dstA) = ha;                                           \
    _Pragma("unroll")                                                      \
    for (int i = 0; i < 4; ++i) *(short8*)(lds + dstB[i]) = stB[i];        \
    __syncthreads();                                                       \
    _Pragma("unroll")                                                      \
    for (int j = 0; j < 8; ++j) FA[j] = apA[(KA) + j];                     \
    _Pragma("unroll")                                                      \
    for (int i = 0; i < 4; ++i) stB[i] = *(const short8*)(spB[i] + (KB));  \
    _Pragma("unroll")                                                      \
    for (int kk = 0; kk < 2; ++kk) {                                       \
      short8 a8[4], b8[2];                                                 \
      _Pragma("unroll")                                                    \
      for (int fm = 0; fm < 4; ++fm) {                                     \
        int row = fm * 16 + l16;                                           \
        a8[fm] = *(const short8*)(lds + row * 64 +                         \
                                  (((kk * 4 + lk) ^ (row & 7)) * 8));      \
      }                                                                    \
      _Pragma("unroll")                                                    \
      for (int fn = 0; fn < 2; ++fn) {                                     \
        int n = wid * 32 + fn * 16 + l16;                                  \
        b8[fn] = *(const short8*)(lds + 4096 + n * 64 +                    \
                                  (((kk * 4 + lk) ^ (n & 7)) * 8));        \
      }                                                                    \
      _Pragma("unroll")                                                    \
      for (int fm = 0; fm < 4; ++fm)                                       \
        _Pragma("unroll")                                                  \
        for (int fn = 0; fn < 2; ++fn)                                     \
          acc[fm][fn] = __builtin_amdgcn_mfma_f32_16x16x32_bf16(           \
              a8[fm], b8[fn], acc[fm][fn], 0, 0, 0);                       \
    }                                                                      \
  }

__global__ __launch_bounds__(512) void k_gemm_ve_m97(
    const float* __restrict__ videos, const unsigned short* __restrict__ wtbf,
    const float* __restrict__ bev, const float* __restrict__ Wel,
    const float* __restrict__ bel, unsigned short* __restrict__ vebf) {
  __shared__ __align__(16) unsigned short lds[20480];  // A: [0,4096) B: [4096,20480)
  int tid = threadIdx.x;
  int rowbase = blockIdx.x * 64;
  int lane = tid & 63, wid = tid >> 6;
  int l16 = lane & 15, lk = lane >> 4;

  // A staging: thread -> row=tid>>3, kc=tid&7 (8 fp32 -> bf16)
  int arow = tid >> 3, akc = tid & 7;
  const float* apA = videos + (size_t)(rowbase + arow) * VD_ + akc * 8;
  int dstA = arow * 64 + ((akc ^ (arow & 7)) * 8);
  // B staging: 4 chunks/thread
  const unsigned short* spB[4];
  int dstB[4];
#pragma unroll
  for (int i = 0; i < 4; ++i) {
    int g = tid + 512 * i;
    int n = g >> 3, kc = g & 7;
    spB[i] = wtbf + (size_t)n * 2048 + kc * 8;
    dstB[i] = 4096 + n * 64 + ((kc ^ (n & 7)) * 8);
  }
  float fa0[8], fa1[8];
  short8 stB[4];
#pragma unroll
  for (int j = 0; j < 8; ++j) fa0[j] = apA[j];         // tile 0
#pragma unroll
  for (int i = 0; i < 4; ++i) stB[i] = *(const short8*)(spB[i]);  // tile 0
#pragma unroll
  for (int j = 0; j < 8; ++j) fa1[j] = apA[64 + j];    // tile 64

  f32x4 acc[4][2] = {};
  for (int k0 = 0; k0 < 2048; k0 += 128) {
    int ka0 = k0 + 128; if (ka0 >= 2048) ka0 -= 2048;
    int kb0 = k0 + 64;
    VESTEP(fa0, ka0, kb0);           // computes tile k0
    int ka1 = k0 + 192; if (ka1 >= 2048) ka1 -= 2048;
    int kb1 = k0 + 128; if (kb1 >= 2048) kb1 -= 2048;
    VESTEP(fa1, ka1, kb1);           // computes tile k0+64
  }
  // epilogue: C/D map col=lane&15, row=(lane>>4)*4+reg (validated r3-r10)
  float bevv[2], belv[2], w5[5][2];
#pragma unroll
  for (int fn = 0; fn < 2; ++fn) {
    int col = wid * 32 + fn * 16 + l16;
    bevv[fn] = bev[col]; belv[fn] = bel[col];
#pragma unroll
    for (int kk = 0; kk < 5; ++kk) w5[kk][fn] = Wel[kk * 256 + col];
  }
#pragma unroll
  for (int fm = 0; fm < 4; ++fm) {
#pragma unroll
    for (int r = 0; r < 4; ++r) {
      int grow = rowbase + fm * 16 + lk * 4 + r;
      const float* vt = videos + (size_t)grow * VD_ + 2048;
      float t0 = vt[0], t1 = vt[1], t2 = vt[2], t3 = vt[3], t4 = vt[4];
      unsigned short* vob = vebf + (size_t)grow * 256;
#pragma unroll
      for (int fn = 0; fn < 2; ++fn) {
        int col = wid * 32 + fn * 16 + l16;
        float s2 = belv[fn] + t0 * w5[0][fn] + t1 * w5[1][fn] + t2 * w5[2][fn] +
                   t3 * w5[3][fn] + t4 * w5[4][fn];
        float vvv = fmaxf(acc[fm][fn][r] + bevv[fn], 0.f) + fmaxf(s2, 0.f);
        vob[col] = f2bf(vvv);
      }
    }
  }
}

// MFMA score kernel (unchanged, validated r5-r10)
__global__ __launch_bounds__(256) void k_score_bf(
    const unsigned short* __restrict__ vebf, const unsigned short* __restrict__ wsp1,
    const float* __restrict__ w_sp2, const float* __restrict__ wbs,
    const float* __restrict__ wbo, float* __restrict__ s_sub,
    float* __restrict__ s_obj) {
  __shared__ float reds[4][64], redo_[4][64];
  int tid = threadIdx.x;
  int rowbase = blockIdx.x * 64;
  int lane = tid & 63, wid = tid >> 6;
  int l16 = lane & 15, lk = lane >> 4;
  const unsigned short* ap[4];
  const unsigned short* bp[4];
#pragma unroll
  for (int fm = 0; fm < 4; ++fm)
    ap[fm] = vebf + (size_t)(rowbase + fm * 16 + l16) * 256 + lk * 8;
#pragma unroll
  for (int fn = 0; fn < 4; ++fn)
    bp[fn] = wsp1 + (size_t)(wid * 64 + fn * 16 + l16) * 256 + lk * 8;
  f32x4 acc[4][4] = {};
#pragma unroll 2
  for (int k0 = 0; k0 < 256; k0 += 32) {
    short8 a8[4], b8[4];
#pragma unroll
    for (int fm = 0; fm < 4; ++fm) a8[fm] = *(const short8*)(ap[fm] + k0);
#pragma unroll
    for (int fn = 0; fn < 4; ++fn) b8[fn] = *(const short8*)(bp[fn] + k0);
#pragma unroll
    for (int fm = 0; fm < 4; ++fm)
#pragma unroll
      for (int fn = 0; fn < 4; ++fn)
        acc[fm][fn] = __builtin_amdgcn_mfma_f32_16x16x32_bf16(
            a8[fm], b8[fn], acc[fm][fn], 0, 0, 0);
  }
  int b = rowbase / 4800;
  float w2[4], bs[4], bo[4];
#pragma unroll
  for (int fn = 0; fn < 4; ++fn) {
    int col = wid * 64 + fn * 16 + l16;
    w2[fn] = w_sp2[col];
    bs[fn] = wbs[b * 256 + col];
    bo[fn] = wbo[b * 256 + col];
  }
  float ps[4][4], po[4][4];
#pragma unroll
  for (int fm = 0; fm < 4; ++fm)
#pragma unroll
    for (int r = 0; r < 4; ++r) {
      float aps = 0, apo = 0;
#pragma unroll
      for (int fn = 0; fn < 4; ++fn) {
        float t = acc[fm][fn][r];
        aps += fast_tanh(t + bs[fn]) * w2[fn];
        apo += fast_tanh(t + bo[fn]) * w2[fn];
      }
      ps[fm][r] = aps;
      po[fm][r] = apo;
    }
#pragma unroll
  for (int m = 1; m < 16; m <<= 1) {
#pragma unroll
    for (int fm = 0; fm < 4; ++fm)
#pragma unroll
      for (int r = 0; r < 4; ++r) {
        ps[fm][r] += __shfl_xor(ps[fm][r], m);
        po[fm][r] += __shfl_xor(po[fm][r], m);
      }
  }
  if (l16 == 0) {
#pragma unroll
    for (int fm = 0; fm < 4; ++fm)
#pragma unroll
      for (int r = 0; r < 4; ++r) {
        int row = fm * 16 + lk * 4 + r;
        reds[wid][row] = ps[fm][r];
        redo_[wid][row] = po[fm][r];
      }
  }
  __syncthreads();
  if (tid < 64) {
    float s1 = reds[0][tid] + reds[1][tid] + reds[2][tid] + reds[3][tid];
    float s2 = redo_[0][tid] + redo_[1][tid] + redo_[2][tid] + redo_[3][tid];
    s_sub[rowbase + tid] = s1;
    s_obj[rowbase + tid] = s2;
  }
}

// attend from bf16 ve (unchanged, validated r6-r10)
__global__ __launch_bounds__(256) void k_attend_bf(
    const float* __restrict__ s_sub, const float* __restrict__ s_obj,
    const unsigned short* __restrict__ vebf, const float* __restrict__ W_s2o,
    const float* __restrict__ b_s2o, const float* __restrict__ W_o2s,
    const float* __restrict__ b_o2s, float* __restrict__ out_satt,
    float* __restrict__ out_oatt, float* __restrict__ orix) {
  int row = blockIdx.x;
  int tid = threadIdx.x;
  __shared__ float alds[2][40];
  int wv = tid >> 6, lane = tid & 63;
  if (wv < 2) {
    const float* sarr = (wv ? s_obj : s_sub) + row * 40;
    float v = (lane < 40) ? sarr[lane] : -1e30f;
    float mx = wredmax(v);
    float e = (lane < 40) ? __expf(v - mx) : 0.f;
    float sm = wredsum(e);
    float p = e / sm;
    if (lane < 40) {
      alds[wv][lane] = p;
      (wv ? out_oatt : out_satt)[row * 40 + lane] = p;
    }
  }
  __syncthreads();
  int e = tid;
  const unsigned short* vrow = vebf + (size_t)row * 40 * 256;
  float sf = 0, of = 0, s2o = b_s2o[e], o2s = b_o2s[e];
  for (int n = 0; n < 40; ++n) {
    float as = alds[0][n], aob = alds[1][n];
    float vv = bf2f(vrow[n * 256 + e]);
    sf += as * vv;
    of += aob * vv;
    s2o += as * W_s2o[n * 256 + e];
    o2s += aob * W_o2s[n * 256 + e];
  }
  s2o = fmaxf(s2o, 0.f);
  o2s = fmaxf(o2s, 0.f);
  orix[(size_t)row * 512 + e] = sf + o2s;
  orix[(size_t)row * 512 + 256 + e] = of + s2o;
}

// --------- fallback kernels (small-ws path, r6/r7-validated) -------
__global__ __launch_bounds__(256) void k_gemm_ve_mfma(
    const float* __restrict__ videos, const unsigned short* __restrict__ wtbf,
    const float* __restrict__ bev, const float* __restrict__ Wel,
    const float* __restrict__ bel, float* __restrict__ ve) {
  int tid = threadIdx.x;
  int rowbase = blockIdx.x * 64;
  int lane = tid & 63, wid = tid >> 6;
  int l16 = lane & 15, lk = lane >> 4;
  const float* ap[4];
  const unsigned short* bp[4];
#pragma unroll
  for (int fm = 0; fm < 4; ++fm)
    ap[fm] = videos + (size_t)(rowbase + fm * 16 + l16) * VD_ + lk * 8;
#pragma unroll
  for (int fn = 0; fn < 4; ++fn)
    bp[fn] = wtbf + (size_t)(wid * 64 + fn * 16 + l16) * 2048 + lk * 8;
  f32x4 acc[4][4] = {};
  for (int k0 = 0; k0 < 2048; k0 += 64) {
#pragma unroll
    for (int kk = 0; kk < 2; ++kk) {
      int ko = k0 + kk * 32;
      short8 a8[4], b8[4];
#pragma unroll
      for (int fm = 0; fm < 4; ++fm) {
        const float* a = ap[fm] + ko;
        float f[8];
#pragma unroll
        for (int j = 0; j < 8; ++j) f[j] = a[j];
        a8[fm] = mk8(f);
      }
#pragma unroll
      for (int fn = 0; fn < 4; ++fn) b8[fn] = *(const short8*)(bp[fn] + ko);
#pragma unroll
      for (int fm = 0; fm < 4; ++fm)
#pragma unroll
        for (int fn = 0; fn < 4; ++fn)
          acc[fm][fn] = __builtin_amdgcn_mfma_f32_16x16x32_bf16(
              a8[fm], b8[fn], acc[fm][fn], 0, 0, 0);
    }
    if ((k0 & 255) == 192) __builtin_amdgcn_s_barrier();
  }
  float bevv[4], belv[4], w5[5][4];
#pragma unroll
  for (int fn = 0; fn < 4; ++fn) {
    int col = wid * 64 + fn * 16 + l16;
    bevv[fn] = bev[col]; belv[fn] = bel[col];
#pragma unroll
    for (int kk = 0; kk < 5; ++kk) w5[kk][fn] = Wel[kk * 256 + col];
  }
#pragma unroll
  for (int fm = 0; fm < 4; ++fm) {
#pragma unroll
    for (int r = 0; r < 4; ++r) {
      int grow = rowbase + fm * 16 + lk * 4 + r;
      const float* vt = videos + (size_t)grow * VD_ + 2048;
      float t0 = vt[0], t1 = vt[1], t2 = vt[2], t3 = vt[3], t4 = vt[4];
      float* vo = ve + (size_t)grow * 256;
#pragma unroll
      for (int fn = 0; fn < 4; ++fn) {
        int col = wid * 64 + fn * 16 + l16;
        float s2 = belv[fn] + t0 * w5[0][fn] + t1 * w5[1][fn] + t2 * w5[2][fn] +
                   t3 * w5[3][fn] + t4 * w5[4][fn];
        vo[col] = fmaxf(acc[fm][fn][r] + bevv[fn], 0.f) + fmaxf(s2, 0.f);
      }
    }
  }
}

__global__ __launch_bounds__(256) void k_score(
    const float* __restrict__ ve, const float* __restrict__ W_sp1,
    const float* __restrict__ w_sp2, const float* __restrict__ wbs,
    const float* __restrict__ wbo, float* __restrict__ s_sub,
    float* __restrict__ s_obj) {
  __shared__ float vel[32][264];
  int tid = threadIdx.x;
  int rowbase = blockIdx.x * 32;
  for (int i = tid; i < 2048; i += 256) {
    int r = i >> 6, c = (i & 63) << 2;
    *(float4*)&vel[r][c] = *(const float4*)&ve[(size_t)(rowbase + r) * 256 + c];
  }
  __syncthreads();
  int wv = tid >> 6, lane = tid & 63;
  int r0 = wv * 8;
  float acc[8][4] = {};
  for (int k = 0; k < 256; ++k) {
    float w4[4];
#pragma unroll
    for (int c = 0; c < 4; ++c) w4[c] = W_sp1[(size_t)k * 256 + c * 64 + lane];
#pragma unroll
    for (int m = 0; m < 8; ++m) {
      float a = vel[r0 + m][k];
#pragma unroll
      for (int c = 0; c < 4; ++c) acc[m][c] += a * w4[c];
    }
  }
  int b = rowbase / 4800;
  float w2[4], bs[4], bo[4];
#pragma unroll
  for (int c = 0; c < 4; ++c) {
    int col = c * 64 + lane;
    w2[c] = w_sp2[col];
    bs[c] = wbs[b * 256 + col];
    bo[c] = wbo[b * 256 + col];
  }
#pragma unroll
  for (int m = 0; m < 8; ++m) {
    float ps = 0, po = 0;
#pragma unroll
    for (int c = 0; c < 4; ++c) {
      float t = acc[m][c];
      ps += fast_tanh(t + bs[c]) * w2[c];
      po += fast_tanh(t + bo[c]) * w2[c];
    }
    ps = wredsum(ps);
    po = wredsum(po);
    if (lane == 0) {
      s_sub[rowbase + r0 + m] = ps;
      s_obj[rowbase + r0 + m] = po;
    }
  }
}

__global__ __launch_bounds__(256) void k_attend(
    const float* __restrict__ s_sub, const float* __restrict__ s_obj,
    const float* __restrict__ ve, const float* __restrict__ W_s2o,
    const float* __restrict__ b_s2o, const float* __restrict__ W_o2s,
    const float* __restrict__ b_o2s, float* __restrict__ out_satt,
    float* __restrict__ out_oatt, float* __restrict__ orix) {
  int row = blockIdx.x;
  int tid = threadIdx.x;
  __shared__ float alds[2][40];
  int wv = tid >> 6, lane = tid & 63;
  if (wv < 2) {
    const float* sarr = (wv ? s_obj : s_sub) + row * 40;
    float v = (lane < 40) ? sarr[lane] : -1e30f;
    float mx = wredmax(v);
    float e = (lane < 40) ? __expf(v - mx) : 0.f;
    float sm = wredsum(e);
    float p = e / sm;
    if (lane < 40) {
      alds[wv][lane] = p;
      (wv ? out_oatt : out_satt)[row * 40 + lane] = p;
    }
  }
  __syncthreads();
  int e = tid;
  const float* vrow = ve + (size_t)row * 40 * 256;
  float sf = 0, of = 0, s2o = b_s2o[e], o2s = b_o2s[e];
  for (int n = 0; n < 40; ++n) {
    float as = alds[0][n], aob = alds[1][n];
    float vv = vrow[n * 256 + e];
    sf += as * vv;
    of += aob * vv;
    s2o += as * W_s2o[n * 256 + e];
    o2s += aob * W_o2s[n * 256 + e];
  }
  s2o = fmaxf(s2o, 0.f);
  o2s = fmaxf(o2s, 0.f);
  orix[(size_t)row * 512 + e] = sf + o2s;
  orix[(size_t)row * 512 + 256 + e] = of + s2o;
}

// Generic H-GEMM, LDS-free MFMA. r11: BM 64->32 (grid x2: 240/720 blocks) —
// the 120-block version left >half the CUs idle on 4 serial calls. Wave tile
// 16x32 (1 A-frag, 2 B-frags). No LDS staging, operands L2-resident, so the
// extra per-block A re-reads are cache hits (r8's HBM-duplication issue N/A).
__global__ __launch_bounds__(256) void k_gemm_h(
    const float* __restrict__ A, const unsigned short* __restrict__ WT,
    const float* __restrict__ b0, const float* __restrict__ b1,
    const float* __restrict__ b2, float* __restrict__ Cbase, int ntiles,
    int relu) {
  int tid = threadIdx.x;
  int bid = blockIdx.x;
  int mt = bid / ntiles, nt = bid - mt * ntiles;
  int rowbase = mt * 32;
  int lane = tid & 63, wid = tid >> 6;
  int wrow = wid >> 1, wcol = wid & 1;
  int l16 = lane & 15, lk = lane >> 4;
  const float* ap = A + (size_t)(rowbase + wrow * 16 + l16) * 512 + lk * 8;
  const unsigned short* bp[2];
#pragma unroll
  for (int fn = 0; fn < 2; ++fn)
    bp[fn] = WT + (size_t)(nt * 64 + wcol * 32 + fn * 16 + l16) * 512 + lk * 8;
  f32x4 acc[2] = {};
  for (int k0 = 0; k0 < 512; k0 += 64) {
#pragma unroll
    for (int kk = 0; kk < 2; ++kk) {
      int ko = k0 + kk * 32;
      float4 x = *(const float4*)(ap + ko);
      float4 y = *(const float4*)(ap + ko + 4);
      float f[8] = {x.x, x.y, x.z, x.w, y.x, y.y, y.z, y.w};
      short8 a8 = mk8(f);
#pragma unroll
      for (int fn = 0; fn < 2; ++fn) {
        short8 b8 = *(const short8*)(bp[fn] + ko);
        acc[fn] = __builtin_amdgcn_mfma_f32_16x16x32_bf16(a8, b8, acc[fn], 0, 0, 0);
      }
    }
  }
#pragma unroll
  for (int fn = 0; fn < 2; ++fn) {
    int cg = nt * 64 + wcol * 32 + fn * 16 + l16;
    int third = cg >> 9, c = cg & 511;
    const float* bb = third == 0 ? b0 : (third == 1 ? b1 : b2);
    float bv = bb[c];
    float* outp = Cbase + (size_t)third * ((size_t)R_ * H_);
#pragma unroll
    for (int r = 0; r < 4; ++r) {
      int grow = rowbase + wrow * 16 + lk * 4 + r;
      float v = acc[fn][r] + bv;
      if (relu) v = fmaxf(v, 0.f);
      outp[(size_t)grow * 512 + c] = v;
    }
  }
}

// Merged xproj (bid<64) + beta2 (bid>=64) (r10-validated)
__global__ __launch_bounds__(256) void k_xb(
    const float* __restrict__ win, const unsigned short* __restrict__ wih,
    const float* __restrict__ b_ih, const float* __restrict__ b_hh,
    float* __restrict__ gx, const float* __restrict__ W_tb1,
    const float* __restrict__ w_tb2, const float* __restrict__ tbias,
    float* __restrict__ z2) {
  __shared__ float xr[512];
  __shared__ float red[256];
  int bid0 = blockIdx.x;
  int tid = threadIdx.x;
  if (bid0 < 64) {
    int bid = bid0;
    int mt = bid >> 5, nt = bid & 31;
    int lane = tid & 63, wid = tid >> 6;
    int wrow = wid >> 1, wcol = wid & 1;
    int l16 = lane & 15, lk = lane >> 4;
    const float* ap[2];
    bool av[2];
#pragma unroll
    for (int fm = 0; fm < 2; ++fm) {
      int base = mt * 64 + wrow * 32 + fm * 16;
      av[fm] = base < 80;
      int grow = base + l16;
      int s = grow >> 3, b = grow & 7;
      ap[fm] = av[fm] ? (win + (size_t)(b * 120 + 11 + 12 * s) * 512 + lk * 8)
                      : win;
    }
    const unsigned short* bp[2];
#pragma unroll
    for (int fn = 0; fn < 2; ++fn)
      bp[fn] = wih + (size_t)(nt * 64 + wcol * 32 + fn * 16 + l16) * 512 + lk * 8;
    f32x4 acc[2][2] = {};
    for (int k0 = 0; k0 < 512; k0 += 64) {
#pragma unroll
      for (int kk = 0; kk < 2; ++kk) {
        int ko = k0 + kk * 32;
        short8 a8[2], b8[2];
#pragma unroll
        for (int fm = 0; fm < 2; ++fm) {
          if (av[fm]) {
            float4 x = *(const float4*)(ap[fm] + ko);
            float4 y = *(const float4*)(ap[fm] + ko + 4);
            float f[8] = {x.x, x.y, x.z, x.w, y.x, y.y, y.z, y.w};
            a8[fm] = mk8(f);
          } else {
            a8[fm] = short8{0, 0, 0, 0, 0, 0, 0, 0};
          }
        }
#pragma unroll
        for (int fn = 0; fn < 2; ++fn) b8[fn] = *(const short8*)(bp[fn] + ko);
#pragma unroll
        for (int fm = 0; fm < 2; ++fm)
#pragma unroll
          for (int fn = 0; fn < 2; ++fn)
            acc[fm][fn] = __builtin_amdgcn_mfma_f32_16x16x32_bf16(
                a8[fm], b8[fn], acc[fm][fn], 0, 0, 0);
      }
    }
#pragma unroll
    for (int fn = 0; fn < 2; ++fn) {
      int cg = nt * 64 + wcol * 32 + fn * 16 + l16;
      float bv = b_ih[cg] + b_hh[cg];
#pragma unroll
      for (int fm = 0; fm < 2; ++fm) {
        if (!av[fm]) continue;
#pragma unroll
        for (int r = 0; r < 4; ++r) {
          int grow = mt * 64 + wrow * 32 + fm * 16 + lk * 4 + r;
          if (grow < 80) gx[(size_t)grow * 2048 + cg] = acc[fm][fn][r] + bv;
        }
      }
    }
  } else {
    int bid = bid0 - 64;  // 0..79
    int b = bid / 10, si = bid - b * 10;
    int trow = b * 120 + 11 + 12 * si;
    for (int i = tid; i < 512; i += 256) xr[i] = win[(size_t)trow * 512 + i];
    __syncthreads();
    float val = 0;
    for (int jj = 0; jj < 2; ++jj) {
      int j = tid + jj * 256;
      float a = tbias[b * 512 + j];
      for (int i = 0; i < 512; ++i) a += xr[i] * W_tb1[(size_t)i * 512 + j];
      val += fast_tanh(a) * w_tb2[j];
    }
    red[tid] = val;
    __syncthreads();
    for (int s = 128; s; s >>= 1) {
      if (tid < s) red[tid] += red[tid + s];
      __syncthreads();
    }
    if (tid == 0) z2[bid] = red[0];
  }
}

// standalone xproj / beta2 (fallback path)
__global__ __launch_bounds__(256) void k_xproj(
    const float* __restrict__ win, const unsigned short* __restrict__ wih,
    const float* __restrict__ b_ih, const float* __restrict__ b_hh,
    float* __restrict__ gx) {
  int bid = blockIdx.x;
  int mt = bid >> 5, nt = bid & 31;
  int tid = threadIdx.x;
  int lane = tid & 63, wid = tid >> 6;
  int wrow = wid >> 1, wcol = wid & 1;
  int l16 = lane & 15, lk = lane >> 4;
  const float* ap[2];
  bool av[2];
#pragma unroll
  for (int fm = 0; fm < 2; ++fm) {
    int base = mt * 64 + wrow * 32 + fm * 16;
    av[fm] = base < 80;
    int grow = base + l16;
    int s = grow >> 3, b = grow & 7;
    ap[fm] = av[fm] ? (win + (size_t)(b * 120 + 11 + 12 * s) * 512 + lk * 8)
                    : win;
  }
  const unsigned short* bp[2];
#pragma unroll
  for (int fn = 0; fn < 2; ++fn)
    bp[fn] = wih + (size_t)(nt * 64 + wcol * 32 + fn * 16 + l16) * 512 + lk * 8;
  f32x4 acc[2][2] = {};
  for (int k0 = 0; k0 < 512; k0 += 64) {
#pragma unroll
    for (int kk = 0; kk < 2; ++kk) {
      int ko = k0 + kk * 32;
      short8 a8[2], b8[2];
#pragma unroll
      for (int fm = 0; fm < 2; ++fm) {
        if (av[fm]) {
          float4 x = *(const float4*)(ap[fm] + ko);
          float4 y = *(const float4*)(ap[fm] + ko + 4);
          float f[8] = {x.x, x.y, x.z, x.w, y.x, y.y, y.z, y.w};
          a8[fm] = mk8(f);
        } else {
          a8[fm] = short8{0, 0, 0, 0, 0, 0, 0, 0};
        }
      }
#pragma unroll
      for (int fn = 0; fn < 2; ++fn) b8[fn] = *(const short8*)(bp[fn] + ko);
#pragma unroll
      for (int fm = 0; fm < 2; ++fm)
#pragma unroll
        for (int fn = 0; fn < 2; ++fn)
          acc[fm][fn] = __builtin_amdgcn_mfma_f32_16x16x32_bf16(
              a8[fm], b8[fn], acc[fm][fn], 0, 0, 0);
    }
  }
#pragma unroll
  for (int fn = 0; fn < 2; ++fn) {
    int cg = nt * 64 + wcol * 32 + fn * 16 + l16;
    float bv = b_ih[cg] + b_hh[cg];
#pragma unroll
    for (int fm = 0; fm < 2; ++fm) {
      if (!av[fm]) continue;
#pragma unroll
      for (int r = 0; r < 4; ++r) {
        int grow = mt * 64 + wrow * 32 + fm * 16 + lk * 4 + r;
        if (grow < 80) gx[(size_t)grow * 2048 + cg] = acc[fm][fn][r] + bv;
      }
    }
  }
}

__global__ __launch_bounds__(256) void k_beta2(
    const float* __restrict__ within, const float* __restrict__ W_tb1,
    const float* __restrict__ w_tb2, const float* __restrict__ tbias,
    float* __restrict__ z2) {
  int bid = blockIdx.x;
  int b = bid / 10, si = bid - b * 10;
  int trow = b * 120 + 11 + 12 * si;
  int tid = threadIdx.x;
  __shared__ float xr[512];
  __shared__ float red[256];
  for (int i = tid; i < 512; i += 256) xr[i] = within[(size_t)trow * 512 + i];
  __syncthreads();
  float val = 0;
  for (int jj = 0; jj < 2; ++jj) {
    int j = tid + jj * 256;
    float a = tbias[b * 512 + j];
    for (int i = 0; i < 512; ++i) a += xr[i] * W_tb1[(size_t)i * 512 + j];
    val += fast_tanh(a) * w_tb2[j];
  }
  red[tid] = val;
  __syncthreads();
  for (int s = 128; s; s >>= 1) {
    if (tid < s) red[tid] += red[tid + s];
    __syncthreads();
  }
  if (tid == 0) z2[bid] = red[0];
}

// LSTM step (r7/r10-validated)
__global__ __launch_bounds__(128) void k_lstm_step(
    const float* __restrict__ hin, const unsigned short* __restrict__ whh,
    const float* __restrict__ gx, int s, float* __restrict__ hout,
    float* __restrict__ c_st) {
  int jb = blockIdx.x;
  int tid = threadIdx.x;
  int lane = tid & 63, kw = tid >> 6;
  int l16 = lane & 15, lk = lane >> 4;
  const float* ap = hin + (size_t)l16 * 512 + kw * 256 + lk * 8;
  const unsigned short* bp[4];
#pragma unroll
  for (int fn = 0; fn < 4; ++fn)
    bp[fn] = whh + (size_t)(fn * 512 + jb * 16 + l16) * 512 + kw * 256 + lk * 8;
  f32x4 acc[4] = {};
  for (int k0 = 0; k0 < 256; k0 += 64) {
#pragma unroll
    for (int kk = 0; kk < 2; ++kk) {
      int ko = k0 + kk * 32;
      float4 x = *(const float4*)(ap + ko);
      float4 y = *(const float4*)(ap + ko + 4);
      float f[8] = {x.x, x.y, x.z, x.w, y.x, y.y, y.z, y.w};
      short8 a8 = mk8(f);
#pragma unroll
      for (int fn = 0; fn < 4; ++fn) {
        short8 b8 = *(const short8*)(bp[fn] + ko);
        acc[fn] = __builtin_amdgcn_mfma_f32_16x16x32_bf16(a8, b8, acc[fn], 0, 0, 0);
      }
    }
  }
  __shared__ float part[4][64][4];
  if (kw == 1) {
#pragma unroll
    for (int fn = 0; fn < 4; ++fn)
#pragma unroll
      for (int r = 0; r < 4; ++r) part[fn][lane][r] = acc[fn][r];
  }
  __syncthreads();
  if (kw == 0 && lk < 2) {
    int j = jb * 16 + l16;
#pragma unroll
    for (int r = 0; r < 4; ++r) {
      int b = lk * 4 + r;
      const float* g = gx + (size_t)(s * 8 + b) * 2048;
      float gi = acc[0][r] + part[0][lane][r] + g[j];
      float gf = acc[1][r] + part[1][lane][r] + g[512 + j];
      float gg = acc[2][r] + part[2][lane][r] + g[1024 + j];
      float go = acc[3][r] + part[3][lane][r] + g[1536 + j];
      float c = sigf(gf) * c_st[b * 512 + j] + sigf(gi) * fast_tanh(gg);
      c_st[b * 512 + j] = c;
      hout[b * 512 + j] = sigf(go) * fast_tanh(c);
    }
  }
}

// MHA per (b,h,qc) (unchanged from r6-r10)
__global__ __launch_bounds__(256) void k_mha(const float* __restrict__ qb,
                                             const float* __restrict__ kb,
                                             const float* __restrict__ vb,
                                             float* __restrict__ ao) {
  int bh = blockIdx.x & 63, qc = blockIdx.x >> 6;
  int b = bh >> 3, h = bh & 7;
  __shared__ float ks[120 * 65];
  __shared__ float vs[120 * 65];
  __shared__ float ps[4][128];
  int tid = threadIdx.x;
  for (int i = 0; i < 30; ++i) {
    int idx = tid + 256 * i;
    int t = idx >> 6, d = idx & 63;
    size_t g = (size_t)(b * 120 + t) * 512 + h * 64 + d;
    ks[t * 65 + d] = kb[g];
    vs[t * 65 + d] = vb[g];
  }
  __syncthreads();
  int wv = tid >> 6, lane = tid & 63;
  for (int i = qc * 30 + wv; i < qc * 30 + 30; i += 4) {
    const float* qrow = qb + (size_t)(b * 120 + i) * 512 + h * 64;
    float s1 = 0, s2 = 0;
    for (int d = 0; d < 64; ++d) {
      float qd = qrow[d];
      s1 += qd * ks[lane * 65 + d];
      if (lane < 56) s2 += qd * ks[(lane + 64) * 65 + d];
    }
    s1 *= 0.125f;
    s2 *= 0.125f;
    if (lane >= 56) s2 = -1e30f;
    float mx = wredmax(fmaxf(s1, s2));
    float e1 = __expf(s1 - mx);
    float e2 = (lane < 56) ? __expf(s2 - mx) : 0.f;
    float sm = wredsum(e1 + e2);
    ps[wv][lane] = e1;
    ps[wv][64 + lane] = e2;
    float o = 0;
    for (int j = 0; j < 120; ++j) o += ps[wv][j] * vs[j * 65 + lane];
    ao[(size_t)(b * 120 + i) * 512 + h * 64 + lane] = o / sm;
  }
}

// LN with optional bf16 dual-write (for win -> winbf)
__global__ __launch_bounds__(256) void k_ln(const float* __restrict__ a,
                                            const float* __restrict__ bsrc,
                                            const float* __restrict__ g,
                                            const float* __restrict__ be,
                                            float* __restrict__ out,
                                            unsigned short* __restrict__ bfout) {
  int row = blockIdx.x * 4 + (threadIdx.x >> 6);
  int lane = threadIdx.x & 63;
  const float* pa = a + (size_t)row * 512;
  const float* pb = bsrc + (size_t)row * 512;
  float z[8];
  float s = 0;
#pragma unroll
  for (int ii = 0; ii < 8; ++ii) {
    int e = lane + 64 * ii;
    z[ii] = pa[e] + pb[e];
    s += z[ii];
  }
  float mean = wredsum(s) * (1.f / 512.f);
  float v = 0;
#pragma unroll
  for (int ii = 0; ii < 8; ++ii) {
    float d = z[ii] - mean;
    v += d * d;
  }
  float rstd = rsqrtf(wredsum(v) * (1.f / 512.f) + 1e-5f);
#pragma unroll
  for (int ii = 0; ii < 8; ++ii) {
    int e = lane + 64 * ii;
    float val = (z[ii] - mean) * rstd * g[e] + be[e];
    out[(size_t)row * 512 + e] = val;
    if (bfout) bfout[(size_t)row * 512 + e] = f2bf(val);
  }
}

__global__ __launch_bounds__(256) void k_hbias(const float* __restrict__ hT,
                                               const float* __restrict__ W_l1,
                                               const float* __restrict__ b_l1,
                                               float* __restrict__ hb) {
  int b = blockIdx.x >> 1, half = blockIdx.x & 1;
  int tid = threadIdx.x;
  __shared__ float hl[512];
  for (int i = tid; i < 512; i += 256) hl[i] = hT[b * 512 + i];
  __syncthreads();
  int j = half * 256 + tid;
  float a = b_l1[j];
  for (int i = 0; i < 512; ++i) a += hl[i] * W_l1[(size_t)(512 + i) * 512 + j];
  hb[b * 512 + j] = a;
}

// MFMA beta1 (unchanged, validated r7-r10)
__global__ __launch_bounds__(256) void k_beta1_bf(
    const unsigned short* __restrict__ winbf, const unsigned short* __restrict__ wl1bf,
    const float* __restrict__ w_l2, const float* __restrict__ hb,
    float* __restrict__ l1) {
  __shared__ float reds[4][64];
  int tid = threadIdx.x;
  int rowbase = blockIdx.x * 64;  // 15 blocks
  int lane = tid & 63, wid = tid >> 6;
  int l16 = lane & 15, lk = lane >> 4;
  const unsigned short* ap[4];
#pragma unroll
  for (int fm = 0; fm < 4; ++fm)
    ap[fm] = winbf + (size_t)(rowbase + fm * 16 + l16) * 512 + lk * 8;
  float ps[4][4] = {};
#pragma unroll
  for (int cs = 0; cs < 2; ++cs) {
    const unsigned short* bp[4];
#pragma unroll
    for (int fn = 0; fn < 4; ++fn)
      bp[fn] = wl1bf + (size_t)(cs * 256 + wid * 64 + fn * 16 + l16) * 512 + lk * 8;
    f32x4 acc[4][4] = {};
    for (int k0 = 0; k0 < 512; k0 += 32) {
      short8 a8[4], b8[4];
#pragma unroll
      for (int fm = 0; fm < 4; ++fm) a8[fm] = *(const short8*)(ap[fm] + k0);
#pragma unroll
      for (int fn = 0; fn < 4; ++fn) b8[fn] = *(const short8*)(bp[fn] + k0);
#pragma unroll
      for (int fm = 0; fm < 4; ++fm)
#pragma unroll
        for (int fn = 0; fn < 4; ++fn)
          acc[fm][fn] = __builtin_amdgcn_mfma_f32_16x16x32_bf16(
              a8[fm], b8[fn], acc[fm][fn], 0, 0, 0);
    }
#pragma unroll
    for (int fm = 0; fm < 4; ++fm)
#pragma unroll
      for (int r = 0; r < 4; ++r) {
        int grow = rowbase + fm * 16 + lk * 4 + r;
        int b = grow / 120;
#pragma unroll
        for (int fn = 0; fn < 4; ++fn) {
          int col = cs * 256 + wid * 64 + fn * 16 + l16;
          ps[fm][r] += fast_tanh(acc[fm][fn][r] + hb[b * 512 + col]) * w_l2[col];
        }
      }
  }
#pragma unroll
  for (int m = 1; m < 16; m <<= 1)
#pragma unroll
    for (int fm = 0; fm < 4; ++fm)
#pragma unroll
      for (int r = 0; r < 4; ++r) ps[fm][r] += __shfl_xor(ps[fm][r], m);
  if (l16 == 0) {
#pragma unroll
    for (int fm = 0; fm < 4; ++fm)
#pragma unroll
      for (int r = 0; r < 4; ++r) reds[wid][fm * 16 + lk * 4 + r] = ps[fm][r];
  }
  __syncthreads();
  if (tid < 64)
    l1[rowbase + tid] = reds[0][tid] + reds[1][tid] + reds[2][tid] + reds[3][tid];
}

// fallback fp32 beta1
__global__ __launch_bounds__(256) void k_beta1(
    const float* __restrict__ within, const float* __restrict__ W_l1,
    const float* __restrict__ w_l2, const float* __restrict__ hb,
    float* __restrict__ l1) {
  int bid = blockIdx.x;
  int r0 = bid * 4;
  int b = r0 / 120;
  int tid = threadIdx.x;
  __shared__ float xr[4][512];
  __shared__ float red[4][256];
  for (int i = tid; i < 2048; i += 256) xr[i >> 9][i & 511] = within[(size_t)r0 * 512 + i];
  __syncthreads();
  float v[4] = {0, 0, 0, 0};
  for (int jj = 0; jj < 2; ++jj) {
    int j = tid + jj * 256;
    float hbv = hb[b * 512 + j];
    float a0 = hbv, a1 = hbv, a2 = hbv, a3 = hbv;
    for (int i = 0; i < 512; ++i) {
      float ww = W_l1[(size_t)i * 512 + j];
      a0 += xr[0][i] * ww;
      a1 += xr[1][i] * ww;
      a2 += xr[2][i] * ww;
      a3 += xr[3][i] * ww;
    }
    float wl = w_l2[j];
    v[0] += fast_tanh(a0) * wl;
    v[1] += fast_tanh(a1) * wl;
    v[2] += fast_tanh(a2) * wl;
    v[3] += fast_tanh(a3) * wl;
  }
#pragma unroll
  for (int r = 0; r < 4; ++r) red[r][tid] = v[r];
  __syncthreads();
  for (int s = 128; s; s >>= 1) {
    if (tid < s)
      for (int r = 0; r < 4; ++r) red[r][tid] += red[r][tid + s];
    __syncthreads();
  }
  if (tid < 4) l1[r0 + tid] = red[tid][0];
}

__global__ __launch_bounds__(256) void k_final(
    const float* __restrict__ l1, const float* __restrict__ z2,
    const float* __restrict__ within, const float* __restrict__ hT,
    const float* __restrict__ cT, float* __restrict__ dout) {
  int b = blockIdx.x;
  int tid = threadIdx.x;
  __shared__ float temp[120];
  __shared__ float b2[10];
  int wv = tid >> 6, lane = tid & 63;
  if (wv == 1) {
    float v = (lane < 10) ? z2[b * 10 + lane] : -1e30f;
    float mx = wredmax(v);
    float e = (lane < 10) ? __expf(v - mx) : 0.f;
    float sm = wredsum(e);
    if (lane < 10) {
      float p = e / sm;
      b2[lane] = p;
      dout[O_B2 + b * 10 + lane] = p;
    }
  }
  if (wv == 0) {
    float v1 = l1[b * 120 + lane];
    float v2 = (lane + 64 < 120) ? l1[b * 120 + 64 + lane] : -1e30f;
    float mx = wredmax(fmaxf(v1, v2));
    float e1 = __expf(v1 - mx);
    float e2 = (lane + 64 < 120) ? __expf(v2 - mx) : 0.f;
    float sm = wredsum(e1 + e2);
    float p1 = e1 / sm;
    dout[O_B1 + b * 120 + lane] = p1;
    temp[lane] = p1;
    if (lane + 64 < 120) {
      float p2 = e2 / sm;
      dout[O_B1 + b * 120 + 64 + lane] = p2;
      temp[64 + lane] = p2;
    }
  }
  __syncthreads();
  for (int t = tid; t < 120; t += 256) temp[t] += b2[t / 12];
  __syncthreads();
  for (int hh = tid; hh < 512; hh += 256) {
    float o = 0;
    for (int t = 0; t < 120; ++t) o += temp[t] * within[(size_t)(b * 120 + t) * 512 + hh];
    dout[O_OUT + b * 512 + hh] = o;
    dout[O_HT + b * 512 + hh] = hT[b * 512 + hh];
    dout[O_CT + b * 512 + hh] = cT[b * 512 + hh];
  }
}

// ---------------------------------------------------------------
extern "C" void kernel_launch(void* const* d_in, const int* in_sizes, int n_in,
                              void* d_out, int out_size, void* d_ws, size_t ws_size,
                              hipStream_t stream) {
  const float* videos = (const float*)d_in[0];
  const float* sub_g  = (const float*)d_in[1];
  const float* obj_g  = (const float*)d_in[2];
  const float* W_ev   = (const float*)d_in[3];
  const float* b_ev   = (const float*)d_in[4];
  const float* W_el   = (const float*)d_in[5];
  const float* b_el   = (const float*)d_in[6];
  const float* W_ew   = (const float*)d_in[7];
  const float* b_ew   = (const float*)d_in[8];
  const float* W_sp1  = (const float*)d_in[9];
  const float* b_sp1  = (const float*)d_in[10];
  const float* w_sp2  = (const float*)d_in[11];
  const float* W_s2o  = (const float*)d_in[12];
  const float* b_s2o  = (const float*)d_in[13];
  const float* W_o2s  = (const float*)d_in[14];
  const float* b_o2s  = (const float*)d_in[15];
  const float* W_tv   = (const float*)d_in[16];
  const float* b_tv   = (const float*)d_in[17];
  const float* Wq     = (const float*)d_in[18];
  const float* bq     = (const float*)d_in[19];
  const float* Wk     = (const float*)d_in[20];
  const float* bk     = (const float*)d_in[21];
  const float* Wv     = (const float*)d_in[22];
  const float* bv     = (const float*)d_in[23];
  const float* Wo     = (const float*)d_in[24];
  const float* bo     = (const float*)d_in[25];
  const float* g1     = (const float*)d_in[26];
  const float* be1    = (const float*)d_in[27];
  const float* Wf1    = (const float*)d_in[28];
  const float* bf1    = (const float*)d_in[29];
  const float* Wf2    = (const float*)d_in[30];
  const float* bf2    = (const float*)d_in[31];
  const float* g2     = (const float*)d_in[32];
  const float* be2    = (const float*)d_in[33];
  const float* W_tr   = (const float*)d_in[34];
  const float* b_tr   = (const float*)d_in[35];
  const float* W_tb1  = (const float*)d_in[36];
  const float* b_tb1  = (const float*)d_in[37];
  const float* w_tb2  = (const float*)d_in[38];
  const float* W_ih   = (const float*)d_in[39];
  const float* W_hh   = (const float*)d_in[40];
  const float* b_ih   = (const float*)d_in[41];
  const float* b_hh   = (const float*)d_in[42];
  const float* W_l1   = (const float*)d_in[43];
  const float* b_l1   = (const float*)d_in[44];
  const float* w_l2   = (const float*)d_in[45];

  float* out = (float*)d_out;
  float* w = (float*)d_ws;

  float* ve_p   = w + OFF_VE;
  float* ssub_p = w + OFF_SSUB;
  float* sobj_p = w + OFF_SOBJ;
  float* wbs_p  = w + OFF_WBS;
  float* wbo_p  = w + OFF_WBO;
  float* tb_p   = w + OFF_TBIAS;
  float* orix_p = w + OFF_ORIX;
  float* x_p    = w + OFF_X;
  float* q_p    = w + OFF_Q;
  float* k_p    = w + OFF_K;
  float* v_p    = w + OFF_V;
  float* ao_p   = w + OFF_AO;
  float* attn_p = w + OFF_ATTN;
  float* x1_p   = w + OFF_X1;
  float* f1_p   = w + OFF_F1;
  float* f2_p   = w + OFF_F2;
  float* win_p  = w + OFF_WIN;
  float* z2_p   = w + OFF_Z2;
  float* h_p    = w + OFF_H0;           // h0[4096], h1[4096], c[4096]
  float* c_p    = h_p + 2 * 4096;
  float* hb_p   = w + OFF_HB;
  float* l1_p   = w + OFF_L1;

  unsigned short* wtbase = (unsigned short*)(w + OFF_WT);
  unsigned short* wevbf = wtbase;                    // [256][2048]
  unsigned short* w7bf  = wtbase + 524288;           // 7 x [512][512]
  unsigned short* wtvbf = w7bf;
  unsigned short* wqbf  = w7bf + 1 * 262144;
  unsigned short* wobf  = w7bf + 4 * 262144;
  unsigned short* wf1bf = w7bf + 5 * 262144;
  unsigned short* wf2bf = w7bf + 6 * 262144;
  unsigned short* wsp1bf = w7bf + 7 * 262144;        // [256][256]
  // big-path dedicated buffers
  unsigned short* wihbf  = (unsigned short*)(w + OFF_WIH);
  unsigned short* whhbf  = (unsigned short*)(w + OFF_WHH);
  unsigned short* wl1bf  = (unsigned short*)(w + OFF_WL1B);
  unsigned short* winbf_p = (unsigned short*)(w + OFF_WINBF);
  unsigned short* vebf_p = (unsigned short*)(w + OFF_VEBF);
  float* gx_p = w + OFF_Q;  // aliases dead Q (written post-mha by k_xb)
  const bool big = ws_size >= (size_t)OFF_END * 4;

  if (big) {
    k_wprep<<<1689, 256, 0, stream>>>(W_ev, W_tv, Wq, Wk, Wv, Wo, Wf1, Wf2,
                                      W_sp1, W_l1, W_ih, W_hh, sub_g, obj_g,
                                      W_ew, b_ew, b_sp1, W_tr, b_tr, W_tb1,
                                      b_tb1, wevbf, w7bf, wsp1bf, wl1bf, wihbf,
                                      whhbf, h_p, wbs_p, wbo_p, tb_p);
    k_gemm_ve_m97<<<600, 512, 0, stream>>>(videos, wevbf, b_ev, W_el, b_el,
                                           vebf_p);
    k_score_bf<<<600, 256, 0, stream>>>(vebf_p, wsp1bf, w_sp2, wbs_p, wbo_p,
                                        ssub_p, sobj_p);
    k_attend_bf<<<960, 256, 0, stream>>>(ssub_p, sobj_p, vebf_p, W_s2o, b_s2o,
                                         W_o2s, b_o2s, out + O_SATT,
                                         out + O_OATT, orix_p);
    k_gemm_h<<<240, 256, 0, stream>>>(orix_p, wtvbf, b_tv, b_tv, b_tv, x_p, 8, 1);
    k_gemm_h<<<720, 256, 0, stream>>>(x_p, wqbf, bq, bk, bv, q_p, 24, 0);
    k_mha<<<256, 256, 0, stream>>>(q_p, k_p, v_p, ao_p);
    k_gemm_h<<<240, 256, 0, stream>>>(ao_p, wobf, bo, bo, bo, attn_p, 8, 0);
    k_ln<<<240, 256, 0, stream>>>(x_p, attn_p, g1, be1, x1_p, nullptr);
    k_gemm_h<<<240, 256, 0, stream>>>(x1_p, wf1bf, bf1, bf1, bf1, f1_p, 8, 1);
    k_gemm_h<<<240, 256, 0, stream>>>(f1_p, wf2bf, bf2, bf2, bf2, f2_p, 8, 0);
    k_ln<<<240, 256, 0, stream>>>(x1_p, f2_p, g2, be2, win_p, winbf_p);
    k_xb<<<144, 256, 0, stream>>>(win_p, wihbf, b_ih, b_hh, gx_p, W_tb1, w_tb2,
                                  tb_p, z2_p);
    for (int s = 0; s < 10; ++s) {
      float* hin = h_p + (s & 1) * 4096;
      float* hout = h_p + ((s & 1) ^ 1) * 4096;
      k_lstm_step<<<32, 128, 0, stream>>>(hin, whhbf, gx_p, s, hout, c_p);
    }
    k_hbias<<<16, 256, 0, stream>>>(h_p, W_l1, b_l1, hb_p);
    k_beta1_bf<<<15, 256, 0, stream>>>(winbf_p, wl1bf, w_l2, hb_p, l1_p);
    k_final<<<8, 256, 0, stream>>>(l1_p, z2_p, win_p, h_p, c_p, out);
  } else {
    // fallback (r6/r7-validated small-ws path)
    unsigned short* wihbf_a = (unsigned short*)(w + OFF_Q + 163840);
    unsigned short* whhbf_a = (unsigned short*)(w + OFF_Q + 688128);
    k_zero<<<48, 256, 0, stream>>>(h_p, 3 * 4096);
    k_small0<<<8, 256, 0, stream>>>(sub_g, obj_g, W_ew, b_ew, W_sp1, b_sp1,
                                    W_tr, b_tr, W_tb1, b_tb1, wbs_p, wbo_p, tb_p);
    k_wconvT<<<128, 256, 0, stream>>>(W_ev, wevbf, 2048, 256);
    k_wconv7<<<448, 256, 0, stream>>>(W_tv, Wq, Wk, Wv, Wo, Wf1, Wf2, w7bf);
    k_gemm_ve_mfma<<<600, 256, 0, stream>>>(videos, wevbf, b_ev, W_el, b_el, ve_p);
    k_score<<<1200, 256, 0, stream>>>(ve_p, W_sp1, w_sp2, wbs_p, wbo_p, ssub_p, sobj_p);
    k_attend<<<960, 256, 0, stream>>>(ssub_p, sobj_p, ve_p, W_s2o, b_s2o, W_o2s,
                                      b_o2s, out + O_SATT, out + O_OATT, orix_p);
    k_gemm_h<<<240, 256, 0, stream>>>(orix_p, wtvbf, b_tv, b_tv, b_tv, x_p, 8, 1);
    k_gemm_h<<<720, 256, 0, stream>>>(x_p, wqbf, bq, bk, bv, q_p, 24, 0);
    k_mha<<<256, 256, 0, stream>>>(q_p, k_p, v_p, ao_p);
    k_gemm_h<<<240, 256, 0, stream>>>(ao_p, wobf, bo, bo, bo, attn_p, 8, 0);
    k_ln<<<240, 256, 0, stream>>>(x_p, attn_p, g1, be1, x1_p, nullptr);
    k_gemm_h<<<240, 256, 0, stream>>>(x1_p, wf1bf, bf1, bf1, bf1, f1_p, 8, 1);
    k_gemm_h<<<240, 256, 0, stream>>>(f1_p, wf2bf, bf2, bf2, bf2, f2_p, 8, 0);
    k_ln<<<240, 256, 0, stream>>>(x1_p, f2_p, g2, be2, win_p, nullptr);
    k_cvt2<<<1024, 256, 0, stream>>>(W_ih, W_hh, wihbf_a, whhbf_a);
    k_xproj<<<64, 256, 0, stream>>>(win_p, wihbf_a, b_ih, b_hh, gx_p);
    k_beta2<<<80, 256, 0, stream>>>(win_p, W_tb1, w_tb2, tb_p, z2_p);
    for (int s = 0; s < 10; ++s) {
      float* hin = h_p + (s & 1) * 4096;
      float* hout = h_p + ((s & 1) ^ 1) * 4096;
      k_lstm_step<<<32, 128, 0, stream>>>(hin, whhbf_a, gx_p, s, hout, c_p);
    }
    k_hbias<<<16, 256, 0, stream>>>(h_p, W_l1, b_l1, hb_p);
    k_beta1<<<240, 256, 0, stream>>>(win_p, W_l1, w_l2, hb_p, l1_p);
    k_final<<<8, 256, 0, stream>>>(l1_p, z2_p, win_p, h_p, c_p, out);
  }
}